// Round 11
// baseline (775.800 us; speedup 1.0000x reference)
//
#include <hip/hip_runtime.h>

#define N_S 512
#define N_G 11560
#define N_P 2000
#define NE_SG 1000000
#define NE_GP 200000
#define NE_PP 50000
#define HID 192
#define HEADS 4
#define CDIM 48
#define NQd 20
#define OUTD 128
#define LDK 12288
#define SPLITK 16
#define CHUNKK 768

typedef __attribute__((ext_vector_type(8))) short short8;
typedef __attribute__((ext_vector_type(4))) float float4v;

__device__ __forceinline__ float bf2f(unsigned short u){
  union { unsigned int i; float f; } x; x.i = ((unsigned int)u) << 16; return x.f;
}
__device__ __forceinline__ unsigned short f2bf(float f){
  union { float f; unsigned int i; } u; u.f = f;
  unsigned int r = u.i + 0x7FFFu + ((u.i >> 16) & 1u);
  return (unsigned short)(r >> 16);
}
__device__ __forceinline__ ushort4 f4bf(float4 v){
  return make_ushort4(f2bf(v.x), f2bf(v.y), f2bf(v.z), f2bf(v.w));
}

// ---------------- dtype detection (flag=1 fp32, flag=0 bf16) ----------------
__global__ __launch_bounds__(256) void k_detect(const unsigned int* __restrict__ raw,
                                                int* __restrict__ flag){
  __shared__ int cnt;
  if (threadIdx.x == 0) cnt = 0;
  __syncthreads();
  int c = 0;
  for (int i = threadIdx.x; i < 2048; i += 256) {
    float f = __uint_as_float(raw[i]);
    float a = fabsf(f);
    if (f == f && a > 1e-4f && a < 1000.0f) c++;
  }
  atomicAdd(&cnt, c);
  __syncthreads();
  if (threadIdx.x == 0) flag[0] = (cnt >= 1024) ? 1 : 0;
}

// ---------------- batched input load (27 tensors, grid-stride) ----------
#define NLOAD 27
#define LOADBX 2048
struct LoadDesc { const void* src; float* dst; int n; };
struct LoadTable { LoadDesc d[NLOAD]; };
__global__ __launch_bounds__(256)
void k_load_all(LoadTable tab, const int* __restrict__ flag){
  LoadDesc de = tab.d[blockIdx.y];
  int fp32 = flag[0];
  for (int i = blockIdx.x*256 + threadIdx.x; i < de.n; i += LOADBX*256) {
    if (fp32) de.dst[i] = ((const float*)de.src)[i];
    else      de.dst[i] = bf2f(((const unsigned short*)de.src)[i]);
  }
}

// ---------------- dense count matrix (CntG only; CntS derived) -------------
__global__ __launch_bounds__(256)
void k_cntbuild(const int* __restrict__ src, const int* __restrict__ dst,
                int* __restrict__ cg, int E){
  int i = blockIdx.x*256 + threadIdx.x;
  if (i >= E) return;
  atomicAdd(&cg[(size_t)dst[i]*N_S + src[i]], 1);
}

// convert CntG(int)->bf16 and write transposed bf16 CntS [512 x LDK] (zero-pad)
__global__ __launch_bounds__(256)
void k_cvtT(const int* __restrict__ cg, unsigned short* __restrict__ bfA,
            unsigned short* __restrict__ bfB){
  __shared__ unsigned short tile[64][68];
  int g0 = blockIdx.x*64, s0 = blockIdx.y*64;
  int t = threadIdx.x; int r = t>>2, seg = t&3;
  int g = g0 + r;
  if (g < N_G) {
    const int* row = cg + (size_t)g*N_S + s0 + seg*16;
    unsigned short* arow = bfA + (size_t)g*N_S + s0 + seg*16;
    #pragma unroll
    for (int i=0;i<16;i++){
      unsigned short v = f2bf((float)row[i]);
      tile[r][seg*16+i] = v;
      arow[i] = v;
    }
  } else {
    #pragma unroll
    for (int i=0;i<16;i++) tile[r][seg*16+i] = 0;
  }
  __syncthreads();
  int s = s0 + r;
  unsigned short* brow = bfB + (size_t)s*LDK + g0 + seg*16;
  #pragma unroll
  for (int i=0;i<16;i++) brow[i] = tile[seg*16+i][r];
}

__global__ __launch_bounds__(256)
void k_rowinv_i(const int* __restrict__ A, int lda, int cols, int n,
                float* __restrict__ outp){
  int row = blockIdx.x*4 + (threadIdx.x >> 6);
  if (row >= n) return;
  int lane = threadIdx.x & 63;
  const int* Ar = A + (size_t)row*lda;
  float s = 0.0f;
  for (int c = lane; c < cols; c += 64) s += (float)Ar[c];
  #pragma unroll
  for (int o = 32; o; o >>= 1) s += __shfl_xor(s, o);
  if (lane == 0) outp[row] = 1.0f / fmaxf(s, 1.0f);
}
__global__ __launch_bounds__(256)
void k_rowinv_h(const unsigned short* __restrict__ A, int lda, int cols, int n,
                float* __restrict__ outp){
  int row = blockIdx.x*4 + (threadIdx.x >> 6);
  if (row >= n) return;
  int lane = threadIdx.x & 63;
  const unsigned short* Ar = A + (size_t)row*lda;
  float s = 0.0f;
  for (int c = lane; c < cols; c += 64) s += bf2f(Ar[c]);
  #pragma unroll
  for (int o = 32; o; o >>= 1) s += __shfl_xor(s, o);
  if (lane == 0) outp[row] = 1.0f / fmaxf(s, 1.0f);
}

// ---------------- dual transpose [n x 192] fp32 -> [192 x ldo] bf16 --------
struct TransJobs { const float* inA; unsigned short* outA; int nA; int ldoA; int rbA;
                   const float* inB; unsigned short* outB; int nB; int ldoB; };
__global__ __launch_bounds__(256)
void k_transpose2(TransJobs tj){
  const float* in; unsigned short* outp; int n, ldo, r0;
  int bx = blockIdx.x;
  if (bx < tj.rbA) { in = tj.inA; outp = tj.outA; n = tj.nA; ldo = tj.ldoA; r0 = bx*64; }
  else             { in = tj.inB; outp = tj.outB; n = tj.nB; ldo = tj.ldoB; r0 = (bx - tj.rbA)*64; }
  __shared__ float tile[64][65];
  int c0 = blockIdx.y*64;
  int t = threadIdx.x;
  int r = t >> 2, seg = t & 3;
  int grr = r0 + r;
  if (grr < n) {
    #pragma unroll
    for (int i = 0; i < 4; i++) {
      float4 v = *(const float4*)(in + (size_t)grr*HID + c0 + seg*16 + i*4);
      tile[r][seg*16+i*4+0] = v.x; tile[r][seg*16+i*4+1] = v.y;
      tile[r][seg*16+i*4+2] = v.z; tile[r][seg*16+i*4+3] = v.w;
    }
  } else {
    #pragma unroll
    for (int i = 0; i < 16; i++) tile[r][seg*16+i] = 0.0f;
  }
  __syncthreads();
  int w = t >> 6, lane = t & 63;
  if (r0 + lane < ldo) {
    #pragma unroll
    for (int j = 0; j < 16; j++) {
      int c = w*16 + j;
      outp[(size_t)(c0+c)*ldo + r0 + lane] = f2bf(tile[lane][c]);
    }
  }
}

// ---------------- batched CSR build (3 graphs) ----------------
struct CsrJob { const int* src; const int* dst; int E; int n;
                int* deg; int* rowptr; int* cursor; int* col; };
struct CsrJobs { CsrJob j[3]; };

__global__ __launch_bounds__(256) void k_hist3(CsrJobs jobs){
  CsrJob jb = jobs.j[blockIdx.y];
  int i = blockIdx.x*256 + threadIdx.x;
  if (i < jb.E) atomicAdd(&jb.deg[jb.dst[i]], 1);
}
__global__ __launch_bounds__(256) void k_scan3(CsrJobs jobs){
  CsrJob jb = jobs.j[blockIdx.x];
  __shared__ int part[256];
  __shared__ int pre[256];
  int t = threadIdx.x;
  int n = jb.n;
  int C = (n + 255) >> 8;
  int lo = t*C, hi = min(n, lo + C);
  int s = 0;
  for (int i = lo; i < hi; i++) s += jb.deg[i];
  part[t] = s;
  __syncthreads();
  if (t == 0) {
    int acc = 0;
    for (int i = 0; i < 256; i++) { pre[i] = acc; acc += part[i]; }
    jb.rowptr[n] = acc;
  }
  __syncthreads();
  int run = pre[t];
  for (int i = lo; i < hi; i++) {
    jb.rowptr[i] = run; jb.cursor[i] = run; run += jb.deg[i];
  }
}
__global__ __launch_bounds__(256) void k_fill3(CsrJobs jobs){
  CsrJob jb = jobs.j[blockIdx.y];
  int i = blockIdx.x*256 + threadIdx.x;
  if (i >= jb.E) return;
  int pos = atomicAdd(&jb.cursor[jb.dst[i]], 1);
  jb.col[pos] = jb.src[i];
}

// ---------------- MFMA bf16 GEMM (K=192, fp32 A/W): out (+)= A·W^T (+bias) --
#define LDA 200
__global__ __launch_bounds__(256)
void k_gemm(const float* __restrict__ A, const float* __restrict__ rowscale,
            const float* __restrict__ W, const float* __restrict__ bias,
            float* __restrict__ outp, int n, int accum)
{
  __shared__ __align__(16) unsigned short Asm[64*LDA];
  __shared__ __align__(16) unsigned short Wsm[64*LDA];
  int t = threadIdx.x;
  int row0 = blockIdx.x * 64;
  int col0 = blockIdx.y * 64;
  {
    int r = t >> 2, seg = t & 3;
    int gr = row0 + r;
    unsigned short* ad = Asm + r*LDA + seg*48;
    if (gr < n) {
      float sc = rowscale ? rowscale[gr] : 1.0f;
      const float* Ar = A + (size_t)gr*HID + seg*48;
      #pragma unroll
      for (int i = 0; i < 12; i++) {
        float4 v = *reinterpret_cast<const float4*>(Ar + i*4);
        v.x *= sc; v.y *= sc; v.z *= sc; v.w *= sc;
        *reinterpret_cast<ushort4*>(ad + i*4) = f4bf(v);
      }
    } else {
      ushort4 z = make_ushort4(0,0,0,0);
      #pragma unroll
      for (int i = 0; i < 12; i++) *reinterpret_cast<ushort4*>(ad + i*4) = z;
    }
    const float* Wr = W + (size_t)(col0 + r)*HID + seg*48;
    unsigned short* wd = Wsm + r*LDA + seg*48;
    #pragma unroll
    for (int i = 0; i < 12; i++) {
      float4 v = *reinterpret_cast<const float4*>(Wr + i*4);
      *reinterpret_cast<ushort4*>(wd + i*4) = f4bf(v);
    }
  }
  __syncthreads();
  int w = t >> 6, lane = t & 63;
  int quad = lane >> 4, mr = lane & 15;
  float4v acc[4] = {};
  const unsigned short* Abase = Asm + (w*16 + mr)*LDA + quad*8;
  const unsigned short* Wbase = Wsm + mr*LDA + quad*8;
  #pragma unroll
  for (int k0 = 0; k0 < 6; k0++) {
    short8 a = *reinterpret_cast<const short8*>(Abase + k0*32);
    #pragma unroll
    for (int ct = 0; ct < 4; ct++) {
      short8 b = *reinterpret_cast<const short8*>(Wbase + ct*16*LDA + k0*32);
      acc[ct] = __builtin_amdgcn_mfma_f32_16x16x32_bf16(a, b, acc[ct], 0, 0, 0);
    }
  }
  #pragma unroll
  for (int ct = 0; ct < 4; ct++) {
    #pragma unroll
    for (int reg = 0; reg < 4; reg++) {
      int rr = row0 + w*16 + quad*4 + reg;
      if (rr < n) {
        int cc = col0 + ct*16 + mr;
        float v = acc[ct][reg];
        if (bias) v += bias[cc];
        if (accum) v += outp[(size_t)rr*HID + cc];
        outp[(size_t)rr*HID + cc] = v;
      }
    }
  }
}

// ---------------- batched K=192 GEMM (6 jobs, bf16 out, flat grid) ---------
struct GemmJob { const float* A; const float* W; const float* bias;
                 unsigned short* out; int n; };
struct GemmJobs { GemmJob j[6]; int rb[7]; };  // rb = cumulative row-blocks
__global__ __launch_bounds__(256)
void k_gemm6(GemmJobs jobs)
{
  int bx = blockIdx.x;
  int z = 0;
  #pragma unroll
  for (int q = 1; q < 6; q++) if (bx >= jobs.rb[q]) z = q;
  GemmJob jb = jobs.j[z];
  int row0 = (bx - jobs.rb[z]) * 64;
  __shared__ __align__(16) unsigned short Asm[64*LDA];
  __shared__ __align__(16) unsigned short Wsm[64*LDA];
  int t = threadIdx.x;
  int col0 = blockIdx.y * 64;
  {
    int r = t >> 2, seg = t & 3;
    int gr = row0 + r;
    unsigned short* ad = Asm + r*LDA + seg*48;
    if (gr < jb.n) {
      const float* Ar = jb.A + (size_t)gr*HID + seg*48;
      #pragma unroll
      for (int i = 0; i < 12; i++) {
        float4 v = *reinterpret_cast<const float4*>(Ar + i*4);
        *reinterpret_cast<ushort4*>(ad + i*4) = f4bf(v);
      }
    } else {
      ushort4 zz = make_ushort4(0,0,0,0);
      #pragma unroll
      for (int i = 0; i < 12; i++) *reinterpret_cast<ushort4*>(ad + i*4) = zz;
    }
    const float* Wr = jb.W + (size_t)(col0 + r)*HID + seg*48;
    unsigned short* wd = Wsm + r*LDA + seg*48;
    #pragma unroll
    for (int i = 0; i < 12; i++) {
      float4 v = *reinterpret_cast<const float4*>(Wr + i*4);
      *reinterpret_cast<ushort4*>(wd + i*4) = f4bf(v);
    }
  }
  __syncthreads();
  int w = t >> 6, lane = t & 63;
  int quad = lane >> 4, mr = lane & 15;
  float4v acc[4] = {};
  const unsigned short* Abase = Asm + (w*16 + mr)*LDA + quad*8;
  const unsigned short* Wbase = Wsm + mr*LDA + quad*8;
  #pragma unroll
  for (int k0 = 0; k0 < 6; k0++) {
    short8 a = *reinterpret_cast<const short8*>(Abase + k0*32);
    #pragma unroll
    for (int ct = 0; ct < 4; ct++) {
      short8 b = *reinterpret_cast<const short8*>(Wbase + ct*16*LDA + k0*32);
      acc[ct] = __builtin_amdgcn_mfma_f32_16x16x32_bf16(a, b, acc[ct], 0, 0, 0);
    }
  }
  #pragma unroll
  for (int ct = 0; ct < 4; ct++) {
    #pragma unroll
    for (int reg = 0; reg < 4; reg++) {
      int rr = row0 + w*16 + quad*4 + reg;
      if (rr < jb.n) {
        int cc = col0 + ct*16 + mr;
        jb.out[(size_t)rr*HID + cc] = f2bf(acc[ct][reg] + jb.bias[cc]);
      }
    }
  }
}

// ---------------- batched K=192 GEMM (3 jobs, fp32 out) — pooling q/k/v ----
struct PoolJob { const float* A; const float* W; const float* bias;
                 float* out; int n; };
struct PoolJobs { PoolJob j[3]; int rb[4]; };
__global__ __launch_bounds__(256)
void k_gemm3(PoolJobs jobs)
{
  int bx = blockIdx.x;
  int z = 0;
  if (bx >= jobs.rb[1]) z = 1;
  if (bx >= jobs.rb[2]) z = 2;
  PoolJob jb = jobs.j[z];
  int row0 = (bx - jobs.rb[z]) * 64;
  __shared__ __align__(16) unsigned short Asm[64*LDA];
  __shared__ __align__(16) unsigned short Wsm[64*LDA];
  int t = threadIdx.x;
  int col0 = blockIdx.y * 64;
  {
    int r = t >> 2, seg = t & 3;
    int gr = row0 + r;
    unsigned short* ad = Asm + r*LDA + seg*48;
    if (gr < jb.n) {
      const float* Ar = jb.A + (size_t)gr*HID + seg*48;
      #pragma unroll
      for (int i = 0; i < 12; i++) {
        float4 v = *reinterpret_cast<const float4*>(Ar + i*4);
        *reinterpret_cast<ushort4*>(ad + i*4) = f4bf(v);
      }
    } else {
      ushort4 zz = make_ushort4(0,0,0,0);
      #pragma unroll
      for (int i = 0; i < 12; i++) *reinterpret_cast<ushort4*>(ad + i*4) = zz;
    }
    const float* Wr = jb.W + (size_t)(col0 + r)*HID + seg*48;
    unsigned short* wd = Wsm + r*LDA + seg*48;
    #pragma unroll
    for (int i = 0; i < 12; i++) {
      float4 v = *reinterpret_cast<const float4*>(Wr + i*4);
      *reinterpret_cast<ushort4*>(wd + i*4) = f4bf(v);
    }
  }
  __syncthreads();
  int w = t >> 6, lane = t & 63;
  int quad = lane >> 4, mr = lane & 15;
  float4v acc[4] = {};
  const unsigned short* Abase = Asm + (w*16 + mr)*LDA + quad*8;
  const unsigned short* Wbase = Wsm + mr*LDA + quad*8;
  #pragma unroll
  for (int k0 = 0; k0 < 6; k0++) {
    short8 a = *reinterpret_cast<const short8*>(Abase + k0*32);
    #pragma unroll
    for (int ct = 0; ct < 4; ct++) {
      short8 b = *reinterpret_cast<const short8*>(Wbase + ct*16*LDA + k0*32);
      acc[ct] = __builtin_amdgcn_mfma_f32_16x16x32_bf16(a, b, acc[ct], 0, 0, 0);
    }
  }
  #pragma unroll
  for (int ct = 0; ct < 4; ct++) {
    #pragma unroll
    for (int reg = 0; reg < 4; reg++) {
      int rr = row0 + w*16 + quad*4 + reg;
      if (rr < jb.n) {
        int cc = col0 + ct*16 + mr;
        jb.out[(size_t)rr*HID + cc] = acc[ct][reg] + jb.bias[cc];
      }
    }
  }
}

// ---------------- fused dual GEMM: out = A1·W1^T (rowscaled) + A2·W2^T + bias
__global__ __launch_bounds__(256)
void k_gemm2(const float* __restrict__ A1, const float* __restrict__ rs1,
             const float* __restrict__ W1,
             const float* __restrict__ A2, const float* __restrict__ W2,
             const float* __restrict__ bias,
             float* __restrict__ outp, int n)
{
  __shared__ __align__(16) unsigned short Asm[64*LDA];
  __shared__ __align__(16) unsigned short Wsm[64*LDA];
  int t = threadIdx.x;
  int row0 = blockIdx.x * 64;
  int col0 = blockIdx.y * 64;
  int r = t >> 2, seg = t & 3;
  int w = t >> 6, lane = t & 63;
  int quad = lane >> 4, mr = lane & 15;
  float4v acc[4] = {};
  for (int p = 0; p < 2; p++) {
    if (p) __syncthreads();
    const float* A = p ? A2 : A1;
    const float* W = p ? W2 : W1;
    {
      int gr = row0 + r;
      unsigned short* ad = Asm + r*LDA + seg*48;
      if (gr < n) {
        float sc = (!p && rs1) ? rs1[gr] : 1.0f;
        const float* Ar = A + (size_t)gr*HID + seg*48;
        #pragma unroll
        for (int i = 0; i < 12; i++) {
          float4 v = *reinterpret_cast<const float4*>(Ar + i*4);
          v.x *= sc; v.y *= sc; v.z *= sc; v.w *= sc;
          *reinterpret_cast<ushort4*>(ad + i*4) = f4bf(v);
        }
      } else {
        ushort4 z = make_ushort4(0,0,0,0);
        #pragma unroll
        for (int i = 0; i < 12; i++) *reinterpret_cast<ushort4*>(ad + i*4) = z;
      }
      const float* Wr = W + (size_t)(col0 + r)*HID + seg*48;
      unsigned short* wd = Wsm + r*LDA + seg*48;
      #pragma unroll
      for (int i = 0; i < 12; i++) {
        float4 v = *reinterpret_cast<const float4*>(Wr + i*4);
        *reinterpret_cast<ushort4*>(wd + i*4) = f4bf(v);
      }
    }
    __syncthreads();
    const unsigned short* Abase = Asm + (w*16 + mr)*LDA + quad*8;
    const unsigned short* Wbase = Wsm + mr*LDA + quad*8;
    #pragma unroll
    for (int k0 = 0; k0 < 6; k0++) {
      short8 a = *reinterpret_cast<const short8*>(Abase + k0*32);
      #pragma unroll
      for (int ct = 0; ct < 4; ct++) {
        short8 b = *reinterpret_cast<const short8*>(Wbase + ct*16*LDA + k0*32);
        acc[ct] = __builtin_amdgcn_mfma_f32_16x16x32_bf16(a, b, acc[ct], 0, 0, 0);
      }
    }
  }
  #pragma unroll
  for (int ct = 0; ct < 4; ct++) {
    #pragma unroll
    for (int reg = 0; reg < 4; reg++) {
      int rr = row0 + w*16 + quad*4 + reg;
      if (rr < n) {
        int cc = col0 + ct*16 + mr;
        outp[(size_t)rr*HID + cc] = acc[ct][reg] + bias[cc];
      }
    }
  }
}

// ---------------- general-K MFMA GEMM, bf16 inputs ----------------
#define BKG 128
#define LDG 136
__global__ __launch_bounds__(256)
void k_gemm_g(const unsigned short* __restrict__ A, int lda,
              const unsigned short* __restrict__ W, int ldw,
              float* __restrict__ outp, int n, int K)
{
  __shared__ __align__(16) unsigned short Asm[64*LDG];
  __shared__ __align__(16) unsigned short Wsm[64*LDG];
  int t = threadIdx.x;
  int row0 = blockIdx.x * 64;
  int col0 = blockIdx.y * 64;
  int r = t >> 2, seg = t & 3;
  int w = t >> 6, lane = t & 63;
  int quad = lane >> 4, mr = lane & 15;
  float4v acc[4] = {};
  for (int k0 = 0; k0 < K; k0 += BKG) {
    {
      int gr = row0 + r;
      unsigned short* ad = Asm + r*LDG + seg*32;
      if (gr < n) {
        const unsigned short* Ar = A + (size_t)gr*lda + k0 + seg*32;
        #pragma unroll
        for (int i = 0; i < 4; i++) *(uint4*)(ad + i*8) = *(const uint4*)(Ar + i*8);
      } else {
        uint4 z = make_uint4(0,0,0,0);
        #pragma unroll
        for (int i = 0; i < 4; i++) *(uint4*)(ad + i*8) = z;
      }
      const unsigned short* Wr = W + (size_t)(col0 + r)*ldw + k0 + seg*32;
      unsigned short* wd = Wsm + r*LDG + seg*32;
      #pragma unroll
      for (int i = 0; i < 4; i++) *(uint4*)(wd + i*8) = *(const uint4*)(Wr + i*8);
    }
    __syncthreads();
    const unsigned short* Abase = Asm + (w*16 + mr)*LDG + quad*8;
    const unsigned short* Wbase = Wsm + mr*LDG + quad*8;
    #pragma unroll
    for (int kk = 0; kk < 4; kk++) {
      short8 a = *(const short8*)(Abase + kk*32);
      #pragma unroll
      for (int ct = 0; ct < 4; ct++) {
        short8 b = *(const short8*)(Wbase + ct*16*LDG + kk*32);
        acc[ct] = __builtin_amdgcn_mfma_f32_16x16x32_bf16(a, b, acc[ct], 0, 0, 0);
      }
    }
    __syncthreads();
  }
  #pragma unroll
  for (int ct = 0; ct < 4; ct++) {
    #pragma unroll
    for (int reg = 0; reg < 4; reg++) {
      int rr = row0 + w*16 + quad*4 + reg;
      if (rr < n) outp[(size_t)rr*HID + col0 + ct*16 + mr] = acc[ct][reg];
    }
  }
}

// ---------------- split-K MFMA GEMM, bf16 inputs ----------------
__global__ __launch_bounds__(256)
void k_gemm_sk(const unsigned short* __restrict__ A, int lda,
               const unsigned short* __restrict__ W, int ldw,
               float* __restrict__ part, int n)
{
  __shared__ __align__(16) unsigned short Asm[64*LDG];
  __shared__ __align__(16) unsigned short Wsm[64*LDG];
  int t = threadIdx.x;
  int row0 = blockIdx.x * 64;
  int col0 = blockIdx.y * 64;
  int kz   = blockIdx.z;
  int kbeg = kz * CHUNKK;
  int r = t >> 2, seg = t & 3;
  int w = t >> 6, lane = t & 63;
  int quad = lane >> 4, mr = lane & 15;
  float4v acc[4] = {};
  for (int k0 = kbeg; k0 < kbeg + CHUNKK; k0 += BKG) {
    {
      int gr = row0 + r;
      unsigned short* ad = Asm + r*LDG + seg*32;
      if (gr < n) {
        const unsigned short* Ar = A + (size_t)gr*lda + k0 + seg*32;
        #pragma unroll
        for (int i = 0; i < 4; i++) *(uint4*)(ad + i*8) = *(const uint4*)(Ar + i*8);
      } else {
        uint4 z = make_uint4(0,0,0,0);
        #pragma unroll
        for (int i = 0; i < 4; i++) *(uint4*)(ad + i*8) = z;
      }
      const unsigned short* Wr = W + (size_t)(col0 + r)*ldw + k0 + seg*32;
      unsigned short* wd = Wsm + r*LDG + seg*32;
      #pragma unroll
      for (int i = 0; i < 4; i++) *(uint4*)(wd + i*8) = *(const uint4*)(Wr + i*8);
    }
    __syncthreads();
    const unsigned short* Abase = Asm + (w*16 + mr)*LDG + quad*8;
    const unsigned short* Wbase = Wsm + mr*LDG + quad*8;
    #pragma unroll
    for (int kk = 0; kk < 4; kk++) {
      short8 a = *(const short8*)(Abase + kk*32);
      #pragma unroll
      for (int ct = 0; ct < 4; ct++) {
        short8 b = *(const short8*)(Wbase + ct*16*LDG + kk*32);
        acc[ct] = __builtin_amdgcn_mfma_f32_16x16x32_bf16(a, b, acc[ct], 0, 0, 0);
      }
    }
    __syncthreads();
  }
  float* pd = part + (size_t)kz*n*HID;
  #pragma unroll
  for (int ct = 0; ct < 4; ct++) {
    #pragma unroll
    for (int reg = 0; reg < 4; reg++) {
      int rr = row0 + w*16 + quad*4 + reg;
      if (rr < n) pd[(size_t)rr*HID + col0 + ct*16 + mr] = acc[ct][reg];
    }
  }
}

__global__ __launch_bounds__(256)
void k_reduce_sk(const float* __restrict__ part, float* __restrict__ outp, int n){
  int i = blockIdx.x*256 + threadIdx.x;
  if (i >= n*HID) return;
  float s = 0.0f;
  #pragma unroll
  for (int z = 0; z < SPLITK; z++) s += part[(size_t)z*n*HID + i];
  outp[i] = s;
}

// ---------------- batched GATv2: wave-per-dst, register-cached att/gr ------
struct GatJob { const unsigned short* gl; const unsigned short* gr;
                const int* rowptr; const int* col;
                const float* att; const float* bias; float* out; int ndst; int accum; };
struct GatJobs { GatJob j[3]; int bo[4]; };  // bo = cumulative block offsets

__global__ __launch_bounds__(256, 3)
void k_gat_all(GatJobs jobs)
{
  int bx = blockIdx.x;
  int jz = 0;
  if (bx >= jobs.bo[1]) jz = 1;
  if (bx >= jobs.bo[2]) jz = 2;
  GatJob jb = jobs.j[jz];
  int tid = threadIdx.x;
  int w = tid >> 6, lane = tid & 63;
  int dst = (bx - jobs.bo[jz])*4 + w;
  if (dst >= jb.ndst) return;   // no barriers anywhere: waves fully independent
  __shared__ float swS[4][4][16];
  __shared__ int   sidxS[4][16];
  __shared__ float fS[4][4];
  __shared__ float lS[4][4];

  int h16 = lane >> 4, j16 = lane & 15;
  // register-cache att slice (12x float4) and gr slice (6x short8) for my head
  float attR[48], grR[48];
  {
    const float4* av = (const float4*)(jb.att + h16*CDIM);
    #pragma unroll
    for (int i = 0; i < 12; i++) {
      float4 v = av[i];
      attR[4*i+0] = v.x; attR[4*i+1] = v.y; attR[4*i+2] = v.z; attR[4*i+3] = v.w;
    }
    const short8* gv = (const short8*)(jb.gr + (size_t)dst*HID + h16*CDIM);
    #pragma unroll
    for (int i = 0; i < 6; i++) {
      short8 g8 = gv[i];
      #pragma unroll
      for (int jj = 0; jj < 8; jj++) grR[8*i+jj] = bf2f((unsigned short)g8[jj]);
    }
  }

  int start = jb.rowptr[dst], end = jb.rowptr[dst+1];
  float m = -1e30f, l = 0.0f;
  float acc0 = 0.f, acc1 = 0.f, acc2 = 0.f;
  int hd0 = lane/48, hd1 = (lane+64)/48, hd2 = (lane+128)/48;

  for (int c0 = start; c0 < end; c0 += 16) {
    int nc = min(16, end - c0);
    float sc = -1e30f; int s = -1;
    if (j16 < nc) {
      s = jb.col[c0 + j16];
      const short8* glv = (const short8*)(jb.gl + (size_t)s*HID + h16*CDIM);
      float a = 0.0f;
      #pragma unroll
      for (int v8 = 0; v8 < 6; v8++) {
        short8 g8 = glv[v8];
        #pragma unroll
        for (int jj = 0; jj < 8; jj++) {
          float v = bf2f((unsigned short)g8[jj]) + grR[v8*8+jj];
          v = v > 0.0f ? v : 0.2f*v;
          a += v * attR[v8*8+jj];
        }
      }
      sc = a;
    }
    if (h16 == 0) sidxS[w][j16] = s;
    float cm = sc;
    cm = fmaxf(cm, __shfl_xor(cm, 1));
    cm = fmaxf(cm, __shfl_xor(cm, 2));
    cm = fmaxf(cm, __shfl_xor(cm, 4));
    cm = fmaxf(cm, __shfl_xor(cm, 8));
    float nm = fmaxf(m, cm);
    float f = __expf(m - nm);          // m=-1e30 -> 0
    l *= f;
    float e = (j16 < nc) ? __expf(sc - nm) : 0.0f;
    swS[w][h16][j16] = e;
    float cl = e;
    cl += __shfl_xor(cl, 1);
    cl += __shfl_xor(cl, 2);
    cl += __shfl_xor(cl, 4);
    cl += __shfl_xor(cl, 8);
    l += cl;
    m = nm;
    if (j16 == 0) fS[w][h16] = f;
    acc0 *= fS[w][hd0]; acc1 *= fS[w][hd1]; acc2 *= fS[w][hd2];
    for (int j = 0; j < nc; j++) {
      const unsigned short* glr = jb.gl + (size_t)sidxS[w][j]*HID;
      acc0 += swS[w][hd0][j] * bf2f(glr[lane]);
      acc1 += swS[w][hd1][j] * bf2f(glr[lane+64]);
      acc2 += swS[w][hd2][j] * bf2f(glr[lane+128]);
    }
  }
  if (j16 == 0) lS[w][h16] = l;
  float* od = jb.out + (size_t)dst*HID;
  float v0 = acc0 / (lS[w][hd0] + 1e-16f) + jb.bias[lane];
  float v1 = acc1 / (lS[w][hd1] + 1e-16f) + jb.bias[lane+64];
  float v2 = acc2 / (lS[w][hd2] + 1e-16f) + jb.bias[lane+128];
  if (jb.accum) { v0 += od[lane]; v1 += od[lane+64]; v2 += od[lane+128]; }
  od[lane] = v0; od[lane+64] = v1; od[lane+128] = v2;
}

// ---------------- batched residual + LayerNorm (3 node types) -------------
__global__ __launch_bounds__(64)
void k_ln3(float* __restrict__ xs, const float* __restrict__ osb,
           float* __restrict__ xg, const float* __restrict__ og,
           float* __restrict__ xp, const float* __restrict__ opb,
           const float* __restrict__ op2,
           const float* __restrict__ LNg, const float* __restrict__ LNb, int l)
{
  int r = blockIdx.x;
  float* x; const float* d1; const float* d2 = nullptr; int typ;
  if (r < N_S)            { x = xs + (size_t)r*HID; d1 = osb + (size_t)r*HID; typ = 0; }
  else if (r < N_S + N_G) { int rr = r - N_S; x = xg + (size_t)rr*HID; d1 = og + (size_t)rr*HID; typ = 1; }
  else                    { int rr = r - N_S - N_G; x = xp + (size_t)rr*HID; d1 = opb + (size_t)rr*HID;
                            d2 = op2 + (size_t)rr*HID; typ = 2; }
  const float* g = LNg + (l*3 + typ)*HID;
  const float* b = LNb + (l*3 + typ)*HID;
  int lane = threadIdx.x;
  float v[3]; float sum = 0.0f;
  #pragma unroll
  for (int j=0;j<3;j++){
    int d = j*64 + lane;
    float t = x[d] + d1[d];
    if (d2) t += d2[d];
    v[j] = t; sum += t;
  }
  #pragma unroll
  for (int o=32;o;o>>=1) sum += __shfl_xor(sum, o);
  float mu = sum * (1.0f/HID);
  float var = 0.0f;
  #pragma unroll
  for (int j=0;j<3;j++){ float dd = v[j]-mu; var += dd*dd; }
  #pragma unroll
  for (int o=32;o;o>>=1) var += __shfl_xor(var, o);
  var *= (1.0f/HID);
  float inv = rsqrtf(var + 1e-5f);
  #pragma unroll
  for (int j=0;j<3;j++){
    int d = j*64 + lane;
    x[d] = (v[j]-mu)*inv*g[d] + b[d];
  }
}

// ---------------- pooling attention: one block per (q,h) ----------------
__global__ __launch_bounds__(256)
void k_pool_attn(const float* __restrict__ qb, const float* __restrict__ kb,
                 const float* __restrict__ vb, float* __restrict__ ob)
{
  int h = blockIdx.x & 3;
  int q = blockIdx.x >> 2;
  __shared__ float prob[N_S];
  __shared__ float red[256];
  int t = threadIdx.x;
  const float* qrow = qb + (size_t)q*HID + h*CDIM;
  const float scale = 0.14433756729740643f;
  for (int n = t; n < N_S; n += 256) {
    const float* krow = kb + (size_t)n*HID + h*CDIM;
    float s = 0.0f;
    #pragma unroll 8
    for (int c=0;c<CDIM;c++) s += qrow[c]*krow[c];
    prob[n] = s * scale;
  }
  __syncthreads();
  float m = -1e30f;
  for (int n=t;n<N_S;n+=256) m = fmaxf(m, prob[n]);
  red[t] = m; __syncthreads();
  for (int s2=128;s2;s2>>=1){ if (t<s2) red[t]=fmaxf(red[t],red[t+s2]); __syncthreads(); }
  m = red[0]; __syncthreads();
  float sum = 0.0f;
  for (int n=t;n<N_S;n+=256){ float e=__expf(prob[n]-m); prob[n]=e; sum+=e; }
  red[t] = sum; __syncthreads();
  for (int s2=128;s2;s2>>=1){ if (t<s2) red[t]+=red[t+s2]; __syncthreads(); }
  float inv = 1.0f/red[0];
  __syncthreads();
  if (t < CDIM) {
    float acc = 0.0f;
    for (int n=0;n<N_S;n++) acc += prob[n]*vb[(size_t)n*HID + h*CDIM + t];
    ob[(size_t)q*HID + h*CDIM + t] = acc * inv;
  }
}

// ---------------- tail ----------------
__global__ __launch_bounds__(192)
void k_tail(const float* __restrict__ ob2,
            const float* ffw1, const float* ffb1,
            const float* ffw2, const float* ffb2,
            const float* lng, const float* lnb,
            const float* pw, const float* pb,
            void* __restrict__ outp, const int* __restrict__ flag)
{
  __shared__ float pooled[HID];
  __shared__ float hh[HID];
  __shared__ float stats[2];
  int t = threadIdx.x;
  float a = 0.0f;
  for (int q=0;q<NQd;q++) a += ob2[q*HID + t];
  pooled[t] = a * (1.0f/NQd);
  __syncthreads();
  float s1 = ffb1[t];
  for (int k=0;k<HID;k++) s1 += pooled[k]*ffw1[t*HID+k];
  hh[t] = fmaxf(s1, 0.0f);
  __syncthreads();
  float s2 = ffb2[t];
  for (int k=0;k<HID;k++) s2 += hh[k]*ffw2[t*HID+k];
  __syncthreads();
  hh[t] = s2;
  __syncthreads();
  if (t == 0) {
    float mu=0.0f; for (int k=0;k<HID;k++) mu += hh[k];
    mu *= (1.0f/HID);
    float v=0.0f; for (int k=0;k<HID;k++){ float d=hh[k]-mu; v+=d*d; }
    v *= (1.0f/HID);
    stats[0]=mu; stats[1]=rsqrtf(v + 1e-5f);
  }
  __syncthreads();
  pooled[t] = (hh[t]-stats[0])*stats[1]*lng[t] + lnb[t];
  __syncthreads();
  if (t < OUTD) {
    float acc = pb[t];
    for (int k=0;k<HID;k++) acc += pooled[k]*pw[t*HID+k];
    if (flag[0]) ((float*)outp)[t] = acc;
    else         ((unsigned short*)outp)[t] = f2bf(acc);
  }
}

// =====================================================================
extern "C" void kernel_launch(void* const* d_in, const int* in_sizes, int n_in,
                              void* d_out, int out_size, void* d_ws, size_t ws_size,
                              hipStream_t stream)
{
  const int* sg_src = (const int*)d_in[3];
  const int* sg_dst = (const int*)d_in[4];
  const int* gp_src = (const int*)d_in[5];
  const int* gp_dst = (const int*)d_in[6];
  const int* pp_src = (const int*)d_in[7];
  const int* pp_dst = (const int*)d_in[8];

  float* base = (float*)d_ws;
  size_t off = 0;
  auto alloc = [&](size_t nf){ nf = (nf + 3) & ~(size_t)3; float* p = base + off; off += nf; return p; };
  int*   flag = (int*)alloc(4);
  float* xs   = alloc((size_t)N_S*HID);
  float* xg   = alloc((size_t)N_G*HID);
  float* xp   = alloc((size_t)N_P*HID);
  float* qin  = alloc((size_t)NQd*HID);
  float* Wsl  = alloc(2*2*HID*HID); float* bsl = alloc(2*2*HID); float* Wsr = alloc(2*2*HID*HID);
  float* Wgl  = alloc(2*3*HID*HID); float* bgl = alloc(2*3*HID);
  float* Wgr  = alloc(2*3*HID*HID); float* bgr = alloc(2*3*HID);
  float* Agat = alloc(2*3*HEADS*CDIM); float* Bgat = alloc(2*3*HID);
  float* LNg  = alloc(2*3*HID); float* LNb = alloc(2*3*HID);
  float* Pinw = alloc(3*HID*HID); float* Pinb = alloc(3*HID);
  float* Poutw= alloc(HID*HID);   float* Poutb= alloc(HID);
  float* Fw1  = alloc(HID*HID);   float* Fb1  = alloc(HID);
  float* Fw2  = alloc(HID*HID);   float* Fb2  = alloc(HID);
  float* PLg  = alloc(HID);       float* PLb  = alloc(HID);
  float* Pw   = alloc(OUTD*HID);  float* Pb   = alloc(OUTD);
  // runtime buffers
  float* agg  = alloc((size_t)N_G*HID);
  float* aggS = alloc((size_t)N_S*HID);
  float* og   = alloc((size_t)N_G*HID);
  float* osb  = alloc((size_t)N_S*HID);
  float* opb  = alloc((size_t)N_P*HID);
  float* op2  = alloc((size_t)N_P*HID);
  // bf16 GAT node transforms
  unsigned short* glGb  = (unsigned short*)alloc((size_t)N_G*HID/2);
  unsigned short* grGb  = (unsigned short*)alloc((size_t)N_G*HID/2);
  unsigned short* grP0b = (unsigned short*)alloc((size_t)N_P*HID/2);
  unsigned short* glP1b = (unsigned short*)alloc((size_t)N_P*HID/2);
  unsigned short* glP2b = (unsigned short*)alloc((size_t)N_P*HID/2);
  unsigned short* grP2b = (unsigned short*)alloc((size_t)N_P*HID/2);
  float* qbuf = alloc((size_t)NQd*HID);
  float* kbuf = alloc((size_t)N_S*HID);
  float* vbuf = alloc((size_t)N_S*HID);
  float* obuf = alloc((size_t)NQd*HID);
  float* ob2  = alloc((size_t)NQd*HID);
  // dense SAGE matrices
  int*            CntGi = (int*)alloc((size_t)N_G*N_S);
  unsigned short* CntGb = (unsigned short*)alloc((size_t)N_G*N_S/2);
  unsigned short* CntSb = (unsigned short*)alloc((size_t)N_S*LDK/2);
  unsigned short* xsTb  = (unsigned short*)alloc((size_t)HID*N_S/2);
  unsigned short* xgTb  = (unsigned short*)alloc((size_t)HID*LDK/2);
  float* part = alloc((size_t)SPLITK*N_S*HID);
  float* invdegG = alloc(N_G);
  float* invdegS = alloc(N_S);
  // CSR storage (GAT graphs)
  int* degAll = (int*)alloc(2*N_P + N_G + 4);
  int* curAll = (int*)alloc(2*N_P + N_G + 4);
  int* rp_gp_p = (int*)alloc(N_P+2);  int* col_gp_p = (int*)alloc(NE_GP);
  int* rp_gp_g = (int*)alloc(N_G+2);  int* col_gp_g = (int*)alloc(NE_GP);
  int* rp_pp_p = (int*)alloc(N_P+2);  int* col_pp_p = (int*)alloc(NE_PP);
  (void)ws_size; (void)in_sizes; (void)n_in; (void)out_size;

  k_detect<<<1,256,0,stream>>>((const unsigned int*)d_in[0], flag);

  // ---- batched input conversion ----
  {
    LoadTable tab;
    int k = 0;
    auto add = [&](int i, float* dst, int n){ tab.d[k].src = d_in[i]; tab.d[k].dst = dst; tab.d[k].n = n; k++; };
    add(0,  xs,  N_S*HID);  add(1,  xg,  N_G*HID);  add(2,  xp,  N_P*HID);
    add(9,  Wsl, 2*2*HID*HID); add(10, bsl, 2*2*HID); add(11, Wsr, 2*2*HID*HID);
    add(12, Wgl, 2*3*HID*HID); add(13, bgl, 2*3*HID);
    add(14, Wgr, 2*3*HID*HID); add(15, bgr, 2*3*HID);
    add(16, Agat, 2*3*HEADS*CDIM); add(17, Bgat, 2*3*HID);
    add(18, LNg, 2*3*HID); add(19, LNb, 2*3*HID);
    add(20, qin, NQd*HID);
    add(21, Pinw, 3*HID*HID); add(22, Pinb, 3*HID);
    add(23, Poutw, HID*HID);  add(24, Poutb, HID);
    add(25, Fw1, HID*HID); add(26, Fb1, HID);
    add(27, Fw2, HID*HID); add(28, Fb2, HID);
    add(29, PLg, HID); add(30, PLb, HID);
    add(31, Pw, OUTD*HID); add(32, Pb, OUTD);
    k_load_all<<<dim3(LOADBX, NLOAD),256,0,stream>>>(tab, flag);
  }

  // ---- dense SAGE counts ----
  hipMemsetAsync(CntGi, 0, (size_t)N_G*N_S*4, stream);
  hipMemsetAsync(degAll, 0, (size_t)(2*N_P + N_G)*4, stream);
  k_cntbuild<<<(NE_SG+255)/256,256,0,stream>>>(sg_src, sg_dst, CntGi, NE_SG);
  k_cvtT<<<dim3(LDK/64, N_S/64),256,0,stream>>>(CntGi, CntGb, CntSb);
  k_rowinv_i<<<(N_G+3)/4,256,0,stream>>>(CntGi, N_S, N_S, N_G, invdegG);
  k_rowinv_h<<<(N_S+3)/4,256,0,stream>>>(CntSb, LDK, LDK, N_S, invdegS);

  // ---- batched CSR build for the 3 GAT graphs ----
  {
    CsrJobs jobs;
    jobs.j[0] = { gp_src, gp_dst, NE_GP, N_P, degAll,           rp_gp_p, curAll,           col_gp_p };
    jobs.j[1] = { gp_dst, gp_src, NE_GP, N_G, degAll+N_P,       rp_gp_g, curAll+N_P,       col_gp_g };
    jobs.j[2] = { pp_src, pp_dst, NE_PP, N_P, degAll+N_P+N_G,   rp_pp_p, curAll+N_P+N_G,   col_pp_p };
    k_hist3<<<dim3((NE_GP+255)/256, 3),256,0,stream>>>(jobs);
    k_scan3<<<3,256,0,stream>>>(jobs);
    k_fill3<<<dim3((NE_GP+255)/256, 3),256,0,stream>>>(jobs);
  }

  const int RB_G = (N_G+63)/64, RB_P = (N_P+63)/64;       // 181, 32
  const int GB_P = (N_P+3)/4,  GB_G = (N_G+3)/4;          // 500, 2890

  for (int l=0; l<2; l++) {
    // both feature transposes in one dispatch
    {
      TransJobs tj;
      tj.inA = xs; tj.outA = xsTb; tj.nA = N_S; tj.ldoA = N_S; tj.rbA = 8;
      tj.inB = xg; tj.outB = xgTb; tj.nB = N_G; tj.ldoB = LDK;
      k_transpose2<<<dim3(8 + LDK/64, 3),256,0,stream>>>(tj);
    }
    // SAGE s->g
    k_gemm_g<<<dim3(RB_G,3),256,0,stream>>>(CntGb, N_S, xsTb, N_S, agg, N_G, N_S);
    k_gemm2<<<dim3(RB_G,3),256,0,stream>>>(agg, invdegG,
        Wsl + (size_t)(l*2+0)*HID*HID, xg, Wsr + (size_t)(l*2+0)*HID*HID,
        bsl + (l*2+0)*HID, og, N_G);

    // SAGE g->s
    k_gemm_sk<<<dim3(8,3,SPLITK),256,0,stream>>>(CntSb, LDK, xgTb, LDK, part, N_S);
    k_reduce_sk<<<(N_S*HID+255)/256,256,0,stream>>>(part, aggS, N_S);
    k_gemm2<<<dim3((N_S+63)/64,3),256,0,stream>>>(aggS, invdegS,
        Wsl + (size_t)(l*2+1)*HID*HID, xs, Wsr + (size_t)(l*2+1)*HID*HID,
        bsl + (l*2+1)*HID, osb, N_S);

    // GAT: 6 node transforms in one flat dispatch (bf16 outputs)
    {
      GemmJobs gj;
      int w0 = l*3+0, w1 = l*3+1, w2 = l*3+2;
      gj.j[0] = { xg, Wgl + (size_t)w0*HID*HID, bgl + w0*HID, glGb,  N_G };
      gj.j[1] = { xp, Wgr + (size_t)w0*HID*HID, bgr + w0*HID, grP0b, N_P };
      gj.j[2] = { xp, Wgl + (size_t)w1*HID*HID, bgl + w1*HID, glP1b, N_P };
      gj.j[3] = { xg, Wgr + (size_t)w1*HID*HID, bgr + w1*HID, grGb,  N_G };
      gj.j[4] = { xp, Wgl + (size_t)w2*HID*HID, bgl + w2*HID, glP2b, N_P };
      gj.j[5] = { xp, Wgr + (size_t)w2*HID*HID, bgr + w2*HID, grP2b, N_P };
      int nrb[6] = { RB_G, RB_P, RB_P, RB_G, RB_P, RB_P };
      gj.rb[0] = 0;
      for (int q = 0; q < 6; q++) gj.rb[q+1] = gj.rb[q] + nrb[q];
      k_gemm6<<<dim3(gj.rb[6],3),256,0,stream>>>(gj);
    }
    // GAT: 3 edge passes in one flat dispatch (wave-per-destination)
    {
      GatJobs gt;
      int w0 = l*3+0, w1 = l*3+1, w2 = l*3+2;
      gt.j[0] = { glGb,  grP0b, rp_gp_p, col_gp_p, Agat + (size_t)w0*HID, Bgat + (size_t)w0*HID, opb, N_P, 0 };
      gt.j[1] = { glP1b, grGb,  rp_gp_g, col_gp_g, Agat + (size_t)w1*HID, Bgat + (size_t)w1*HID, og,  N_G, 1 };
      gt.j[2] = { glP2b, grP2b, rp_pp_p, col_pp_p, Agat + (size_t)w2*HID, Bgat + (size_t)w2*HID, op2, N_P, 0 };
      gt.bo[0] = 0; gt.bo[1] = GB_P; gt.bo[2] = GB_P + GB_G; gt.bo[3] = GB_P + GB_G + GB_P;
      k_gat_all<<<dim3(gt.bo[3]),256,0,stream>>>(gt);
    }
    // residual + LN, all node types in one dispatch
    k_ln3<<<N_S+N_G+N_P,64,0,stream>>>(xs, osb, xg, og, xp, opb, op2, LNg, LNb, l);
  }

  // ---- pooling: q/k/v in one dispatch ----
  {
    PoolJobs pj;
    pj.j[0] = { qin, Pinw,                     Pinb,         qbuf, NQd };
    pj.j[1] = { xs,  Pinw + (size_t)HID*HID,   Pinb + HID,   kbuf, N_S };
    pj.j[2] = { xs,  Pinw + (size_t)2*HID*HID, Pinb + 2*HID, vbuf, N_S };
    pj.rb[0] = 0; pj.rb[1] = 1; pj.rb[2] = 1 + (N_S+63)/64; pj.rb[3] = pj.rb[2] + (N_S+63)/64;
    k_gemm3<<<dim3(pj.rb[3],3),256,0,stream>>>(pj);
  }
  k_pool_attn<<<NQd*HEADS,256,0,stream>>>(qbuf, kbuf, vbuf, obuf);
  k_gemm<<<dim3(1,3),256,0,stream>>>(obuf, nullptr, Poutw, Poutb, ob2, NQd, 0);
  k_tail<<<1,HID,0,stream>>>(ob2, Fw1, Fb1, Fw2, Fb2, PLg, PLb, Pw, Pb, d_out, flag);
}

// Round 12
// 730.654 us; speedup vs baseline: 1.0618x; 1.0618x over previous
//
#include <hip/hip_runtime.h>

#define N_S 512
#define N_G 11560
#define N_P 2000
#define NE_SG 1000000
#define NE_GP 200000
#define NE_PP 50000
#define HID 192
#define HEADS 4
#define CDIM 48
#define NQd 20
#define OUTD 128
#define LDK 12288
#define SPLITK 16
#define CHUNKK 768

typedef __attribute__((ext_vector_type(8))) short short8;
typedef __attribute__((ext_vector_type(4))) float float4v;

__device__ __forceinline__ float bf2f(unsigned short u){
  union { unsigned int i; float f; } x; x.i = ((unsigned int)u) << 16; return x.f;
}
__device__ __forceinline__ unsigned short f2bf(float f){
  union { float f; unsigned int i; } u; u.f = f;
  unsigned int r = u.i + 0x7FFFu + ((u.i >> 16) & 1u);
  return (unsigned short)(r >> 16);
}
__device__ __forceinline__ ushort4 f4bf(float4 v){
  return make_ushort4(f2bf(v.x), f2bf(v.y), f2bf(v.z), f2bf(v.w));
}

// ---------------- dtype detection (flag=1 fp32, flag=0 bf16) ----------------
__global__ __launch_bounds__(256) void k_detect(const unsigned int* __restrict__ raw,
                                                int* __restrict__ flag){
  __shared__ int cnt;
  if (threadIdx.x == 0) cnt = 0;
  __syncthreads();
  int c = 0;
  for (int i = threadIdx.x; i < 2048; i += 256) {
    float f = __uint_as_float(raw[i]);
    float a = fabsf(f);
    if (f == f && a > 1e-4f && a < 1000.0f) c++;
  }
  atomicAdd(&cnt, c);
  __syncthreads();
  if (threadIdx.x == 0) flag[0] = (cnt >= 1024) ? 1 : 0;
}

// ---------------- batched input load (27 tensors, grid-stride) ----------
#define NLOAD 27
#define LOADBX 2048
struct LoadDesc { const void* src; float* dst; int n; };
struct LoadTable { LoadDesc d[NLOAD]; };
__global__ __launch_bounds__(256)
void k_load_all(LoadTable tab, const int* __restrict__ flag){
  LoadDesc de = tab.d[blockIdx.y];
  int fp32 = flag[0];
  for (int i = blockIdx.x*256 + threadIdx.x; i < de.n; i += LOADBX*256) {
    if (fp32) de.dst[i] = ((const float*)de.src)[i];
    else      de.dst[i] = bf2f(((const unsigned short*)de.src)[i]);
  }
}

// ---------------- dense count matrix (CntG only; CntS derived) -------------
__global__ __launch_bounds__(256)
void k_cntbuild(const int* __restrict__ src, const int* __restrict__ dst,
                int* __restrict__ cg, int E){
  int i = blockIdx.x*256 + threadIdx.x;
  if (i >= E) return;
  atomicAdd(&cg[(size_t)dst[i]*N_S + src[i]], 1);
}

// convert CntG(int)->bf16 and write transposed bf16 CntS [512 x LDK] (zero-pad)
__global__ __launch_bounds__(256)
void k_cvtT(const int* __restrict__ cg, unsigned short* __restrict__ bfA,
            unsigned short* __restrict__ bfB){
  __shared__ unsigned short tile[64][68];
  int g0 = blockIdx.x*64, s0 = blockIdx.y*64;
  int t = threadIdx.x; int r = t>>2, seg = t&3;
  int g = g0 + r;
  if (g < N_G) {
    const int* row = cg + (size_t)g*N_S + s0 + seg*16;
    unsigned short* arow = bfA + (size_t)g*N_S + s0 + seg*16;
    #pragma unroll
    for (int i=0;i<16;i++){
      unsigned short v = f2bf((float)row[i]);
      tile[r][seg*16+i] = v;
      arow[i] = v;
    }
  } else {
    #pragma unroll
    for (int i=0;i<16;i++) tile[r][seg*16+i] = 0;
  }
  __syncthreads();
  int s = s0 + r;
  unsigned short* brow = bfB + (size_t)s*LDK + g0 + seg*16;
  #pragma unroll
  for (int i=0;i<16;i++) brow[i] = tile[seg*16+i][r];
}

__global__ __launch_bounds__(256)
void k_rowinv_i(const int* __restrict__ A, int lda, int cols, int n,
                float* __restrict__ outp){
  int row = blockIdx.x*4 + (threadIdx.x >> 6);
  if (row >= n) return;
  int lane = threadIdx.x & 63;
  const int* Ar = A + (size_t)row*lda;
  float s = 0.0f;
  for (int c = lane; c < cols; c += 64) s += (float)Ar[c];
  #pragma unroll
  for (int o = 32; o; o >>= 1) s += __shfl_xor(s, o);
  if (lane == 0) outp[row] = 1.0f / fmaxf(s, 1.0f);
}
__global__ __launch_bounds__(256)
void k_rowinv_h(const unsigned short* __restrict__ A, int lda, int cols, int n,
                float* __restrict__ outp){
  int row = blockIdx.x*4 + (threadIdx.x >> 6);
  if (row >= n) return;
  int lane = threadIdx.x & 63;
  const unsigned short* Ar = A + (size_t)row*lda;
  float s = 0.0f;
  for (int c = lane; c < cols; c += 64) s += bf2f(Ar[c]);
  #pragma unroll
  for (int o = 32; o; o >>= 1) s += __shfl_xor(s, o);
  if (lane == 0) outp[row] = 1.0f / fmaxf(s, 1.0f);
}

// ---------------- dual transpose [n x 192] fp32 -> [192 x ldo] bf16 --------
struct TransJobs { const float* inA; unsigned short* outA; int nA; int ldoA; int rbA;
                   const float* inB; unsigned short* outB; int nB; int ldoB; };
__global__ __launch_bounds__(256)
void k_transpose2(TransJobs tj){
  const float* in; unsigned short* outp; int n, ldo, r0;
  int bx = blockIdx.x;
  if (bx < tj.rbA) { in = tj.inA; outp = tj.outA; n = tj.nA; ldo = tj.ldoA; r0 = bx*64; }
  else             { in = tj.inB; outp = tj.outB; n = tj.nB; ldo = tj.ldoB; r0 = (bx - tj.rbA)*64; }
  __shared__ float tile[64][65];
  int c0 = blockIdx.y*64;
  int t = threadIdx.x;
  int r = t >> 2, seg = t & 3;
  int grr = r0 + r;
  if (grr < n) {
    #pragma unroll
    for (int i = 0; i < 4; i++) {
      float4 v = *(const float4*)(in + (size_t)grr*HID + c0 + seg*16 + i*4);
      tile[r][seg*16+i*4+0] = v.x; tile[r][seg*16+i*4+1] = v.y;
      tile[r][seg*16+i*4+2] = v.z; tile[r][seg*16+i*4+3] = v.w;
    }
  } else {
    #pragma unroll
    for (int i = 0; i < 16; i++) tile[r][seg*16+i] = 0.0f;
  }
  __syncthreads();
  int w = t >> 6, lane = t & 63;
  if (r0 + lane < ldo) {
    #pragma unroll
    for (int j = 0; j < 16; j++) {
      int c = w*16 + j;
      outp[(size_t)(c0+c)*ldo + r0 + lane] = f2bf(tile[lane][c]);
    }
  }
}

// ---------------- batched CSR build (3 graphs) ----------------
struct CsrJob { const int* src; const int* dst; int E; int n;
                int* deg; int* rowptr; int* cursor; int* col; };
struct CsrJobs { CsrJob j[3]; };

__global__ __launch_bounds__(256) void k_hist3(CsrJobs jobs){
  CsrJob jb = jobs.j[blockIdx.y];
  int i = blockIdx.x*256 + threadIdx.x;
  if (i < jb.E) atomicAdd(&jb.deg[jb.dst[i]], 1);
}
__global__ __launch_bounds__(256) void k_scan3(CsrJobs jobs){
  CsrJob jb = jobs.j[blockIdx.x];
  __shared__ int part[256];
  __shared__ int pre[256];
  int t = threadIdx.x;
  int n = jb.n;
  int C = (n + 255) >> 8;
  int lo = t*C, hi = min(n, lo + C);
  int s = 0;
  for (int i = lo; i < hi; i++) s += jb.deg[i];
  part[t] = s;
  __syncthreads();
  if (t == 0) {
    int acc = 0;
    for (int i = 0; i < 256; i++) { pre[i] = acc; acc += part[i]; }
    jb.rowptr[n] = acc;
  }
  __syncthreads();
  int run = pre[t];
  for (int i = lo; i < hi; i++) {
    jb.rowptr[i] = run; jb.cursor[i] = run; run += jb.deg[i];
  }
}
__global__ __launch_bounds__(256) void k_fill3(CsrJobs jobs){
  CsrJob jb = jobs.j[blockIdx.y];
  int i = blockIdx.x*256 + threadIdx.x;
  if (i >= jb.E) return;
  int pos = atomicAdd(&jb.cursor[jb.dst[i]], 1);
  jb.col[pos] = jb.src[i];
}

// ---------------- MFMA bf16 GEMM (K=192, fp32 A/W): out (+)= A·W^T (+bias) --
#define LDA 200
__global__ __launch_bounds__(256)
void k_gemm(const float* __restrict__ A, const float* __restrict__ rowscale,
            const float* __restrict__ W, const float* __restrict__ bias,
            float* __restrict__ outp, int n, int accum)
{
  __shared__ __align__(16) unsigned short Asm[64*LDA];
  __shared__ __align__(16) unsigned short Wsm[64*LDA];
  int t = threadIdx.x;
  int row0 = blockIdx.x * 64;
  int col0 = blockIdx.y * 64;
  {
    int r = t >> 2, seg = t & 3;
    int gr = row0 + r;
    unsigned short* ad = Asm + r*LDA + seg*48;
    if (gr < n) {
      float sc = rowscale ? rowscale[gr] : 1.0f;
      const float* Ar = A + (size_t)gr*HID + seg*48;
      #pragma unroll
      for (int i = 0; i < 12; i++) {
        float4 v = *reinterpret_cast<const float4*>(Ar + i*4);
        v.x *= sc; v.y *= sc; v.z *= sc; v.w *= sc;
        *reinterpret_cast<ushort4*>(ad + i*4) = f4bf(v);
      }
    } else {
      ushort4 z = make_ushort4(0,0,0,0);
      #pragma unroll
      for (int i = 0; i < 12; i++) *reinterpret_cast<ushort4*>(ad + i*4) = z;
    }
    const float* Wr = W + (size_t)(col0 + r)*HID + seg*48;
    unsigned short* wd = Wsm + r*LDA + seg*48;
    #pragma unroll
    for (int i = 0; i < 12; i++) {
      float4 v = *reinterpret_cast<const float4*>(Wr + i*4);
      *reinterpret_cast<ushort4*>(wd + i*4) = f4bf(v);
    }
  }
  __syncthreads();
  int w = t >> 6, lane = t & 63;
  int quad = lane >> 4, mr = lane & 15;
  float4v acc[4] = {};
  const unsigned short* Abase = Asm + (w*16 + mr)*LDA + quad*8;
  const unsigned short* Wbase = Wsm + mr*LDA + quad*8;
  #pragma unroll
  for (int k0 = 0; k0 < 6; k0++) {
    short8 a = *reinterpret_cast<const short8*>(Abase + k0*32);
    #pragma unroll
    for (int ct = 0; ct < 4; ct++) {
      short8 b = *reinterpret_cast<const short8*>(Wbase + ct*16*LDA + k0*32);
      acc[ct] = __builtin_amdgcn_mfma_f32_16x16x32_bf16(a, b, acc[ct], 0, 0, 0);
    }
  }
  #pragma unroll
  for (int ct = 0; ct < 4; ct++) {
    #pragma unroll
    for (int reg = 0; reg < 4; reg++) {
      int rr = row0 + w*16 + quad*4 + reg;
      if (rr < n) {
        int cc = col0 + ct*16 + mr;
        float v = acc[ct][reg];
        if (bias) v += bias[cc];
        if (accum) v += outp[(size_t)rr*HID + cc];
        outp[(size_t)rr*HID + cc] = v;
      }
    }
  }
}

// ---------------- batched K=192 GEMM (6 jobs, bf16 out, flat grid) ---------
struct GemmJob { const float* A; const float* W; const float* bias;
                 unsigned short* out; int n; };
struct GemmJobs { GemmJob j[6]; int rb[7]; };
__global__ __launch_bounds__(256)
void k_gemm6(GemmJobs jobs)
{
  int bx = blockIdx.x;
  int z = 0;
  #pragma unroll
  for (int q = 1; q < 6; q++) if (bx >= jobs.rb[q]) z = q;
  GemmJob jb = jobs.j[z];
  int row0 = (bx - jobs.rb[z]) * 64;
  __shared__ __align__(16) unsigned short Asm[64*LDA];
  __shared__ __align__(16) unsigned short Wsm[64*LDA];
  int t = threadIdx.x;
  int col0 = blockIdx.y * 64;
  {
    int r = t >> 2, seg = t & 3;
    int gr = row0 + r;
    unsigned short* ad = Asm + r*LDA + seg*48;
    if (gr < jb.n) {
      const float* Ar = jb.A + (size_t)gr*HID + seg*48;
      #pragma unroll
      for (int i = 0; i < 12; i++) {
        float4 v = *reinterpret_cast<const float4*>(Ar + i*4);
        *reinterpret_cast<ushort4*>(ad + i*4) = f4bf(v);
      }
    } else {
      ushort4 zz = make_ushort4(0,0,0,0);
      #pragma unroll
      for (int i = 0; i < 12; i++) *reinterpret_cast<ushort4*>(ad + i*4) = zz;
    }
    const float* Wr = jb.W + (size_t)(col0 + r)*HID + seg*48;
    unsigned short* wd = Wsm + r*LDA + seg*48;
    #pragma unroll
    for (int i = 0; i < 12; i++) {
      float4 v = *reinterpret_cast<const float4*>(Wr + i*4);
      *reinterpret_cast<ushort4*>(wd + i*4) = f4bf(v);
    }
  }
  __syncthreads();
  int w = t >> 6, lane = t & 63;
  int quad = lane >> 4, mr = lane & 15;
  float4v acc[4] = {};
  const unsigned short* Abase = Asm + (w*16 + mr)*LDA + quad*8;
  const unsigned short* Wbase = Wsm + mr*LDA + quad*8;
  #pragma unroll
  for (int k0 = 0; k0 < 6; k0++) {
    short8 a = *reinterpret_cast<const short8*>(Abase + k0*32);
    #pragma unroll
    for (int ct = 0; ct < 4; ct++) {
      short8 b = *reinterpret_cast<const short8*>(Wbase + ct*16*LDA + k0*32);
      acc[ct] = __builtin_amdgcn_mfma_f32_16x16x32_bf16(a, b, acc[ct], 0, 0, 0);
    }
  }
  #pragma unroll
  for (int ct = 0; ct < 4; ct++) {
    #pragma unroll
    for (int reg = 0; reg < 4; reg++) {
      int rr = row0 + w*16 + quad*4 + reg;
      if (rr < jb.n) {
        int cc = col0 + ct*16 + mr;
        jb.out[(size_t)rr*HID + cc] = f2bf(acc[ct][reg] + jb.bias[cc]);
      }
    }
  }
}

// ---------------- batched K=192 GEMM (3 jobs, fp32 out) — pooling q/k/v ----
struct PoolJob { const float* A; const float* W; const float* bias;
                 float* out; int n; };
struct PoolJobs { PoolJob j[3]; int rb[4]; };
__global__ __launch_bounds__(256)
void k_gemm3(PoolJobs jobs)
{
  int bx = blockIdx.x;
  int z = 0;
  if (bx >= jobs.rb[1]) z = 1;
  if (bx >= jobs.rb[2]) z = 2;
  PoolJob jb = jobs.j[z];
  int row0 = (bx - jobs.rb[z]) * 64;
  __shared__ __align__(16) unsigned short Asm[64*LDA];
  __shared__ __align__(16) unsigned short Wsm[64*LDA];
  int t = threadIdx.x;
  int col0 = blockIdx.y * 64;
  {
    int r = t >> 2, seg = t & 3;
    int gr = row0 + r;
    unsigned short* ad = Asm + r*LDA + seg*48;
    if (gr < jb.n) {
      const float* Ar = jb.A + (size_t)gr*HID + seg*48;
      #pragma unroll
      for (int i = 0; i < 12; i++) {
        float4 v = *reinterpret_cast<const float4*>(Ar + i*4);
        *reinterpret_cast<ushort4*>(ad + i*4) = f4bf(v);
      }
    } else {
      ushort4 zz = make_ushort4(0,0,0,0);
      #pragma unroll
      for (int i = 0; i < 12; i++) *reinterpret_cast<ushort4*>(ad + i*4) = zz;
    }
    const float* Wr = jb.W + (size_t)(col0 + r)*HID + seg*48;
    unsigned short* wd = Wsm + r*LDA + seg*48;
    #pragma unroll
    for (int i = 0; i < 12; i++) {
      float4 v = *reinterpret_cast<const float4*>(Wr + i*4);
      *reinterpret_cast<ushort4*>(wd + i*4) = f4bf(v);
    }
  }
  __syncthreads();
  int w = t >> 6, lane = t & 63;
  int quad = lane >> 4, mr = lane & 15;
  float4v acc[4] = {};
  const unsigned short* Abase = Asm + (w*16 + mr)*LDA + quad*8;
  const unsigned short* Wbase = Wsm + mr*LDA + quad*8;
  #pragma unroll
  for (int k0 = 0; k0 < 6; k0++) {
    short8 a = *reinterpret_cast<const short8*>(Abase + k0*32);
    #pragma unroll
    for (int ct = 0; ct < 4; ct++) {
      short8 b = *reinterpret_cast<const short8*>(Wbase + ct*16*LDA + k0*32);
      acc[ct] = __builtin_amdgcn_mfma_f32_16x16x32_bf16(a, b, acc[ct], 0, 0, 0);
    }
  }
  #pragma unroll
  for (int ct = 0; ct < 4; ct++) {
    #pragma unroll
    for (int reg = 0; reg < 4; reg++) {
      int rr = row0 + w*16 + quad*4 + reg;
      if (rr < jb.n) {
        int cc = col0 + ct*16 + mr;
        jb.out[(size_t)rr*HID + cc] = acc[ct][reg] + jb.bias[cc];
      }
    }
  }
}

// ---------------- fused dual GEMM: out = A1·W1^T (rowscaled) + A2·W2^T + bias
__global__ __launch_bounds__(256)
void k_gemm2(const float* __restrict__ A1, const float* __restrict__ rs1,
             const float* __restrict__ W1,
             const float* __restrict__ A2, const float* __restrict__ W2,
             const float* __restrict__ bias,
             float* __restrict__ outp, int n)
{
  __shared__ __align__(16) unsigned short Asm[64*LDA];
  __shared__ __align__(16) unsigned short Wsm[64*LDA];
  int t = threadIdx.x;
  int row0 = blockIdx.x * 64;
  int col0 = blockIdx.y * 64;
  int r = t >> 2, seg = t & 3;
  int w = t >> 6, lane = t & 63;
  int quad = lane >> 4, mr = lane & 15;
  float4v acc[4] = {};
  for (int p = 0; p < 2; p++) {
    if (p) __syncthreads();
    const float* A = p ? A2 : A1;
    const float* W = p ? W2 : W1;
    {
      int gr = row0 + r;
      unsigned short* ad = Asm + r*LDA + seg*48;
      if (gr < n) {
        float sc = (!p && rs1) ? rs1[gr] : 1.0f;
        const float* Ar = A + (size_t)gr*HID + seg*48;
        #pragma unroll
        for (int i = 0; i < 12; i++) {
          float4 v = *reinterpret_cast<const float4*>(Ar + i*4);
          v.x *= sc; v.y *= sc; v.z *= sc; v.w *= sc;
          *reinterpret_cast<ushort4*>(ad + i*4) = f4bf(v);
        }
      } else {
        ushort4 z = make_ushort4(0,0,0,0);
        #pragma unroll
        for (int i = 0; i < 12; i++) *reinterpret_cast<ushort4*>(ad + i*4) = z;
      }
      const float* Wr = W + (size_t)(col0 + r)*HID + seg*48;
      unsigned short* wd = Wsm + r*LDA + seg*48;
      #pragma unroll
      for (int i = 0; i < 12; i++) {
        float4 v = *reinterpret_cast<const float4*>(Wr + i*4);
        *reinterpret_cast<ushort4*>(wd + i*4) = f4bf(v);
      }
    }
    __syncthreads();
    const unsigned short* Abase = Asm + (w*16 + mr)*LDA + quad*8;
    const unsigned short* Wbase = Wsm + mr*LDA + quad*8;
    #pragma unroll
    for (int k0 = 0; k0 < 6; k0++) {
      short8 a = *reinterpret_cast<const short8*>(Abase + k0*32);
      #pragma unroll
      for (int ct = 0; ct < 4; ct++) {
        short8 b = *reinterpret_cast<const short8*>(Wbase + ct*16*LDA + k0*32);
        acc[ct] = __builtin_amdgcn_mfma_f32_16x16x32_bf16(a, b, acc[ct], 0, 0, 0);
      }
    }
  }
  #pragma unroll
  for (int ct = 0; ct < 4; ct++) {
    #pragma unroll
    for (int reg = 0; reg < 4; reg++) {
      int rr = row0 + w*16 + quad*4 + reg;
      if (rr < n) {
        int cc = col0 + ct*16 + mr;
        outp[(size_t)rr*HID + cc] = acc[ct][reg] + bias[cc];
      }
    }
  }
}

// ---------------- general-K MFMA GEMM, bf16 inputs ----------------
#define BKG 128
#define LDG 136
__global__ __launch_bounds__(256)
void k_gemm_g(const unsigned short* __restrict__ A, int lda,
              const unsigned short* __restrict__ W, int ldw,
              float* __restrict__ outp, int n, int K)
{
  __shared__ __align__(16) unsigned short Asm[64*LDG];
  __shared__ __align__(16) unsigned short Wsm[64*LDG];
  int t = threadIdx.x;
  int row0 = blockIdx.x * 64;
  int col0 = blockIdx.y * 64;
  int r = t >> 2, seg = t & 3;
  int w = t >> 6, lane = t & 63;
  int quad = lane >> 4, mr = lane & 15;
  float4v acc[4] = {};
  for (int k0 = 0; k0 < K; k0 += BKG) {
    {
      int gr = row0 + r;
      unsigned short* ad = Asm + r*LDG + seg*32;
      if (gr < n) {
        const unsigned short* Ar = A + (size_t)gr*lda + k0 + seg*32;
        #pragma unroll
        for (int i = 0; i < 4; i++) *(uint4*)(ad + i*8) = *(const uint4*)(Ar + i*8);
      } else {
        uint4 z = make_uint4(0,0,0,0);
        #pragma unroll
        for (int i = 0; i < 4; i++) *(uint4*)(ad + i*8) = z;
      }
      const unsigned short* Wr = W + (size_t)(col0 + r)*ldw + k0 + seg*32;
      unsigned short* wd = Wsm + r*LDG + seg*32;
      #pragma unroll
      for (int i = 0; i < 4; i++) *(uint4*)(wd + i*8) = *(const uint4*)(Wr + i*8);
    }
    __syncthreads();
    const unsigned short* Abase = Asm + (w*16 + mr)*LDG + quad*8;
    const unsigned short* Wbase = Wsm + mr*LDG + quad*8;
    #pragma unroll
    for (int kk = 0; kk < 4; kk++) {
      short8 a = *(const short8*)(Abase + kk*32);
      #pragma unroll
      for (int ct = 0; ct < 4; ct++) {
        short8 b = *(const short8*)(Wbase + ct*16*LDG + kk*32);
        acc[ct] = __builtin_amdgcn_mfma_f32_16x16x32_bf16(a, b, acc[ct], 0, 0, 0);
      }
    }
    __syncthreads();
  }
  #pragma unroll
  for (int ct = 0; ct < 4; ct++) {
    #pragma unroll
    for (int reg = 0; reg < 4; reg++) {
      int rr = row0 + w*16 + quad*4 + reg;
      if (rr < n) outp[(size_t)rr*HID + col0 + ct*16 + mr] = acc[ct][reg];
    }
  }
}

// ---------------- split-K MFMA GEMM, bf16 inputs ----------------
__global__ __launch_bounds__(256)
void k_gemm_sk(const unsigned short* __restrict__ A, int lda,
               const unsigned short* __restrict__ W, int ldw,
               float* __restrict__ part, int n)
{
  __shared__ __align__(16) unsigned short Asm[64*LDG];
  __shared__ __align__(16) unsigned short Wsm[64*LDG];
  int t = threadIdx.x;
  int row0 = blockIdx.x * 64;
  int col0 = blockIdx.y * 64;
  int kz   = blockIdx.z;
  int kbeg = kz * CHUNKK;
  int r = t >> 2, seg = t & 3;
  int w = t >> 6, lane = t & 63;
  int quad = lane >> 4, mr = lane & 15;
  float4v acc[4] = {};
  for (int k0 = kbeg; k0 < kbeg + CHUNKK; k0 += BKG) {
    {
      int gr = row0 + r;
      unsigned short* ad = Asm + r*LDG + seg*32;
      if (gr < n) {
        const unsigned short* Ar = A + (size_t)gr*lda + k0 + seg*32;
        #pragma unroll
        for (int i = 0; i < 4; i++) *(uint4*)(ad + i*8) = *(const uint4*)(Ar + i*8);
      } else {
        uint4 z = make_uint4(0,0,0,0);
        #pragma unroll
        for (int i = 0; i < 4; i++) *(uint4*)(ad + i*8) = z;
      }
      const unsigned short* Wr = W + (size_t)(col0 + r)*ldw + k0 + seg*32;
      unsigned short* wd = Wsm + r*LDG + seg*32;
      #pragma unroll
      for (int i = 0; i < 4; i++) *(uint4*)(wd + i*8) = *(const uint4*)(Wr + i*8);
    }
    __syncthreads();
    const unsigned short* Abase = Asm + (w*16 + mr)*LDG + quad*8;
    const unsigned short* Wbase = Wsm + mr*LDG + quad*8;
    #pragma unroll
    for (int kk = 0; kk < 4; kk++) {
      short8 a = *(const short8*)(Abase + kk*32);
      #pragma unroll
      for (int ct = 0; ct < 4; ct++) {
        short8 b = *(const short8*)(Wbase + ct*16*LDG + kk*32);
        acc[ct] = __builtin_amdgcn_mfma_f32_16x16x32_bf16(a, b, acc[ct], 0, 0, 0);
      }
    }
    __syncthreads();
  }
  float* pd = part + (size_t)kz*n*HID;
  #pragma unroll
  for (int ct = 0; ct < 4; ct++) {
    #pragma unroll
    for (int reg = 0; reg < 4; reg++) {
      int rr = row0 + w*16 + quad*4 + reg;
      if (rr < n) pd[(size_t)rr*HID + col0 + ct*16 + mr] = acc[ct][reg];
    }
  }
}

__global__ __launch_bounds__(256)
void k_reduce_sk(const float* __restrict__ part, float* __restrict__ outp, int n){
  int i = blockIdx.x*256 + threadIdx.x;
  if (i >= n*HID) return;
  float s = 0.0f;
  #pragma unroll
  for (int z = 0; z < SPLITK; z++) s += part[(size_t)z*n*HID + i];
  outp[i] = s;
}

// ---------------- batched GATv2: wave-per-dst, LDS att/gr, short8 loads ----
struct GatJob { const unsigned short* gl; const unsigned short* gr;
                const int* rowptr; const int* col;
                const float* att; const float* bias; float* out; int ndst; int accum; };
struct GatJobs { GatJob j[3]; int bo[4]; };

__global__ __launch_bounds__(256)
void k_gat_all(GatJobs jobs)
{
  int bx = blockIdx.x;
  int jz = 0;
  if (bx >= jobs.bo[1]) jz = 1;
  if (bx >= jobs.bo[2]) jz = 2;
  GatJob jb = jobs.j[jz];
  int tid = threadIdx.x;
  int w = tid >> 6, lane = tid & 63;
  int dst = (bx - jobs.bo[jz])*4 + w;
  bool active = dst < jb.ndst;
  __shared__ float attS[HID];
  __shared__ float grS[4][HID];
  __shared__ float swS[4][4][16];
  __shared__ int   sidxS[4][16];
  __shared__ float fS[4][4];
  __shared__ float lS[4][4];
  if (tid < HID) attS[tid] = jb.att[tid];
  if (active) {
    const unsigned short* grr = jb.gr + (size_t)dst*HID;
    grS[w][lane]     = bf2f(grr[lane]);
    grS[w][lane+64]  = bf2f(grr[lane+64]);
    grS[w][lane+128] = bf2f(grr[lane+128]);
  }
  __syncthreads();   // attS visibility (all 256 threads reach this)
  if (!active) return;

  int h16 = lane >> 4, j16 = lane & 15;
  int start = jb.rowptr[dst], end = jb.rowptr[dst+1];
  float m = -1e30f, l = 0.0f;
  float acc0 = 0.f, acc1 = 0.f, acc2 = 0.f;
  int hd0 = lane/48, hd1 = (lane+64)/48, hd2 = (lane+128)/48;
  const float* attH = attS + h16*CDIM;
  const float* grH  = grS[w] + h16*CDIM;

  for (int c0 = start; c0 < end; c0 += 16) {
    int nc = min(16, end - c0);
    float sc = -1e30f; int s = -1;
    if (j16 < nc) {
      s = jb.col[c0 + j16];
      const short8* glv = (const short8*)(jb.gl + (size_t)s*HID + h16*CDIM);
      float a = 0.0f;
      #pragma unroll
      for (int v8 = 0; v8 < 6; v8++) {
        short8 g8 = glv[v8];
        #pragma unroll
        for (int jj = 0; jj < 8; jj++) {
          float v = bf2f((unsigned short)g8[jj]) + grH[v8*8+jj];
          v = v > 0.0f ? v : 0.2f*v;
          a += v * attH[v8*8+jj];
        }
      }
      sc = a;
    }
    if (h16 == 0) sidxS[w][j16] = s;
    float cm = sc;
    cm = fmaxf(cm, __shfl_xor(cm, 1));
    cm = fmaxf(cm, __shfl_xor(cm, 2));
    cm = fmaxf(cm, __shfl_xor(cm, 4));
    cm = fmaxf(cm, __shfl_xor(cm, 8));
    float nm = fmaxf(m, cm);
    float f = __expf(m - nm);          // m=-1e30 -> 0
    l *= f;
    float e = (j16 < nc) ? __expf(sc - nm) : 0.0f;
    swS[w][h16][j16] = e;
    float cl = e;
    cl += __shfl_xor(cl, 1);
    cl += __shfl_xor(cl, 2);
    cl += __shfl_xor(cl, 4);
    cl += __shfl_xor(cl, 8);
    l += cl;
    m = nm;
    if (j16 == 0) fS[w][h16] = f;
    acc0 *= fS[w][hd0]; acc1 *= fS[w][hd1]; acc2 *= fS[w][hd2];
    for (int j = 0; j < nc; j++) {
      const unsigned short* glr = jb.gl + (size_t)sidxS[w][j]*HID;
      acc0 += swS[w][hd0][j] * bf2f(glr[lane]);
      acc1 += swS[w][hd1][j] * bf2f(glr[lane+64]);
      acc2 += swS[w][hd2][j] * bf2f(glr[lane+128]);
    }
  }
  if (j16 == 0) lS[w][h16] = l;
  float* od = jb.out + (size_t)dst*HID;
  float v0 = acc0 / (lS[w][hd0] + 1e-16f) + jb.bias[lane];
  float v1 = acc1 / (lS[w][hd1] + 1e-16f) + jb.bias[lane+64];
  float v2 = acc2 / (lS[w][hd2] + 1e-16f) + jb.bias[lane+128];
  if (jb.accum) { v0 += od[lane]; v1 += od[lane+64]; v2 += od[lane+128]; }
  od[lane] = v0; od[lane+64] = v1; od[lane+128] = v2;
}

// ---------------- batched residual + LayerNorm (3 node types) -------------
__global__ __launch_bounds__(64)
void k_ln3(float* __restrict__ xs, const float* __restrict__ osb,
           float* __restrict__ xg, const float* __restrict__ og,
           float* __restrict__ xp, const float* __restrict__ opb,
           const float* __restrict__ op2,
           const float* __restrict__ LNg, const float* __restrict__ LNb, int l)
{
  int r = blockIdx.x;
  float* x; const float* d1; const float* d2 = nullptr; int typ;
  if (r < N_S)            { x = xs + (size_t)r*HID; d1 = osb + (size_t)r*HID; typ = 0; }
  else if (r < N_S + N_G) { int rr = r - N_S; x = xg + (size_t)rr*HID; d1 = og + (size_t)rr*HID; typ = 1; }
  else                    { int rr = r - N_S - N_G; x = xp + (size_t)rr*HID; d1 = opb + (size_t)rr*HID;
                            d2 = op2 + (size_t)rr*HID; typ = 2; }
  const float* g = LNg + (l*3 + typ)*HID;
  const float* b = LNb + (l*3 + typ)*HID;
  int lane = threadIdx.x;
  float v[3]; float sum = 0.0f;
  #pragma unroll
  for (int j=0;j<3;j++){
    int d = j*64 + lane;
    float t = x[d] + d1[d];
    if (d2) t += d2[d];
    v[j] = t; sum += t;
  }
  #pragma unroll
  for (int o=32;o;o>>=1) sum += __shfl_xor(sum, o);
  float mu = sum * (1.0f/HID);
  float var = 0.0f;
  #pragma unroll
  for (int j=0;j<3;j++){ float dd = v[j]-mu; var += dd*dd; }
  #pragma unroll
  for (int o=32;o;o>>=1) var += __shfl_xor(var, o);
  var *= (1.0f/HID);
  float inv = rsqrtf(var + 1e-5f);
  #pragma unroll
  for (int j=0;j<3;j++){
    int d = j*64 + lane;
    x[d] = (v[j]-mu)*inv*g[d] + b[d];
  }
}

// ---------------- pooling attention: one block per (q,h) ----------------
__global__ __launch_bounds__(256)
void k_pool_attn(const float* __restrict__ qb, const float* __restrict__ kb,
                 const float* __restrict__ vb, float* __restrict__ ob)
{
  int h = blockIdx.x & 3;
  int q = blockIdx.x >> 2;
  __shared__ float prob[N_S];
  __shared__ float red[256];
  int t = threadIdx.x;
  const float* qrow = qb + (size_t)q*HID + h*CDIM;
  const float scale = 0.14433756729740643f;
  for (int n = t; n < N_S; n += 256) {
    const float* krow = kb + (size_t)n*HID + h*CDIM;
    float s = 0.0f;
    #pragma unroll 8
    for (int c=0;c<CDIM;c++) s += qrow[c]*krow[c];
    prob[n] = s * scale;
  }
  __syncthreads();
  float m = -1e30f;
  for (int n=t;n<N_S;n+=256) m = fmaxf(m, prob[n]);
  red[t] = m; __syncthreads();
  for (int s2=128;s2;s2>>=1){ if (t<s2) red[t]=fmaxf(red[t],red[t+s2]); __syncthreads(); }
  m = red[0]; __syncthreads();
  float sum = 0.0f;
  for (int n=t;n<N_S;n+=256){ float e=__expf(prob[n]-m); prob[n]=e; sum+=e; }
  red[t] = sum; __syncthreads();
  for (int s2=128;s2;s2>>=1){ if (t<s2) red[t]+=red[t+s2]; __syncthreads(); }
  float inv = 1.0f/red[0];
  __syncthreads();
  if (t < CDIM) {
    float acc = 0.0f;
    for (int n=0;n<N_S;n++) acc += prob[n]*vb[(size_t)n*HID + h*CDIM + t];
    ob[(size_t)q*HID + h*CDIM + t] = acc * inv;
  }
}

// ---------------- tail ----------------
__global__ __launch_bounds__(192)
void k_tail(const float* __restrict__ ob2,
            const float* ffw1, const float* ffb1,
            const float* ffw2, const float* ffb2,
            const float* lng, const float* lnb,
            const float* pw, const float* pb,
            void* __restrict__ outp, const int* __restrict__ flag)
{
  __shared__ float pooled[HID];
  __shared__ float hh[HID];
  __shared__ float stats[2];
  int t = threadIdx.x;
  float a = 0.0f;
  for (int q=0;q<NQd;q++) a += ob2[q*HID + t];
  pooled[t] = a * (1.0f/NQd);
  __syncthreads();
  float s1 = ffb1[t];
  for (int k=0;k<HID;k++) s1 += pooled[k]*ffw1[t*HID+k];
  hh[t] = fmaxf(s1, 0.0f);
  __syncthreads();
  float s2 = ffb2[t];
  for (int k=0;k<HID;k++) s2 += hh[k]*ffw2[t*HID+k];
  __syncthreads();
  hh[t] = s2;
  __syncthreads();
  if (t == 0) {
    float mu=0.0f; for (int k=0;k<HID;k++) mu += hh[k];
    mu *= (1.0f/HID);
    float v=0.0f; for (int k=0;k<HID;k++){ float d=hh[k]-mu; v+=d*d; }
    v *= (1.0f/HID);
    stats[0]=mu; stats[1]=rsqrtf(v + 1e-5f);
  }
  __syncthreads();
  pooled[t] = (hh[t]-stats[0])*stats[1]*lng[t] + lnb[t];
  __syncthreads();
  if (t < OUTD) {
    float acc = pb[t];
    for (int k=0;k<HID;k++) acc += pooled[k]*pw[t*HID+k];
    if (flag[0]) ((float*)outp)[t] = acc;
    else         ((unsigned short*)outp)[t] = f2bf(acc);
  }
}

// =====================================================================
extern "C" void kernel_launch(void* const* d_in, const int* in_sizes, int n_in,
                              void* d_out, int out_size, void* d_ws, size_t ws_size,
                              hipStream_t stream)
{
  const int* sg_src = (const int*)d_in[3];
  const int* sg_dst = (const int*)d_in[4];
  const int* gp_src = (const int*)d_in[5];
  const int* gp_dst = (const int*)d_in[6];
  const int* pp_src = (const int*)d_in[7];
  const int* pp_dst = (const int*)d_in[8];

  float* base = (float*)d_ws;
  size_t off = 0;
  auto alloc = [&](size_t nf){ nf = (nf + 3) & ~(size_t)3; float* p = base + off; off += nf; return p; };
  int*   flag = (int*)alloc(4);
  float* xs   = alloc((size_t)N_S*HID);
  float* xg   = alloc((size_t)N_G*HID);
  float* xp   = alloc((size_t)N_P*HID);
  float* qin  = alloc((size_t)NQd*HID);
  float* Wsl  = alloc(2*2*HID*HID); float* bsl = alloc(2*2*HID); float* Wsr = alloc(2*2*HID*HID);
  float* Wgl  = alloc(2*3*HID*HID); float* bgl = alloc(2*3*HID);
  float* Wgr  = alloc(2*3*HID*HID); float* bgr = alloc(2*3*HID);
  float* Agat = alloc(2*3*HEADS*CDIM); float* Bgat = alloc(2*3*HID);
  float* LNg  = alloc(2*3*HID); float* LNb = alloc(2*3*HID);
  float* Pinw = alloc(3*HID*HID); float* Pinb = alloc(3*HID);
  float* Poutw= alloc(HID*HID);   float* Poutb= alloc(HID);
  float* Fw1  = alloc(HID*HID);   float* Fb1  = alloc(HID);
  float* Fw2  = alloc(HID*HID);   float* Fb2  = alloc(HID);
  float* PLg  = alloc(HID);       float* PLb  = alloc(HID);
  float* Pw   = alloc(OUTD*HID);  float* Pb   = alloc(OUTD);
  // runtime buffers
  float* agg  = alloc((size_t)N_G*HID);
  float* aggS = alloc((size_t)N_S*HID);
  float* og   = alloc((size_t)N_G*HID);
  float* osb  = alloc((size_t)N_S*HID);
  float* opb  = alloc((size_t)N_P*HID);
  float* op2  = alloc((size_t)N_P*HID);
  // bf16 GAT node transforms
  unsigned short* glGb  = (unsigned short*)alloc((size_t)N_G*HID/2);
  unsigned short* grGb  = (unsigned short*)alloc((size_t)N_G*HID/2);
  unsigned short* grP0b = (unsigned short*)alloc((size_t)N_P*HID/2);
  unsigned short* glP1b = (unsigned short*)alloc((size_t)N_P*HID/2);
  unsigned short* glP2b = (unsigned short*)alloc((size_t)N_P*HID/2);
  unsigned short* grP2b = (unsigned short*)alloc((size_t)N_P*HID/2);
  float* qbuf = alloc((size_t)NQd*HID);
  float* kbuf = alloc((size_t)N_S*HID);
  float* vbuf = alloc((size_t)N_S*HID);
  float* obuf = alloc((size_t)NQd*HID);
  float* ob2  = alloc((size_t)NQd*HID);
  // dense SAGE matrices
  int*            CntGi = (int*)alloc((size_t)N_G*N_S);
  unsigned short* CntGb = (unsigned short*)alloc((size_t)N_G*N_S/2);
  unsigned short* CntSb = (unsigned short*)alloc((size_t)N_S*LDK/2);
  unsigned short* xsTb  = (unsigned short*)alloc((size_t)HID*N_S/2);
  unsigned short* xgTb  = (unsigned short*)alloc((size_t)HID*LDK/2);
  float* part = alloc((size_t)SPLITK*N_S*HID);
  float* invdegG = alloc(N_G);
  float* invdegS = alloc(N_S);
  // CSR storage (GAT graphs)
  int* degAll = (int*)alloc(2*N_P + N_G + 4);
  int* curAll = (int*)alloc(2*N_P + N_G + 4);
  int* rp_gp_p = (int*)alloc(N_P+2);  int* col_gp_p = (int*)alloc(NE_GP);
  int* rp_gp_g = (int*)alloc(N_G+2);  int* col_gp_g = (int*)alloc(NE_GP);
  int* rp_pp_p = (int*)alloc(N_P+2);  int* col_pp_p = (int*)alloc(NE_PP);
  (void)ws_size; (void)in_sizes; (void)n_in; (void)out_size;

  k_detect<<<1,256,0,stream>>>((const unsigned int*)d_in[0], flag);

  // ---- batched input conversion ----
  {
    LoadTable tab;
    int k = 0;
    auto add = [&](int i, float* dst, int n){ tab.d[k].src = d_in[i]; tab.d[k].dst = dst; tab.d[k].n = n; k++; };
    add(0,  xs,  N_S*HID);  add(1,  xg,  N_G*HID);  add(2,  xp,  N_P*HID);
    add(9,  Wsl, 2*2*HID*HID); add(10, bsl, 2*2*HID); add(11, Wsr, 2*2*HID*HID);
    add(12, Wgl, 2*3*HID*HID); add(13, bgl, 2*3*HID);
    add(14, Wgr, 2*3*HID*HID); add(15, bgr, 2*3*HID);
    add(16, Agat, 2*3*HEADS*CDIM); add(17, Bgat, 2*3*HID);
    add(18, LNg, 2*3*HID); add(19, LNb, 2*3*HID);
    add(20, qin, NQd*HID);
    add(21, Pinw, 3*HID*HID); add(22, Pinb, 3*HID);
    add(23, Poutw, HID*HID);  add(24, Poutb, HID);
    add(25, Fw1, HID*HID); add(26, Fb1, HID);
    add(27, Fw2, HID*HID); add(28, Fb2, HID);
    add(29, PLg, HID); add(30, PLb, HID);
    add(31, Pw, OUTD*HID); add(32, Pb, OUTD);
    k_load_all<<<dim3(LOADBX, NLOAD),256,0,stream>>>(tab, flag);
  }

  // ---- dense SAGE counts ----
  hipMemsetAsync(CntGi, 0, (size_t)N_G*N_S*4, stream);
  hipMemsetAsync(degAll, 0, (size_t)(2*N_P + N_G)*4, stream);
  k_cntbuild<<<(NE_SG+255)/256,256,0,stream>>>(sg_src, sg_dst, CntGi, NE_SG);
  k_cvtT<<<dim3(LDK/64, N_S/64),256,0,stream>>>(CntGi, CntGb, CntSb);
  k_rowinv_i<<<(N_G+3)/4,256,0,stream>>>(CntGi, N_S, N_S, N_G, invdegG);
  k_rowinv_h<<<(N_S+3)/4,256,0,stream>>>(CntSb, LDK, LDK, N_S, invdegS);

  // ---- batched CSR build for the 3 GAT graphs ----
  {
    CsrJobs jobs;
    jobs.j[0] = { gp_src, gp_dst, NE_GP, N_P, degAll,           rp_gp_p, curAll,           col_gp_p };
    jobs.j[1] = { gp_dst, gp_src, NE_GP, N_G, degAll+N_P,       rp_gp_g, curAll+N_P,       col_gp_g };
    jobs.j[2] = { pp_src, pp_dst, NE_PP, N_P, degAll+N_P+N_G,   rp_pp_p, curAll+N_P+N_G,   col_pp_p };
    k_hist3<<<dim3((NE_GP+255)/256, 3),256,0,stream>>>(jobs);
    k_scan3<<<3,256,0,stream>>>(jobs);
    k_fill3<<<dim3((NE_GP+255)/256, 3),256,0,stream>>>(jobs);
  }

  const int RB_G = (N_G+63)/64, RB_P = (N_P+63)/64;       // 181, 32
  const int GB_P = (N_P+3)/4,  GB_G = (N_G+3)/4;          // 500, 2890

  for (int l=0; l<2; l++) {
    // both feature transposes in one dispatch
    {
      TransJobs tj;
      tj.inA = xs; tj.outA = xsTb; tj.nA = N_S; tj.ldoA = N_S; tj.rbA = 8;
      tj.inB = xg; tj.outB = xgTb; tj.nB = N_G; tj.ldoB = LDK;
      k_transpose2<<<dim3(8 + LDK/64, 3),256,0,stream>>>(tj);
    }
    // SAGE s->g
    k_gemm_g<<<dim3(RB_G,3),256,0,stream>>>(CntGb, N_S, xsTb, N_S, agg, N_G, N_S);
    k_gemm2<<<dim3(RB_G,3),256,0,stream>>>(agg, invdegG,
        Wsl + (size_t)(l*2+0)*HID*HID, xg, Wsr + (size_t)(l*2+0)*HID*HID,
        bsl + (l*2+0)*HID, og, N_G);

    // SAGE g->s
    k_gemm_sk<<<dim3(8,3,SPLITK),256,0,stream>>>(CntSb, LDK, xgTb, LDK, part, N_S);
    k_reduce_sk<<<(N_S*HID+255)/256,256,0,stream>>>(part, aggS, N_S);
    k_gemm2<<<dim3((N_S+63)/64,3),256,0,stream>>>(aggS, invdegS,
        Wsl + (size_t)(l*2+1)*HID*HID, xs, Wsr + (size_t)(l*2+1)*HID*HID,
        bsl + (l*2+1)*HID, osb, N_S);

    // GAT: 6 node transforms in one flat dispatch (bf16 outputs)
    {
      GemmJobs gj;
      int w0 = l*3+0, w1 = l*3+1, w2 = l*3+2;
      gj.j[0] = { xg, Wgl + (size_t)w0*HID*HID, bgl + w0*HID, glGb,  N_G };
      gj.j[1] = { xp, Wgr + (size_t)w0*HID*HID, bgr + w0*HID, grP0b, N_P };
      gj.j[2] = { xp, Wgl + (size_t)w1*HID*HID, bgl + w1*HID, glP1b, N_P };
      gj.j[3] = { xg, Wgr + (size_t)w1*HID*HID, bgr + w1*HID, grGb,  N_G };
      gj.j[4] = { xp, Wgl + (size_t)w2*HID*HID, bgl + w2*HID, glP2b, N_P };
      gj.j[5] = { xp, Wgr + (size_t)w2*HID*HID, bgr + w2*HID, grP2b, N_P };
      int nrb[6] = { RB_G, RB_P, RB_P, RB_G, RB_P, RB_P };
      gj.rb[0] = 0;
      for (int q = 0; q < 6; q++) gj.rb[q+1] = gj.rb[q] + nrb[q];
      k_gemm6<<<dim3(gj.rb[6],3),256,0,stream>>>(gj);
    }
    // GAT: 3 edge passes in one flat dispatch (wave-per-destination)
    {
      GatJobs gt;
      int w0 = l*3+0, w1 = l*3+1, w2 = l*3+2;
      gt.j[0] = { glGb,  grP0b, rp_gp_p, col_gp_p, Agat + (size_t)w0*HID, Bgat + (size_t)w0*HID, opb, N_P, 0 };
      gt.j[1] = { glP1b, grGb,  rp_gp_g, col_gp_g, Agat + (size_t)w1*HID, Bgat + (size_t)w1*HID, og,  N_G, 1 };
      gt.j[2] = { glP2b, grP2b, rp_pp_p, col_pp_p, Agat + (size_t)w2*HID, Bgat + (size_t)w2*HID, op2, N_P, 0 };
      gt.bo[0] = 0; gt.bo[1] = GB_P; gt.bo[2] = GB_P + GB_G; gt.bo[3] = GB_P + GB_G + GB_P;
      k_gat_all<<<dim3(gt.bo[3]),256,0,stream>>>(gt);
    }
    // residual + LN, all node types in one dispatch
    k_ln3<<<N_S+N_G+N_P,64,0,stream>>>(xs, osb, xg, og, xp, opb, op2, LNg, LNb, l);
  }

  // ---- pooling: q/k/v in one dispatch ----
  {
    PoolJobs pj;
    pj.j[0] = { qin, Pinw,                     Pinb,         qbuf, NQd };
    pj.j[1] = { xs,  Pinw + (size_t)HID*HID,   Pinb + HID,   kbuf, N_S };
    pj.j[2] = { xs,  Pinw + (size_t)2*HID*HID, Pinb + 2*HID, vbuf, N_S };
    pj.rb[0] = 0; pj.rb[1] = 1; pj.rb[2] = 1 + (N_S+63)/64; pj.rb[3] = pj.rb[2] + (N_S+63)/64;
    k_gemm3<<<dim3(pj.rb[3],3),256,0,stream>>>(pj);
  }
  k_pool_attn<<<NQd*HEADS,256,0,stream>>>(qbuf, kbuf, vbuf, obuf);
  k_gemm<<<dim3(1,3),256,0,stream>>>(obuf, nullptr, Poutw, Poutb, ob2, NQd, 0);
  k_tail<<<1,HID,0,stream>>>(ob2, Fw1, Fb1, Fw2, Fb2, PLg, PLb, Pw, Pb, d_out, flag);
}

// Round 13
// 688.306 us; speedup vs baseline: 1.1271x; 1.0615x over previous
//
#include <hip/hip_runtime.h>

#define N_S 512
#define N_G 11560
#define N_P 2000
#define NE_SG 1000000
#define NE_GP 200000
#define NE_PP 50000
#define HID 192
#define HEADS 4
#define CDIM 48
#define NQd 20
#define OUTD 128
#define LDK 12288
#define SPLITK 16
#define CHUNKK 768

typedef __attribute__((ext_vector_type(8))) short short8;
typedef __attribute__((ext_vector_type(4))) float float4v;

__device__ __forceinline__ float bf2f(unsigned short u){
  union { unsigned int i; float f; } x; x.i = ((unsigned int)u) << 16; return x.f;
}
__device__ __forceinline__ unsigned short f2bf(float f){
  union { float f; unsigned int i; } u; u.f = f;
  unsigned int r = u.i + 0x7FFFu + ((u.i >> 16) & 1u);
  return (unsigned short)(r >> 16);
}
__device__ __forceinline__ ushort4 f4bf(float4 v){
  return make_ushort4(f2bf(v.x), f2bf(v.y), f2bf(v.z), f2bf(v.w));
}

// ---------------- dtype detection (flag=1 fp32, flag=0 bf16) ----------------
__global__ __launch_bounds__(256) void k_detect(const unsigned int* __restrict__ raw,
                                                int* __restrict__ flag){
  __shared__ int cnt;
  if (threadIdx.x == 0) cnt = 0;
  __syncthreads();
  int c = 0;
  for (int i = threadIdx.x; i < 2048; i += 256) {
    float f = __uint_as_float(raw[i]);
    float a = fabsf(f);
    if (f == f && a > 1e-4f && a < 1000.0f) c++;
  }
  atomicAdd(&cnt, c);
  __syncthreads();
  if (threadIdx.x == 0) flag[0] = (cnt >= 1024) ? 1 : 0;
}

// ---------------- batched input load (27 tensors, grid-stride) ----------
#define NLOAD 27
#define LOADBX 2048
struct LoadDesc { const void* src; float* dst; int n; };
struct LoadTable { LoadDesc d[NLOAD]; };
__global__ __launch_bounds__(256)
void k_load_all(LoadTable tab, const int* __restrict__ flag){
  LoadDesc de = tab.d[blockIdx.y];
  int fp32 = flag[0];
  for (int i = blockIdx.x*256 + threadIdx.x; i < de.n; i += LOADBX*256) {
    if (fp32) de.dst[i] = ((const float*)de.src)[i];
    else      de.dst[i] = bf2f(((const unsigned short*)de.src)[i]);
  }
}

// ---------------- dense count matrix (CntG only; CntS derived) -------------
__global__ __launch_bounds__(256)
void k_cntbuild(const int* __restrict__ src, const int* __restrict__ dst,
                int* __restrict__ cg, int E){
  int i = blockIdx.x*256 + threadIdx.x;
  if (i >= E) return;
  atomicAdd(&cg[(size_t)dst[i]*N_S + src[i]], 1);
}

// convert CntG(int)->bf16 and write transposed bf16 CntS [512 x LDK] (zero-pad)
__global__ __launch_bounds__(256)
void k_cvtT(const int* __restrict__ cg, unsigned short* __restrict__ bfA,
            unsigned short* __restrict__ bfB){
  __shared__ unsigned short tile[64][68];
  int g0 = blockIdx.x*64, s0 = blockIdx.y*64;
  int t = threadIdx.x; int r = t>>2, seg = t&3;
  int g = g0 + r;
  if (g < N_G) {
    const int* row = cg + (size_t)g*N_S + s0 + seg*16;
    unsigned short* arow = bfA + (size_t)g*N_S + s0 + seg*16;
    #pragma unroll
    for (int i=0;i<16;i++){
      unsigned short v = f2bf((float)row[i]);
      tile[r][seg*16+i] = v;
      arow[i] = v;
    }
  } else {
    #pragma unroll
    for (int i=0;i<16;i++) tile[r][seg*16+i] = 0;
  }
  __syncthreads();
  int s = s0 + r;
  unsigned short* brow = bfB + (size_t)s*LDK + g0 + seg*16;
  #pragma unroll
  for (int i=0;i<16;i++) brow[i] = tile[seg*16+i][r];
}

__global__ __launch_bounds__(256)
void k_rowinv_i(const int* __restrict__ A, int lda, int cols, int n,
                float* __restrict__ outp){
  int row = blockIdx.x*4 + (threadIdx.x >> 6);
  if (row >= n) return;
  int lane = threadIdx.x & 63;
  const int* Ar = A + (size_t)row*lda;
  float s = 0.0f;
  for (int c = lane; c < cols; c += 64) s += (float)Ar[c];
  #pragma unroll
  for (int o = 32; o; o >>= 1) s += __shfl_xor(s, o);
  if (lane == 0) outp[row] = 1.0f / fmaxf(s, 1.0f);
}
__global__ __launch_bounds__(256)
void k_rowinv_h(const unsigned short* __restrict__ A, int lda, int cols, int n,
                float* __restrict__ outp){
  int row = blockIdx.x*4 + (threadIdx.x >> 6);
  if (row >= n) return;
  int lane = threadIdx.x & 63;
  const unsigned short* Ar = A + (size_t)row*lda;
  float s = 0.0f;
  for (int c = lane; c < cols; c += 64) s += bf2f(Ar[c]);
  #pragma unroll
  for (int o = 32; o; o >>= 1) s += __shfl_xor(s, o);
  if (lane == 0) outp[row] = 1.0f / fmaxf(s, 1.0f);
}

// ---------------- dual transpose [n x 192] fp32 -> [192 x ldo] bf16 --------
struct TransJobs { const float* inA; unsigned short* outA; int nA; int ldoA; int rbA;
                   const float* inB; unsigned short* outB; int nB; int ldoB; };
__global__ __launch_bounds__(256)
void k_transpose2(TransJobs tj){
  const float* in; unsigned short* outp; int n, ldo, r0;
  int bx = blockIdx.x;
  if (bx < tj.rbA) { in = tj.inA; outp = tj.outA; n = tj.nA; ldo = tj.ldoA; r0 = bx*64; }
  else             { in = tj.inB; outp = tj.outB; n = tj.nB; ldo = tj.ldoB; r0 = (bx - tj.rbA)*64; }
  __shared__ float tile[64][65];
  int c0 = blockIdx.y*64;
  int t = threadIdx.x;
  int r = t >> 2, seg = t & 3;
  int grr = r0 + r;
  if (grr < n) {
    #pragma unroll
    for (int i = 0; i < 4; i++) {
      float4 v = *(const float4*)(in + (size_t)grr*HID + c0 + seg*16 + i*4);
      tile[r][seg*16+i*4+0] = v.x; tile[r][seg*16+i*4+1] = v.y;
      tile[r][seg*16+i*4+2] = v.z; tile[r][seg*16+i*4+3] = v.w;
    }
  } else {
    #pragma unroll
    for (int i = 0; i < 16; i++) tile[r][seg*16+i] = 0.0f;
  }
  __syncthreads();
  int w = t >> 6, lane = t & 63;
  if (r0 + lane < ldo) {
    #pragma unroll
    for (int j = 0; j < 16; j++) {
      int c = w*16 + j;
      outp[(size_t)(c0+c)*ldo + r0 + lane] = f2bf(tile[lane][c]);
    }
  }
}

// ---------------- batched CSR build (3 graphs) ----------------
struct CsrJob { const int* src; const int* dst; int E; int n;
                int* deg; int* rowptr; int* cursor; int* col; };
struct CsrJobs { CsrJob j[3]; };

__global__ __launch_bounds__(256) void k_hist3(CsrJobs jobs){
  CsrJob jb = jobs.j[blockIdx.y];
  int i = blockIdx.x*256 + threadIdx.x;
  if (i < jb.E) atomicAdd(&jb.deg[jb.dst[i]], 1);
}
__global__ __launch_bounds__(256) void k_scan3(CsrJobs jobs){
  CsrJob jb = jobs.j[blockIdx.x];
  __shared__ int part[256];
  __shared__ int pre[256];
  int t = threadIdx.x;
  int n = jb.n;
  int C = (n + 255) >> 8;
  int lo = t*C, hi = min(n, lo + C);
  int s = 0;
  for (int i = lo; i < hi; i++) s += jb.deg[i];
  part[t] = s;
  __syncthreads();
  if (t == 0) {
    int acc = 0;
    for (int i = 0; i < 256; i++) { pre[i] = acc; acc += part[i]; }
    jb.rowptr[n] = acc;
  }
  __syncthreads();
  int run = pre[t];
  for (int i = lo; i < hi; i++) {
    jb.rowptr[i] = run; jb.cursor[i] = run; run += jb.deg[i];
  }
}
__global__ __launch_bounds__(256) void k_fill3(CsrJobs jobs){
  CsrJob jb = jobs.j[blockIdx.y];
  int i = blockIdx.x*256 + threadIdx.x;
  if (i >= jb.E) return;
  int pos = atomicAdd(&jb.cursor[jb.dst[i]], 1);
  jb.col[pos] = jb.src[i];
}

// ---------------- MFMA bf16 GEMM (K=192, fp32 A/W): out = A·W^T + bias ----
#define LDA 200
__global__ __launch_bounds__(256)
void k_gemm(const float* __restrict__ A,
            const float* __restrict__ W, const float* __restrict__ bias,
            float* __restrict__ outp, int n)
{
  __shared__ __align__(16) unsigned short Asm[64*LDA];
  __shared__ __align__(16) unsigned short Wsm[64*LDA];
  int t = threadIdx.x;
  int row0 = blockIdx.x * 64;
  int col0 = blockIdx.y * 64;
  {
    int r = t >> 2, seg = t & 3;
    int gr = row0 + r;
    unsigned short* ad = Asm + r*LDA + seg*48;
    if (gr < n) {
      const float* Ar = A + (size_t)gr*HID + seg*48;
      #pragma unroll
      for (int i = 0; i < 12; i++) {
        float4 v = *reinterpret_cast<const float4*>(Ar + i*4);
        *reinterpret_cast<ushort4*>(ad + i*4) = f4bf(v);
      }
    } else {
      ushort4 z = make_ushort4(0,0,0,0);
      #pragma unroll
      for (int i = 0; i < 12; i++) *reinterpret_cast<ushort4*>(ad + i*4) = z;
    }
    const float* Wr = W + (size_t)(col0 + r)*HID + seg*48;
    unsigned short* wd = Wsm + r*LDA + seg*48;
    #pragma unroll
    for (int i = 0; i < 12; i++) {
      float4 v = *reinterpret_cast<const float4*>(Wr + i*4);
      *reinterpret_cast<ushort4*>(wd + i*4) = f4bf(v);
    }
  }
  __syncthreads();
  int w = t >> 6, lane = t & 63;
  int quad = lane >> 4, mr = lane & 15;
  float4v acc[4] = {};
  const unsigned short* Abase = Asm + (w*16 + mr)*LDA + quad*8;
  const unsigned short* Wbase = Wsm + mr*LDA + quad*8;
  #pragma unroll
  for (int k0 = 0; k0 < 6; k0++) {
    short8 a = *reinterpret_cast<const short8*>(Abase + k0*32);
    #pragma unroll
    for (int ct = 0; ct < 4; ct++) {
      short8 b = *reinterpret_cast<const short8*>(Wbase + ct*16*LDA + k0*32);
      acc[ct] = __builtin_amdgcn_mfma_f32_16x16x32_bf16(a, b, acc[ct], 0, 0, 0);
    }
  }
  #pragma unroll
  for (int ct = 0; ct < 4; ct++) {
    #pragma unroll
    for (int reg = 0; reg < 4; reg++) {
      int rr = row0 + w*16 + quad*4 + reg;
      if (rr < n) {
        int cc = col0 + ct*16 + mr;
        outp[(size_t)rr*HID + cc] = acc[ct][reg] + bias[cc];
      }
    }
  }
}

// ---------------- batched K=192 GEMM (6 jobs, bf16 out, flat grid) ---------
struct GemmJob { const float* A; const float* W; const float* bias;
                 unsigned short* out; int n; };
struct GemmJobs { GemmJob j[6]; int rb[7]; };
__global__ __launch_bounds__(256)
void k_gemm6(GemmJobs jobs)
{
  int bx = blockIdx.x;
  int z = 0;
  #pragma unroll
  for (int q = 1; q < 6; q++) if (bx >= jobs.rb[q]) z = q;
  GemmJob jb = jobs.j[z];
  int row0 = (bx - jobs.rb[z]) * 64;
  __shared__ __align__(16) unsigned short Asm[64*LDA];
  __shared__ __align__(16) unsigned short Wsm[64*LDA];
  int t = threadIdx.x;
  int col0 = blockIdx.y * 64;
  {
    int r = t >> 2, seg = t & 3;
    int gr = row0 + r;
    unsigned short* ad = Asm + r*LDA + seg*48;
    if (gr < jb.n) {
      const float* Ar = jb.A + (size_t)gr*HID + seg*48;
      #pragma unroll
      for (int i = 0; i < 12; i++) {
        float4 v = *reinterpret_cast<const float4*>(Ar + i*4);
        *reinterpret_cast<ushort4*>(ad + i*4) = f4bf(v);
      }
    } else {
      ushort4 zz = make_ushort4(0,0,0,0);
      #pragma unroll
      for (int i = 0; i < 12; i++) *reinterpret_cast<ushort4*>(ad + i*4) = zz;
    }
    const float* Wr = jb.W + (size_t)(col0 + r)*HID + seg*48;
    unsigned short* wd = Wsm + r*LDA + seg*48;
    #pragma unroll
    for (int i = 0; i < 12; i++) {
      float4 v = *reinterpret_cast<const float4*>(Wr + i*4);
      *reinterpret_cast<ushort4*>(wd + i*4) = f4bf(v);
    }
  }
  __syncthreads();
  int w = t >> 6, lane = t & 63;
  int quad = lane >> 4, mr = lane & 15;
  float4v acc[4] = {};
  const unsigned short* Abase = Asm + (w*16 + mr)*LDA + quad*8;
  const unsigned short* Wbase = Wsm + mr*LDA + quad*8;
  #pragma unroll
  for (int k0 = 0; k0 < 6; k0++) {
    short8 a = *reinterpret_cast<const short8*>(Abase + k0*32);
    #pragma unroll
    for (int ct = 0; ct < 4; ct++) {
      short8 b = *reinterpret_cast<const short8*>(Wbase + ct*16*LDA + k0*32);
      acc[ct] = __builtin_amdgcn_mfma_f32_16x16x32_bf16(a, b, acc[ct], 0, 0, 0);
    }
  }
  #pragma unroll
  for (int ct = 0; ct < 4; ct++) {
    #pragma unroll
    for (int reg = 0; reg < 4; reg++) {
      int rr = row0 + w*16 + quad*4 + reg;
      if (rr < jb.n) {
        int cc = col0 + ct*16 + mr;
        jb.out[(size_t)rr*HID + cc] = f2bf(acc[ct][reg] + jb.bias[cc]);
      }
    }
  }
}

// ---------------- batched K=192 GEMM (3 jobs, fp32 out) — pooling q/k/v ----
struct PoolJob { const float* A; const float* W; const float* bias;
                 float* out; int n; };
struct PoolJobs { PoolJob j[3]; int rb[4]; };
__global__ __launch_bounds__(256)
void k_gemm3(PoolJobs jobs)
{
  int bx = blockIdx.x;
  int z = 0;
  if (bx >= jobs.rb[1]) z = 1;
  if (bx >= jobs.rb[2]) z = 2;
  PoolJob jb = jobs.j[z];
  int row0 = (bx - jobs.rb[z]) * 64;
  __shared__ __align__(16) unsigned short Asm[64*LDA];
  __shared__ __align__(16) unsigned short Wsm[64*LDA];
  int t = threadIdx.x;
  int col0 = blockIdx.y * 64;
  {
    int r = t >> 2, seg = t & 3;
    int gr = row0 + r;
    unsigned short* ad = Asm + r*LDA + seg*48;
    if (gr < jb.n) {
      const float* Ar = jb.A + (size_t)gr*HID + seg*48;
      #pragma unroll
      for (int i = 0; i < 12; i++) {
        float4 v = *reinterpret_cast<const float4*>(Ar + i*4);
        *reinterpret_cast<ushort4*>(ad + i*4) = f4bf(v);
      }
    } else {
      ushort4 zz = make_ushort4(0,0,0,0);
      #pragma unroll
      for (int i = 0; i < 12; i++) *reinterpret_cast<ushort4*>(ad + i*4) = zz;
    }
    const float* Wr = jb.W + (size_t)(col0 + r)*HID + seg*48;
    unsigned short* wd = Wsm + r*LDA + seg*48;
    #pragma unroll
    for (int i = 0; i < 12; i++) {
      float4 v = *reinterpret_cast<const float4*>(Wr + i*4);
      *reinterpret_cast<ushort4*>(wd + i*4) = f4bf(v);
    }
  }
  __syncthreads();
  int w = t >> 6, lane = t & 63;
  int quad = lane >> 4, mr = lane & 15;
  float4v acc[4] = {};
  const unsigned short* Abase = Asm + (w*16 + mr)*LDA + quad*8;
  const unsigned short* Wbase = Wsm + mr*LDA + quad*8;
  #pragma unroll
  for (int k0 = 0; k0 < 6; k0++) {
    short8 a = *reinterpret_cast<const short8*>(Abase + k0*32);
    #pragma unroll
    for (int ct = 0; ct < 4; ct++) {
      short8 b = *reinterpret_cast<const short8*>(Wbase + ct*16*LDA + k0*32);
      acc[ct] = __builtin_amdgcn_mfma_f32_16x16x32_bf16(a, b, acc[ct], 0, 0, 0);
    }
  }
  #pragma unroll
  for (int ct = 0; ct < 4; ct++) {
    #pragma unroll
    for (int reg = 0; reg < 4; reg++) {
      int rr = row0 + w*16 + quad*4 + reg;
      if (rr < jb.n) {
        int cc = col0 + ct*16 + mr;
        jb.out[(size_t)rr*HID + cc] = acc[ct][reg] + jb.bias[cc];
      }
    }
  }
}

// ---------------- batched dual GEMM (2 jobs): out = A1·W1^T(rs) + A2·W2^T + b
struct G2Job { const float* A1; const float* rs1; const float* W1;
               const float* A2; const float* W2; const float* bias;
               float* out; int n; };
struct G2Jobs { G2Job j[2]; int rb[3]; };
__global__ __launch_bounds__(256)
void k_gemm2(G2Jobs jobs)
{
  int bx = blockIdx.x;
  int z = (bx >= jobs.rb[1]) ? 1 : 0;
  G2Job jb = jobs.j[z];
  int row0 = (bx - jobs.rb[z]) * 64;
  __shared__ __align__(16) unsigned short Asm[64*LDA];
  __shared__ __align__(16) unsigned short Wsm[64*LDA];
  int t = threadIdx.x;
  int col0 = blockIdx.y * 64;
  int r = t >> 2, seg = t & 3;
  int w = t >> 6, lane = t & 63;
  int quad = lane >> 4, mr = lane & 15;
  float4v acc[4] = {};
  for (int p = 0; p < 2; p++) {
    if (p) __syncthreads();
    const float* A = p ? jb.A2 : jb.A1;
    const float* W = p ? jb.W2 : jb.W1;
    {
      int gr = row0 + r;
      unsigned short* ad = Asm + r*LDA + seg*48;
      if (gr < jb.n) {
        float sc = (!p && jb.rs1) ? jb.rs1[gr] : 1.0f;
        const float* Ar = A + (size_t)gr*HID + seg*48;
        #pragma unroll
        for (int i = 0; i < 12; i++) {
          float4 v = *reinterpret_cast<const float4*>(Ar + i*4);
          v.x *= sc; v.y *= sc; v.z *= sc; v.w *= sc;
          *reinterpret_cast<ushort4*>(ad + i*4) = f4bf(v);
        }
      } else {
        ushort4 zz = make_ushort4(0,0,0,0);
        #pragma unroll
        for (int i = 0; i < 12; i++) *reinterpret_cast<ushort4*>(ad + i*4) = zz;
      }
      const float* Wr = W + (size_t)(col0 + r)*HID + seg*48;
      unsigned short* wd = Wsm + r*LDA + seg*48;
      #pragma unroll
      for (int i = 0; i < 12; i++) {
        float4 v = *reinterpret_cast<const float4*>(Wr + i*4);
        *reinterpret_cast<ushort4*>(wd + i*4) = f4bf(v);
      }
    }
    __syncthreads();
    const unsigned short* Abase = Asm + (w*16 + mr)*LDA + quad*8;
    const unsigned short* Wbase = Wsm + mr*LDA + quad*8;
    #pragma unroll
    for (int k0 = 0; k0 < 6; k0++) {
      short8 a = *reinterpret_cast<const short8*>(Abase + k0*32);
      #pragma unroll
      for (int ct = 0; ct < 4; ct++) {
        short8 b = *reinterpret_cast<const short8*>(Wbase + ct*16*LDA + k0*32);
        acc[ct] = __builtin_amdgcn_mfma_f32_16x16x32_bf16(a, b, acc[ct], 0, 0, 0);
      }
    }
  }
  #pragma unroll
  for (int ct = 0; ct < 4; ct++) {
    #pragma unroll
    for (int reg = 0; reg < 4; reg++) {
      int rr = row0 + w*16 + quad*4 + reg;
      if (rr < jb.n) {
        int cc = col0 + ct*16 + mr;
        jb.out[(size_t)rr*HID + cc] = acc[ct][reg] + jb.bias[cc];
      }
    }
  }
}

// ---------------- unified K-loop MFMA GEMM (17 jobs: s->g + split-K g->s) --
#define BKG 128
#define LDG 136
struct KJob { const unsigned short* A; int lda;
              const unsigned short* W; int ldw;
              float* out; int n; int kbeg; int kend; };
struct KJobs { KJob j[17]; int rb[18]; };
__global__ __launch_bounds__(256)
void k_gemm_k(KJobs jobs)
{
  int bx = blockIdx.x;
  int z = 0;
  for (int q = 1; q < 17; q++) if (bx >= jobs.rb[q]) z = q;
  KJob jb = jobs.j[z];
  int row0 = (bx - jobs.rb[z]) * 64;
  __shared__ __align__(16) unsigned short Asm[64*LDG];
  __shared__ __align__(16) unsigned short Wsm[64*LDG];
  int t = threadIdx.x;
  int col0 = blockIdx.y * 64;
  int r = t >> 2, seg = t & 3;
  int w = t >> 6, lane = t & 63;
  int quad = lane >> 4, mr = lane & 15;
  float4v acc[4] = {};
  for (int k0 = jb.kbeg; k0 < jb.kend; k0 += BKG) {
    {
      int gr = row0 + r;
      unsigned short* ad = Asm + r*LDG + seg*32;
      if (gr < jb.n) {
        const unsigned short* Ar = jb.A + (size_t)gr*jb.lda + k0 + seg*32;
        #pragma unroll
        for (int i = 0; i < 4; i++) *(uint4*)(ad + i*8) = *(const uint4*)(Ar + i*8);
      } else {
        uint4 zz = make_uint4(0,0,0,0);
        #pragma unroll
        for (int i = 0; i < 4; i++) *(uint4*)(ad + i*8) = zz;
      }
      const unsigned short* Wr = jb.W + (size_t)(col0 + r)*jb.ldw + k0 + seg*32;
      unsigned short* wd = Wsm + r*LDG + seg*32;
      #pragma unroll
      for (int i = 0; i < 4; i++) *(uint4*)(wd + i*8) = *(const uint4*)(Wr + i*8);
    }
    __syncthreads();
    const unsigned short* Abase = Asm + (w*16 + mr)*LDG + quad*8;
    const unsigned short* Wbase = Wsm + mr*LDG + quad*8;
    #pragma unroll
    for (int kk = 0; kk < 4; kk++) {
      short8 a = *(const short8*)(Abase + kk*32);
      #pragma unroll
      for (int ct = 0; ct < 4; ct++) {
        short8 b = *(const short8*)(Wbase + ct*16*LDG + kk*32);
        acc[ct] = __builtin_amdgcn_mfma_f32_16x16x32_bf16(a, b, acc[ct], 0, 0, 0);
      }
    }
    __syncthreads();
  }
  #pragma unroll
  for (int ct = 0; ct < 4; ct++) {
    #pragma unroll
    for (int reg = 0; reg < 4; reg++) {
      int rr = row0 + w*16 + quad*4 + reg;
      if (rr < jb.n) jb.out[(size_t)rr*HID + col0 + ct*16 + mr] = acc[ct][reg];
    }
  }
}

__global__ __launch_bounds__(256)
void k_reduce_sk(const float* __restrict__ part, float* __restrict__ outp, int n){
  int i = blockIdx.x*256 + threadIdx.x;
  if (i >= n*HID) return;
  float s = 0.0f;
  #pragma unroll
  for (int z = 0; z < SPLITK; z++) s += part[(size_t)z*n*HID + i];
  outp[i] = s;
}

// ---------------- batched GATv2: wave-per-dst, LDS-staged gl rows ----------
struct GatJob { const unsigned short* gl; const unsigned short* gr;
                const int* rowptr; const int* col;
                const float* att; const float* bias; float* out; int ndst; int accum; };
struct GatJobs { GatJob j[3]; int bo[4]; };

#define GLS_LD 200   // padded LDS row (ushort) for staged gl
__global__ __launch_bounds__(256)
void k_gat_all(GatJobs jobs)
{
  int bx = blockIdx.x;
  int jz = 0;
  if (bx >= jobs.bo[1]) jz = 1;
  if (bx >= jobs.bo[2]) jz = 2;
  GatJob jb = jobs.j[jz];
  int tid = threadIdx.x;
  int w = tid >> 6, lane = tid & 63;
  int dst = (bx - jobs.bo[jz])*4 + w;
  bool active = dst < jb.ndst;
  __shared__ float attS[HID];
  __shared__ float grS[4][HID];
  __shared__ __align__(16) unsigned short glS[4][16][GLS_LD];
  __shared__ float swS[4][4][16];
  __shared__ float fS[4][4];
  __shared__ float lS[4][4];
  if (tid < HID) attS[tid] = jb.att[tid];
  if (active) {
    const unsigned short* grr = jb.gr + (size_t)dst*HID;
    grS[w][lane]     = bf2f(grr[lane]);
    grS[w][lane+64]  = bf2f(grr[lane+64]);
    grS[w][lane+128] = bf2f(grr[lane+128]);
  }
  __syncthreads();   // attS visibility (all 256 threads reach this)
  if (!active) return;

  int h16 = lane >> 4, j16 = lane & 15;
  int start = jb.rowptr[dst], end = jb.rowptr[dst+1];
  float m = -1e30f, l = 0.0f;
  float acc0 = 0.f, acc1 = 0.f, acc2 = 0.f;
  int hd0 = lane/48, hd1 = (lane+64)/48, hd2 = (lane+128)/48;
  const float* attH = attS + h16*CDIM;
  const float* grH  = grS[w] + h16*CDIM;

  for (int c0 = start; c0 < end; c0 += 16) {
    int nc = min(16, end - c0);
    float sc = -1e30f;
    if (j16 < nc) {
      int s = jb.col[c0 + j16];
      const short8* glv = (const short8*)(jb.gl + (size_t)s*HID + h16*CDIM);
      unsigned short* ls = &glS[w][j16][h16*CDIM];
      float a = 0.0f;
      #pragma unroll
      for (int v8 = 0; v8 < 6; v8++) {
        short8 g8 = glv[v8];
        *(short8*)(ls + v8*8) = g8;     // stage row slice to LDS (wave-local)
        #pragma unroll
        for (int jj = 0; jj < 8; jj++) {
          float v = bf2f((unsigned short)g8[jj]) + grH[v8*8+jj];
          v = v > 0.0f ? v : 0.2f*v;
          a += v * attH[v8*8+jj];
        }
      }
      sc = a;
    }
    float cm = sc;
    cm = fmaxf(cm, __shfl_xor(cm, 1));
    cm = fmaxf(cm, __shfl_xor(cm, 2));
    cm = fmaxf(cm, __shfl_xor(cm, 4));
    cm = fmaxf(cm, __shfl_xor(cm, 8));
    float nm = fmaxf(m, cm);
    float f = __expf(m - nm);          // m=-1e30 -> 0
    l *= f;
    float e = (j16 < nc) ? __expf(sc - nm) : 0.0f;
    swS[w][h16][j16] = e;
    float cl = e;
    cl += __shfl_xor(cl, 1);
    cl += __shfl_xor(cl, 2);
    cl += __shfl_xor(cl, 4);
    cl += __shfl_xor(cl, 8);
    l += cl;
    m = nm;
    if (j16 == 0) fS[w][h16] = f;
    acc0 *= fS[w][hd0]; acc1 *= fS[w][hd1]; acc2 *= fS[w][hd2];
    for (int j = 0; j < nc; j++) {
      acc0 += swS[w][hd0][j] * bf2f(glS[w][j][lane]);
      acc1 += swS[w][hd1][j] * bf2f(glS[w][j][lane+64]);
      acc2 += swS[w][hd2][j] * bf2f(glS[w][j][lane+128]);
    }
  }
  if (j16 == 0) lS[w][h16] = l;
  float* od = jb.out + (size_t)dst*HID;
  float v0 = acc0 / (lS[w][hd0] + 1e-16f) + jb.bias[lane];
  float v1 = acc1 / (lS[w][hd1] + 1e-16f) + jb.bias[lane+64];
  float v2 = acc2 / (lS[w][hd2] + 1e-16f) + jb.bias[lane+128];
  if (jb.accum) { v0 += od[lane]; v1 += od[lane+64]; v2 += od[lane+128]; }
  od[lane] = v0; od[lane+64] = v1; od[lane+128] = v2;
}

// ---------------- batched residual + LayerNorm (3 node types) -------------
__global__ __launch_bounds__(64)
void k_ln3(float* __restrict__ xs, const float* __restrict__ osb,
           float* __restrict__ xg, const float* __restrict__ og,
           float* __restrict__ xp, const float* __restrict__ opb,
           const float* __restrict__ op2,
           const float* __restrict__ LNg, const float* __restrict__ LNb, int l)
{
  int r = blockIdx.x;
  float* x; const float* d1; const float* d2 = nullptr; int typ;
  if (r < N_S)            { x = xs + (size_t)r*HID; d1 = osb + (size_t)r*HID; typ = 0; }
  else if (r < N_S + N_G) { int rr = r - N_S; x = xg + (size_t)rr*HID; d1 = og + (size_t)rr*HID; typ = 1; }
  else                    { int rr = r - N_S - N_G; x = xp + (size_t)rr*HID; d1 = opb + (size_t)rr*HID;
                            d2 = op2 + (size_t)rr*HID; typ = 2; }
  const float* g = LNg + (l*3 + typ)*HID;
  const float* b = LNb + (l*3 + typ)*HID;
  int lane = threadIdx.x;
  float v[3]; float sum = 0.0f;
  #pragma unroll
  for (int j=0;j<3;j++){
    int d = j*64 + lane;
    float t = x[d] + d1[d];
    if (d2) t += d2[d];
    v[j] = t; sum += t;
  }
  #pragma unroll
  for (int o=32;o;o>>=1) sum += __shfl_xor(sum, o);
  float mu = sum * (1.0f/HID);
  float var = 0.0f;
  #pragma unroll
  for (int j=0;j<3;j++){ float dd = v[j]-mu; var += dd*dd; }
  #pragma unroll
  for (int o=32;o;o>>=1) var += __shfl_xor(var, o);
  var *= (1.0f/HID);
  float inv = rsqrtf(var + 1e-5f);
  #pragma unroll
  for (int j=0;j<3;j++){
    int d = j*64 + lane;
    x[d] = (v[j]-mu)*inv*g[d] + b[d];
  }
}

// ---------------- pooling attention: one block per (q,h) ----------------
__global__ __launch_bounds__(256)
void k_pool_attn(const float* __restrict__ qb, const float* __restrict__ kb,
                 const float* __restrict__ vb, float* __restrict__ ob)
{
  int h = blockIdx.x & 3;
  int q = blockIdx.x >> 2;
  __shared__ float prob[N_S];
  __shared__ float red[256];
  int t = threadIdx.x;
  const float* qrow = qb + (size_t)q*HID + h*CDIM;
  const float scale = 0.14433756729740643f;
  for (int n = t; n < N_S; n += 256) {
    const float* krow = kb + (size_t)n*HID + h*CDIM;
    float s = 0.0f;
    #pragma unroll 8
    for (int c=0;c<CDIM;c++) s += qrow[c]*krow[c];
    prob[n] = s * scale;
  }
  __syncthreads();
  float m = -1e30f;
  for (int n=t;n<N_S;n+=256) m = fmaxf(m, prob[n]);
  red[t] = m; __syncthreads();
  for (int s2=128;s2;s2>>=1){ if (t<s2) red[t]=fmaxf(red[t],red[t+s2]); __syncthreads(); }
  m = red[0]; __syncthreads();
  float sum = 0.0f;
  for (int n=t;n<N_S;n+=256){ float e=__expf(prob[n]-m); prob[n]=e; sum+=e; }
  red[t] = sum; __syncthreads();
  for (int s2=128;s2;s2>>=1){ if (t<s2) red[t]+=red[t+s2]; __syncthreads(); }
  float inv = 1.0f/red[0];
  __syncthreads();
  if (t < CDIM) {
    float acc = 0.0f;
    for (int n=0;n<N_S;n++) acc += prob[n]*vb[(size_t)n*HID + h*CDIM + t];
    ob[(size_t)q*HID + h*CDIM + t] = acc * inv;
  }
}

// ---------------- tail ----------------
__global__ __launch_bounds__(192)
void k_tail(const float* __restrict__ ob2,
            const float* ffw1, const float* ffb1,
            const float* ffw2, const float* ffb2,
            const float* lng, const float* lnb,
            const float* pw, const float* pb,
            void* __restrict__ outp, const int* __restrict__ flag)
{
  __shared__ float pooled[HID];
  __shared__ float hh[HID];
  __shared__ float stats[2];
  int t = threadIdx.x;
  float a = 0.0f;
  for (int q=0;q<NQd;q++) a += ob2[q*HID + t];
  pooled[t] = a * (1.0f/NQd);
  __syncthreads();
  float s1 = ffb1[t];
  for (int k=0;k<HID;k++) s1 += pooled[k]*ffw1[t*HID+k];
  hh[t] = fmaxf(s1, 0.0f);
  __syncthreads();
  float s2 = ffb2[t];
  for (int k=0;k<HID;k++) s2 += hh[k]*ffw2[t*HID+k];
  __syncthreads();
  hh[t] = s2;
  __syncthreads();
  if (t == 0) {
    float mu=0.0f; for (int k=0;k<HID;k++) mu += hh[k];
    mu *= (1.0f/HID);
    float v=0.0f; for (int k=0;k<HID;k++){ float d=hh[k]-mu; v+=d*d; }
    v *= (1.0f/HID);
    stats[0]=mu; stats[1]=rsqrtf(v + 1e-5f);
  }
  __syncthreads();
  pooled[t] = (hh[t]-stats[0])*stats[1]*lng[t] + lnb[t];
  __syncthreads();
  if (t < OUTD) {
    float acc = pb[t];
    for (int k=0;k<HID;k++) acc += pooled[k]*pw[t*HID+k];
    if (flag[0]) ((float*)outp)[t] = acc;
    else         ((unsigned short*)outp)[t] = f2bf(acc);
  }
}

// =====================================================================
extern "C" void kernel_launch(void* const* d_in, const int* in_sizes, int n_in,
                              void* d_out, int out_size, void* d_ws, size_t ws_size,
                              hipStream_t stream)
{
  const int* sg_src = (const int*)d_in[3];
  const int* sg_dst = (const int*)d_in[4];
  const int* gp_src = (const int*)d_in[5];
  const int* gp_dst = (const int*)d_in[6];
  const int* pp_src = (const int*)d_in[7];
  const int* pp_dst = (const int*)d_in[8];

  float* base = (float*)d_ws;
  size_t off = 0;
  auto alloc = [&](size_t nf){ nf = (nf + 3) & ~(size_t)3; float* p = base + off; off += nf; return p; };
  int*   flag = (int*)alloc(4);
  float* xs   = alloc((size_t)N_S*HID);
  float* xg   = alloc((size_t)N_G*HID);
  float* xp   = alloc((size_t)N_P*HID);
  float* qin  = alloc((size_t)NQd*HID);
  float* Wsl  = alloc(2*2*HID*HID); float* bsl = alloc(2*2*HID); float* Wsr = alloc(2*2*HID*HID);
  float* Wgl  = alloc(2*3*HID*HID); float* bgl = alloc(2*3*HID);
  float* Wgr  = alloc(2*3*HID*HID); float* bgr = alloc(2*3*HID);
  float* Agat = alloc(2*3*HEADS*CDIM); float* Bgat = alloc(2*3*HID);
  float* LNg  = alloc(2*3*HID); float* LNb = alloc(2*3*HID);
  float* Pinw = alloc(3*HID*HID); float* Pinb = alloc(3*HID);
  float* Poutw= alloc(HID*HID);   float* Poutb= alloc(HID);
  float* Fw1  = alloc(HID*HID);   float* Fb1  = alloc(HID);
  float* Fw2  = alloc(HID*HID);   float* Fb2  = alloc(HID);
  float* PLg  = alloc(HID);       float* PLb  = alloc(HID);
  float* Pw   = alloc(OUTD*HID);  float* Pb   = alloc(OUTD);
  // runtime buffers
  float* agg  = alloc((size_t)N_G*HID);
  float* aggS = alloc((size_t)N_S*HID);
  float* og   = alloc((size_t)N_G*HID);
  float* osb  = alloc((size_t)N_S*HID);
  float* opb  = alloc((size_t)N_P*HID);
  float* op2  = alloc((size_t)N_P*HID);
  // bf16 GAT node transforms
  unsigned short* glGb  = (unsigned short*)alloc((size_t)N_G*HID/2);
  unsigned short* grGb  = (unsigned short*)alloc((size_t)N_G*HID/2);
  unsigned short* grP0b = (unsigned short*)alloc((size_t)N_P*HID/2);
  unsigned short* glP1b = (unsigned short*)alloc((size_t)N_P*HID/2);
  unsigned short* glP2b = (unsigned short*)alloc((size_t)N_P*HID/2);
  unsigned short* grP2b = (unsigned short*)alloc((size_t)N_P*HID/2);
  float* qbuf = alloc((size_t)NQd*HID);
  float* kbuf = alloc((size_t)N_S*HID);
  float* vbuf = alloc((size_t)N_S*HID);
  float* obuf = alloc((size_t)NQd*HID);
  float* ob2  = alloc((size_t)NQd*HID);
  // dense SAGE matrices
  int*            CntGi = (int*)alloc((size_t)N_G*N_S);
  unsigned short* CntGb = (unsigned short*)alloc((size_t)N_G*N_S/2);
  unsigned short* CntSb = (unsigned short*)alloc((size_t)N_S*LDK/2);
  unsigned short* xsTb  = (unsigned short*)alloc((size_t)HID*N_S/2);
  unsigned short* xgTb  = (unsigned short*)alloc((size_t)HID*LDK/2);
  float* part = alloc((size_t)SPLITK*N_S*HID);
  float* invdegG = alloc(N_G);
  float* invdegS = alloc(N_S);
  // CSR storage (GAT graphs)
  int* degAll = (int*)alloc(2*N_P + N_G + 4);
  int* curAll = (int*)alloc(2*N_P + N_G + 4);
  int* rp_gp_p = (int*)alloc(N_P+2);  int* col_gp_p = (int*)alloc(NE_GP);
  int* rp_gp_g = (int*)alloc(N_G+2);  int* col_gp_g = (int*)alloc(NE_GP);
  int* rp_pp_p = (int*)alloc(N_P+2);  int* col_pp_p = (int*)alloc(NE_PP);
  (void)ws_size; (void)in_sizes; (void)n_in; (void)out_size;

  k_detect<<<1,256,0,stream>>>((const unsigned int*)d_in[0], flag);

  // ---- batched input conversion ----
  {
    LoadTable tab;
    int k = 0;
    auto add = [&](int i, float* dst, int n){ tab.d[k].src = d_in[i]; tab.d[k].dst = dst; tab.d[k].n = n; k++; };
    add(0,  xs,  N_S*HID);  add(1,  xg,  N_G*HID);  add(2,  xp,  N_P*HID);
    add(9,  Wsl, 2*2*HID*HID); add(10, bsl, 2*2*HID); add(11, Wsr, 2*2*HID*HID);
    add(12, Wgl, 2*3*HID*HID); add(13, bgl, 2*3*HID);
    add(14, Wgr, 2*3*HID*HID); add(15, bgr, 2*3*HID);
    add(16, Agat, 2*3*HEADS*CDIM); add(17, Bgat, 2*3*HID);
    add(18, LNg, 2*3*HID); add(19, LNb, 2*3*HID);
    add(20, qin, NQd*HID);
    add(21, Pinw, 3*HID*HID); add(22, Pinb, 3*HID);
    add(23, Poutw, HID*HID);  add(24, Poutb, HID);
    add(25, Fw1, HID*HID); add(26, Fb1, HID);
    add(27, Fw2, HID*HID); add(28, Fb2, HID);
    add(29, PLg, HID); add(30, PLb, HID);
    add(31, Pw, OUTD*HID); add(32, Pb, OUTD);
    k_load_all<<<dim3(LOADBX, NLOAD),256,0,stream>>>(tab, flag);
  }

  // ---- dense SAGE counts ----
  hipMemsetAsync(CntGi, 0, (size_t)N_G*N_S*4, stream);
  hipMemsetAsync(degAll, 0, (size_t)(2*N_P + N_G)*4, stream);
  k_cntbuild<<<(NE_SG+255)/256,256,0,stream>>>(sg_src, sg_dst, CntGi, NE_SG);
  k_cvtT<<<dim3(LDK/64, N_S/64),256,0,stream>>>(CntGi, CntGb, CntSb);
  k_rowinv_i<<<(N_G+3)/4,256,0,stream>>>(CntGi, N_S, N_S, N_G, invdegG);
  k_rowinv_h<<<(N_S+3)/4,256,0,stream>>>(CntSb, LDK, LDK, N_S, invdegS);

  // ---- batched CSR build for the 3 GAT graphs ----
  {
    CsrJobs jobs;
    jobs.j[0] = { gp_src, gp_dst, NE_GP, N_P, degAll,           rp_gp_p, curAll,           col_gp_p };
    jobs.j[1] = { gp_dst, gp_src, NE_GP, N_G, degAll+N_P,       rp_gp_g, curAll+N_P,       col_gp_g };
    jobs.j[2] = { pp_src, pp_dst, NE_PP, N_P, degAll+N_P+N_G,   rp_pp_p, curAll+N_P+N_G,   col_pp_p };
    k_hist3<<<dim3((NE_GP+255)/256, 3),256,0,stream>>>(jobs);
    k_scan3<<<3,256,0,stream>>>(jobs);
    k_fill3<<<dim3((NE_GP+255)/256, 3),256,0,stream>>>(jobs);
  }

  const int RB_G = (N_G+63)/64, RB_P = (N_P+63)/64;       // 181, 32
  const int GB_P = (N_P+3)/4,  GB_G = (N_G+3)/4;          // 500, 2890

  for (int l=0; l<2; l++) {
    // both feature transposes in one dispatch
    {
      TransJobs tj;
      tj.inA = xs; tj.outA = xsTb; tj.nA = N_S; tj.ldoA = N_S; tj.rbA = 8;
      tj.inB = xg; tj.outB = xgTb; tj.nB = N_G; tj.ldoB = LDK;
      k_transpose2<<<dim3(8 + LDK/64, 3),256,0,stream>>>(tj);
    }
    // SAGE aggregations: s->g (K=512) + split-K g->s, one dispatch
    {
      KJobs kj;
      kj.j[0] = { CntGb, N_S, xsTb, N_S, agg, N_G, 0, N_S };
      kj.rb[0] = 0; kj.rb[1] = RB_G;
      for (int z = 0; z < SPLITK; z++) {
        kj.j[1+z] = { CntSb, LDK, xgTb, LDK, part + (size_t)z*N_S*HID, N_S,
                      z*CHUNKK, (z+1)*CHUNKK };
        kj.rb[2+z] = kj.rb[1+z] + 8;
      }
      k_gemm_k<<<dim3(kj.rb[17],3),256,0,stream>>>(kj);
    }
    k_reduce_sk<<<(N_S*HID+255)/256,256,0,stream>>>(part, aggS, N_S);
    // both SAGE weight GEMMs (og, osb) in one dispatch
    {
      G2Jobs g2;
      g2.j[0] = { agg,  invdegG, Wsl + (size_t)(l*2+0)*HID*HID,
                  xg, Wsr + (size_t)(l*2+0)*HID*HID, bsl + (l*2+0)*HID, og,  N_G };
      g2.j[1] = { aggS, invdegS, Wsl + (size_t)(l*2+1)*HID*HID,
                  xs, Wsr + (size_t)(l*2+1)*HID*HID, bsl + (l*2+1)*HID, osb, N_S };
      g2.rb[0] = 0; g2.rb[1] = RB_G; g2.rb[2] = RB_G + (N_S+63)/64;
      k_gemm2<<<dim3(g2.rb[2],3),256,0,stream>>>(g2);
    }
    // GAT: 6 node transforms in one flat dispatch (bf16 outputs)
    {
      GemmJobs gj;
      int w0 = l*3+0, w1 = l*3+1, w2 = l*3+2;
      gj.j[0] = { xg, Wgl + (size_t)w0*HID*HID, bgl + w0*HID, glGb,  N_G };
      gj.j[1] = { xp, Wgr + (size_t)w0*HID*HID, bgr + w0*HID, grP0b, N_P };
      gj.j[2] = { xp, Wgl + (size_t)w1*HID*HID, bgl + w1*HID, glP1b, N_P };
      gj.j[3] = { xg, Wgr + (size_t)w1*HID*HID, bgr + w1*HID, grGb,  N_G };
      gj.j[4] = { xp, Wgl + (size_t)w2*HID*HID, bgl + w2*HID, glP2b, N_P };
      gj.j[5] = { xp, Wgr + (size_t)w2*HID*HID, bgr + w2*HID, grP2b, N_P };
      int nrb[6] = { RB_G, RB_P, RB_P, RB_G, RB_P, RB_P };
      gj.rb[0] = 0;
      for (int q = 0; q < 6; q++) gj.rb[q+1] = gj.rb[q] + nrb[q];
      k_gemm6<<<dim3(gj.rb[6],3),256,0,stream>>>(gj);
    }
    // GAT: 3 edge passes in one flat dispatch (wave-per-destination)
    {
      GatJobs gt;
      int w0 = l*3+0, w1 = l*3+1, w2 = l*3+2;
      gt.j[0] = { glGb,  grP0b, rp_gp_p, col_gp_p, Agat + (size_t)w0*HID, Bgat + (size_t)w0*HID, opb, N_P, 0 };
      gt.j[1] = { glP1b, grGb,  rp_gp_g, col_gp_g, Agat + (size_t)w1*HID, Bgat + (size_t)w1*HID, og,  N_G, 1 };
      gt.j[2] = { glP2b, grP2b, rp_pp_p, col_pp_p, Agat + (size_t)w2*HID, Bgat + (size_t)w2*HID, op2, N_P, 0 };
      gt.bo[0] = 0; gt.bo[1] = GB_P; gt.bo[2] = GB_P + GB_G; gt.bo[3] = GB_P + GB_G + GB_P;
      k_gat_all<<<dim3(gt.bo[3]),256,0,stream>>>(gt);
    }
    // residual + LN, all node types in one dispatch
    k_ln3<<<N_S+N_G+N_P,64,0,stream>>>(xs, osb, xg, og, xp, opb, op2, LNg, LNb, l);
  }

  // ---- pooling: q/k/v in one dispatch ----
  {
    PoolJobs pj;
    pj.j[0] = { qin, Pinw,                     Pinb,         qbuf, NQd };
    pj.j[1] = { xs,  Pinw + (size_t)HID*HID,   Pinb + HID,   kbuf, N_S };
    pj.j[2] = { xs,  Pinw + (size_t)2*HID*HID, Pinb + 2*HID, vbuf, N_S };
    pj.rb[0] = 0; pj.rb[1] = 1; pj.rb[2] = 1 + (N_S+63)/64; pj.rb[3] = pj.rb[2] + (N_S+63)/64;
    k_gemm3<<<dim3(pj.rb[3],3),256,0,stream>>>(pj);
  }
  k_pool_attn<<<NQd*HEADS,256,0,stream>>>(qbuf, kbuf, vbuf, obuf);
  k_gemm<<<dim3(1,3),256,0,stream>>>(obuf, Poutw, Poutb, ob2, NQd);
  k_tail<<<1,HID,0,stream>>>(ob2, Fw1, Fb1, Fw2, Fb2, PLg, PLb, Pw, Pb, d_out, flag);
}

// Round 14
// 638.275 us; speedup vs baseline: 1.2155x; 1.0784x over previous
//
#include <hip/hip_runtime.h>

#define N_S 512
#define N_G 11560
#define N_P 2000
#define NE_SG 1000000
#define NE_GP 200000
#define NE_PP 50000
#define HID 192
#define HEADS 4
#define CDIM 48
#define NQd 20
#define OUTD 128
#define LDK 12288
#define SPLITK 16
#define CHUNKK 768

typedef __attribute__((ext_vector_type(8))) short short8;
typedef __attribute__((ext_vector_type(4))) float float4v;

__device__ __forceinline__ float bf2f(unsigned short u){
  union { unsigned int i; float f; } x; x.i = ((unsigned int)u) << 16; return x.f;
}
__device__ __forceinline__ unsigned short f2bf(float f){
  union { float f; unsigned int i; } u; u.f = f;
  unsigned int r = u.i + 0x7FFFu + ((u.i >> 16) & 1u);
  return (unsigned short)(r >> 16);
}
__device__ __forceinline__ ushort4 f4bf(float4 v){
  return make_ushort4(f2bf(v.x), f2bf(v.y), f2bf(v.z), f2bf(v.w));
}

// ---------------- dtype detection (flag=1 fp32, flag=0 bf16) ----------------
__global__ __launch_bounds__(256) void k_detect(const unsigned int* __restrict__ raw,
                                                int* __restrict__ flag){
  __shared__ int cnt;
  if (threadIdx.x == 0) cnt = 0;
  __syncthreads();
  int c = 0;
  for (int i = threadIdx.x; i < 2048; i += 256) {
    float f = __uint_as_float(raw[i]);
    float a = fabsf(f);
    if (f == f && a > 1e-4f && a < 1000.0f) c++;
  }
  atomicAdd(&cnt, c);
  __syncthreads();
  if (threadIdx.x == 0) flag[0] = (cnt >= 1024) ? 1 : 0;
}

// ---------------- batched input load (27 tensors, grid-stride) ----------
#define NLOAD 27
#define LOADBX 2048
struct LoadDesc { const void* src; float* dst; int n; };
struct LoadTable { LoadDesc d[NLOAD]; };
__global__ __launch_bounds__(256)
void k_load_all(LoadTable tab, const int* __restrict__ flag){
  LoadDesc de = tab.d[blockIdx.y];
  int fp32 = flag[0];
  for (int i = blockIdx.x*256 + threadIdx.x; i < de.n; i += LOADBX*256) {
    if (fp32) de.dst[i] = ((const float*)de.src)[i];
    else      de.dst[i] = bf2f(((const unsigned short*)de.src)[i]);
  }
}

// ---------------- dense count matrix (CntG only; CntS derived) -------------
__global__ __launch_bounds__(256)
void k_cntbuild(const int* __restrict__ src, const int* __restrict__ dst,
                int* __restrict__ cg, int E){
  int i = blockIdx.x*256 + threadIdx.x;
  if (i >= E) return;
  atomicAdd(&cg[(size_t)dst[i]*N_S + src[i]], 1);
}

// convert CntG(int)->bf16 and write transposed bf16 CntS [512 x LDK] (zero-pad)
__global__ __launch_bounds__(256)
void k_cvtT(const int* __restrict__ cg, unsigned short* __restrict__ bfA,
            unsigned short* __restrict__ bfB){
  __shared__ unsigned short tile[64][68];
  int g0 = blockIdx.x*64, s0 = blockIdx.y*64;
  int t = threadIdx.x; int r = t>>2, seg = t&3;
  int g = g0 + r;
  if (g < N_G) {
    const int* row = cg + (size_t)g*N_S + s0 + seg*16;
    unsigned short* arow = bfA + (size_t)g*N_S + s0 + seg*16;
    #pragma unroll
    for (int i=0;i<16;i++){
      unsigned short v = f2bf((float)row[i]);
      tile[r][seg*16+i] = v;
      arow[i] = v;
    }
  } else {
    #pragma unroll
    for (int i=0;i<16;i++) tile[r][seg*16+i] = 0;
  }
  __syncthreads();
  int s = s0 + r;
  unsigned short* brow = bfB + (size_t)s*LDK + g0 + seg*16;
  #pragma unroll
  for (int i=0;i<16;i++) brow[i] = tile[seg*16+i][r];
}

__global__ __launch_bounds__(256)
void k_rowinv_i(const int* __restrict__ A, int lda, int cols, int n,
                float* __restrict__ outp){
  int row = blockIdx.x*4 + (threadIdx.x >> 6);
  if (row >= n) return;
  int lane = threadIdx.x & 63;
  const int* Ar = A + (size_t)row*lda;
  float s = 0.0f;
  for (int c = lane; c < cols; c += 64) s += (float)Ar[c];
  #pragma unroll
  for (int o = 32; o; o >>= 1) s += __shfl_xor(s, o);
  if (lane == 0) outp[row] = 1.0f / fmaxf(s, 1.0f);
}
// block-per-row vectorized bf16 row-sum (cols multiple of 2048)
__global__ __launch_bounds__(256)
void k_rowinv_h(const unsigned short* __restrict__ A, int lda, int cols, int n,
                float* __restrict__ outp){
  int row = blockIdx.x;
  if (row >= n) return;
  int t = threadIdx.x;
  const short8* Av = (const short8*)(A + (size_t)row*lda);
  float s = 0.0f;
  for (int i = t; i < cols/8; i += 256) {
    short8 v = Av[i];
    #pragma unroll
    for (int j = 0; j < 8; j++) s += bf2f((unsigned short)v[j]);
  }
  #pragma unroll
  for (int o = 32; o; o >>= 1) s += __shfl_xor(s, o);
  __shared__ float red[4];
  int w = t >> 6, lane = t & 63;
  if (lane == 0) red[w] = s;
  __syncthreads();
  if (t == 0) {
    float tot = red[0] + red[1] + red[2] + red[3];
    outp[row] = 1.0f / fmaxf(tot, 1.0f);
  }
}

// ---------------- dual transpose [n x 192] fp32 -> [192 x ldo] bf16 --------
struct TransJobs { const float* inA; unsigned short* outA; int nA; int ldoA; int rbA;
                   const float* inB; unsigned short* outB; int nB; int ldoB; };
__global__ __launch_bounds__(256)
void k_transpose2(TransJobs tj){
  const float* in; unsigned short* outp; int n, ldo, r0;
  int bx = blockIdx.x;
  if (bx < tj.rbA) { in = tj.inA; outp = tj.outA; n = tj.nA; ldo = tj.ldoA; r0 = bx*64; }
  else             { in = tj.inB; outp = tj.outB; n = tj.nB; ldo = tj.ldoB; r0 = (bx - tj.rbA)*64; }
  __shared__ float tile[64][65];
  int c0 = blockIdx.y*64;
  int t = threadIdx.x;
  int r = t >> 2, seg = t & 3;
  int grr = r0 + r;
  if (grr < n) {
    #pragma unroll
    for (int i = 0; i < 4; i++) {
      float4 v = *(const float4*)(in + (size_t)grr*HID + c0 + seg*16 + i*4);
      tile[r][seg*16+i*4+0] = v.x; tile[r][seg*16+i*4+1] = v.y;
      tile[r][seg*16+i*4+2] = v.z; tile[r][seg*16+i*4+3] = v.w;
    }
  } else {
    #pragma unroll
    for (int i = 0; i < 16; i++) tile[r][seg*16+i] = 0.0f;
  }
  __syncthreads();
  int w = t >> 6, lane = t & 63;
  if (r0 + lane < ldo) {
    #pragma unroll
    for (int j = 0; j < 16; j++) {
      int c = w*16 + j;
      outp[(size_t)(c0+c)*ldo + r0 + lane] = f2bf(tile[lane][c]);
    }
  }
}

// ---------------- batched CSR build (3 graphs) ----------------
struct CsrJob { const int* src; const int* dst; int E; int n;
                int* deg; int* rowptr; int* cursor; int* col; };
struct CsrJobs { CsrJob j[3]; };

__global__ __launch_bounds__(256) void k_hist3(CsrJobs jobs){
  CsrJob jb = jobs.j[blockIdx.y];
  int i = blockIdx.x*256 + threadIdx.x;
  if (i < jb.E) atomicAdd(&jb.deg[jb.dst[i]], 1);
}
__global__ __launch_bounds__(256) void k_scan3(CsrJobs jobs){
  CsrJob jb = jobs.j[blockIdx.x];
  __shared__ int part[256];
  __shared__ int pre[256];
  int t = threadIdx.x;
  int n = jb.n;
  int C = (n + 255) >> 8;
  int lo = t*C, hi = min(n, lo + C);
  int s = 0;
  for (int i = lo; i < hi; i++) s += jb.deg[i];
  part[t] = s;
  __syncthreads();
  if (t == 0) {
    int acc = 0;
    for (int i = 0; i < 256; i++) { pre[i] = acc; acc += part[i]; }
    jb.rowptr[n] = acc;
  }
  __syncthreads();
  int run = pre[t];
  for (int i = lo; i < hi; i++) {
    jb.rowptr[i] = run; jb.cursor[i] = run; run += jb.deg[i];
  }
}
__global__ __launch_bounds__(256) void k_fill3(CsrJobs jobs){
  CsrJob jb = jobs.j[blockIdx.y];
  int i = blockIdx.x*256 + threadIdx.x;
  if (i >= jb.E) return;
  int pos = atomicAdd(&jb.cursor[jb.dst[i]], 1);
  jb.col[pos] = jb.src[i];
}

// ---------------- MFMA bf16 GEMM (K=192, fp32 A/W): out = A·W^T + bias ----
#define LDA 200
__global__ __launch_bounds__(256)
void k_gemm(const float* __restrict__ A,
            const float* __restrict__ W, const float* __restrict__ bias,
            float* __restrict__ outp, int n)
{
  __shared__ __align__(16) unsigned short Asm[64*LDA];
  __shared__ __align__(16) unsigned short Wsm[64*LDA];
  int t = threadIdx.x;
  int row0 = blockIdx.x * 64;
  int col0 = blockIdx.y * 64;
  {
    int r = t >> 2, seg = t & 3;
    int gr = row0 + r;
    unsigned short* ad = Asm + r*LDA + seg*48;
    if (gr < n) {
      const float* Ar = A + (size_t)gr*HID + seg*48;
      #pragma unroll
      for (int i = 0; i < 12; i++) {
        float4 v = *reinterpret_cast<const float4*>(Ar + i*4);
        *reinterpret_cast<ushort4*>(ad + i*4) = f4bf(v);
      }
    } else {
      ushort4 z = make_ushort4(0,0,0,0);
      #pragma unroll
      for (int i = 0; i < 12; i++) *reinterpret_cast<ushort4*>(ad + i*4) = z;
    }
    const float* Wr = W + (size_t)(col0 + r)*HID + seg*48;
    unsigned short* wd = Wsm + r*LDA + seg*48;
    #pragma unroll
    for (int i = 0; i < 12; i++) {
      float4 v = *reinterpret_cast<const float4*>(Wr + i*4);
      *reinterpret_cast<ushort4*>(wd + i*4) = f4bf(v);
    }
  }
  __syncthreads();
  int w = t >> 6, lane = t & 63;
  int quad = lane >> 4, mr = lane & 15;
  float4v acc[4] = {};
  const unsigned short* Abase = Asm + (w*16 + mr)*LDA + quad*8;
  const unsigned short* Wbase = Wsm + mr*LDA + quad*8;
  #pragma unroll
  for (int k0 = 0; k0 < 6; k0++) {
    short8 a = *reinterpret_cast<const short8*>(Abase + k0*32);
    #pragma unroll
    for (int ct = 0; ct < 4; ct++) {
      short8 b = *reinterpret_cast<const short8*>(Wbase + ct*16*LDA + k0*32);
      acc[ct] = __builtin_amdgcn_mfma_f32_16x16x32_bf16(a, b, acc[ct], 0, 0, 0);
    }
  }
  #pragma unroll
  for (int ct = 0; ct < 4; ct++) {
    #pragma unroll
    for (int reg = 0; reg < 4; reg++) {
      int rr = row0 + w*16 + quad*4 + reg;
      if (rr < n) {
        int cc = col0 + ct*16 + mr;
        outp[(size_t)rr*HID + cc] = acc[ct][reg] + bias[cc];
      }
    }
  }
}

// ---------------- batched K=192 GEMM (6 jobs, bf16 out, flat grid) ---------
struct GemmJob { const float* A; const float* W; const float* bias;
                 unsigned short* out; int n; };
struct GemmJobs { GemmJob j[6]; int rb[7]; };
__global__ __launch_bounds__(256)
void k_gemm6(GemmJobs jobs)
{
  int bx = blockIdx.x;
  int z = 0;
  #pragma unroll
  for (int q = 1; q < 6; q++) if (bx >= jobs.rb[q]) z = q;
  GemmJob jb = jobs.j[z];
  int row0 = (bx - jobs.rb[z]) * 64;
  __shared__ __align__(16) unsigned short Asm[64*LDA];
  __shared__ __align__(16) unsigned short Wsm[64*LDA];
  int t = threadIdx.x;
  int col0 = blockIdx.y * 64;
  {
    int r = t >> 2, seg = t & 3;
    int gr = row0 + r;
    unsigned short* ad = Asm + r*LDA + seg*48;
    if (gr < jb.n) {
      const float* Ar = jb.A + (size_t)gr*HID + seg*48;
      #pragma unroll
      for (int i = 0; i < 12; i++) {
        float4 v = *reinterpret_cast<const float4*>(Ar + i*4);
        *reinterpret_cast<ushort4*>(ad + i*4) = f4bf(v);
      }
    } else {
      ushort4 zz = make_ushort4(0,0,0,0);
      #pragma unroll
      for (int i = 0; i < 12; i++) *reinterpret_cast<ushort4*>(ad + i*4) = zz;
    }
    const float* Wr = jb.W + (size_t)(col0 + r)*HID + seg*48;
    unsigned short* wd = Wsm + r*LDA + seg*48;
    #pragma unroll
    for (int i = 0; i < 12; i++) {
      float4 v = *reinterpret_cast<const float4*>(Wr + i*4);
      *reinterpret_cast<ushort4*>(wd + i*4) = f4bf(v);
    }
  }
  __syncthreads();
  int w = t >> 6, lane = t & 63;
  int quad = lane >> 4, mr = lane & 15;
  float4v acc[4] = {};
  const unsigned short* Abase = Asm + (w*16 + mr)*LDA + quad*8;
  const unsigned short* Wbase = Wsm + mr*LDA + quad*8;
  #pragma unroll
  for (int k0 = 0; k0 < 6; k0++) {
    short8 a = *reinterpret_cast<const short8*>(Abase + k0*32);
    #pragma unroll
    for (int ct = 0; ct < 4; ct++) {
      short8 b = *reinterpret_cast<const short8*>(Wbase + ct*16*LDA + k0*32);
      acc[ct] = __builtin_amdgcn_mfma_f32_16x16x32_bf16(a, b, acc[ct], 0, 0, 0);
    }
  }
  #pragma unroll
  for (int ct = 0; ct < 4; ct++) {
    #pragma unroll
    for (int reg = 0; reg < 4; reg++) {
      int rr = row0 + w*16 + quad*4 + reg;
      if (rr < jb.n) {
        int cc = col0 + ct*16 + mr;
        jb.out[(size_t)rr*HID + cc] = f2bf(acc[ct][reg] + jb.bias[cc]);
      }
    }
  }
}

// ---------------- batched K=192 GEMM (3 jobs, fp32 out) — pooling q/k/v ----
struct PoolJob { const float* A; const float* W; const float* bias;
                 float* out; int n; };
struct PoolJobs { PoolJob j[3]; int rb[4]; };
__global__ __launch_bounds__(256)
void k_gemm3(PoolJobs jobs)
{
  int bx = blockIdx.x;
  int z = 0;
  if (bx >= jobs.rb[1]) z = 1;
  if (bx >= jobs.rb[2]) z = 2;
  PoolJob jb = jobs.j[z];
  int row0 = (bx - jobs.rb[z]) * 64;
  __shared__ __align__(16) unsigned short Asm[64*LDA];
  __shared__ __align__(16) unsigned short Wsm[64*LDA];
  int t = threadIdx.x;
  int col0 = blockIdx.y * 64;
  {
    int r = t >> 2, seg = t & 3;
    int gr = row0 + r;
    unsigned short* ad = Asm + r*LDA + seg*48;
    if (gr < jb.n) {
      const float* Ar = jb.A + (size_t)gr*HID + seg*48;
      #pragma unroll
      for (int i = 0; i < 12; i++) {
        float4 v = *reinterpret_cast<const float4*>(Ar + i*4);
        *reinterpret_cast<ushort4*>(ad + i*4) = f4bf(v);
      }
    } else {
      ushort4 zz = make_ushort4(0,0,0,0);
      #pragma unroll
      for (int i = 0; i < 12; i++) *reinterpret_cast<ushort4*>(ad + i*4) = zz;
    }
    const float* Wr = jb.W + (size_t)(col0 + r)*HID + seg*48;
    unsigned short* wd = Wsm + r*LDA + seg*48;
    #pragma unroll
    for (int i = 0; i < 12; i++) {
      float4 v = *reinterpret_cast<const float4*>(Wr + i*4);
      *reinterpret_cast<ushort4*>(wd + i*4) = f4bf(v);
    }
  }
  __syncthreads();
  int w = t >> 6, lane = t & 63;
  int quad = lane >> 4, mr = lane & 15;
  float4v acc[4] = {};
  const unsigned short* Abase = Asm + (w*16 + mr)*LDA + quad*8;
  const unsigned short* Wbase = Wsm + mr*LDA + quad*8;
  #pragma unroll
  for (int k0 = 0; k0 < 6; k0++) {
    short8 a = *reinterpret_cast<const short8*>(Abase + k0*32);
    #pragma unroll
    for (int ct = 0; ct < 4; ct++) {
      short8 b = *reinterpret_cast<const short8*>(Wbase + ct*16*LDA + k0*32);
      acc[ct] = __builtin_amdgcn_mfma_f32_16x16x32_bf16(a, b, acc[ct], 0, 0, 0);
    }
  }
  #pragma unroll
  for (int ct = 0; ct < 4; ct++) {
    #pragma unroll
    for (int reg = 0; reg < 4; reg++) {
      int rr = row0 + w*16 + quad*4 + reg;
      if (rr < jb.n) {
        int cc = col0 + ct*16 + mr;
        jb.out[(size_t)rr*HID + cc] = acc[ct][reg] + jb.bias[cc];
      }
    }
  }
}

// ---------------- batched dual GEMM (2 jobs): out = A1·W1^T(rs) + A2·W2^T + b
struct G2Job { const float* A1; const float* rs1; const float* W1;
               const float* A2; const float* W2; const float* bias;
               float* out; int n; };
struct G2Jobs { G2Job j[2]; int rb[3]; };
__global__ __launch_bounds__(256)
void k_gemm2(G2Jobs jobs)
{
  int bx = blockIdx.x;
  int z = (bx >= jobs.rb[1]) ? 1 : 0;
  G2Job jb = jobs.j[z];
  int row0 = (bx - jobs.rb[z]) * 64;
  __shared__ __align__(16) unsigned short Asm[64*LDA];
  __shared__ __align__(16) unsigned short Wsm[64*LDA];
  int t = threadIdx.x;
  int col0 = blockIdx.y * 64;
  int r = t >> 2, seg = t & 3;
  int w = t >> 6, lane = t & 63;
  int quad = lane >> 4, mr = lane & 15;
  float4v acc[4] = {};
  for (int p = 0; p < 2; p++) {
    if (p) __syncthreads();
    const float* A = p ? jb.A2 : jb.A1;
    const float* W = p ? jb.W2 : jb.W1;
    {
      int gr = row0 + r;
      unsigned short* ad = Asm + r*LDA + seg*48;
      if (gr < jb.n) {
        float sc = (!p && jb.rs1) ? jb.rs1[gr] : 1.0f;
        const float* Ar = A + (size_t)gr*HID + seg*48;
        #pragma unroll
        for (int i = 0; i < 12; i++) {
          float4 v = *reinterpret_cast<const float4*>(Ar + i*4);
          v.x *= sc; v.y *= sc; v.z *= sc; v.w *= sc;
          *reinterpret_cast<ushort4*>(ad + i*4) = f4bf(v);
        }
      } else {
        ushort4 zz = make_ushort4(0,0,0,0);
        #pragma unroll
        for (int i = 0; i < 12; i++) *reinterpret_cast<ushort4*>(ad + i*4) = zz;
      }
      const float* Wr = W + (size_t)(col0 + r)*HID + seg*48;
      unsigned short* wd = Wsm + r*LDA + seg*48;
      #pragma unroll
      for (int i = 0; i < 12; i++) {
        float4 v = *reinterpret_cast<const float4*>(Wr + i*4);
        *reinterpret_cast<ushort4*>(wd + i*4) = f4bf(v);
      }
    }
    __syncthreads();
    const unsigned short* Abase = Asm + (w*16 + mr)*LDA + quad*8;
    const unsigned short* Wbase = Wsm + mr*LDA + quad*8;
    #pragma unroll
    for (int k0 = 0; k0 < 6; k0++) {
      short8 a = *reinterpret_cast<const short8*>(Abase + k0*32);
      #pragma unroll
      for (int ct = 0; ct < 4; ct++) {
        short8 b = *reinterpret_cast<const short8*>(Wbase + ct*16*LDA + k0*32);
        acc[ct] = __builtin_amdgcn_mfma_f32_16x16x32_bf16(a, b, acc[ct], 0, 0, 0);
      }
    }
  }
  #pragma unroll
  for (int ct = 0; ct < 4; ct++) {
    #pragma unroll
    for (int reg = 0; reg < 4; reg++) {
      int rr = row0 + w*16 + quad*4 + reg;
      if (rr < jb.n) {
        int cc = col0 + ct*16 + mr;
        jb.out[(size_t)rr*HID + cc] = acc[ct][reg] + jb.bias[cc];
      }
    }
  }
}

// ---------------- unified K-loop MFMA GEMM (17 jobs: s->g + split-K g->s) --
#define BKG 128
#define LDG 136
struct KJob { const unsigned short* A; int lda;
              const unsigned short* W; int ldw;
              float* out; int n; int kbeg; int kend; };
struct KJobs { KJob j[17]; int rb[18]; };
__global__ __launch_bounds__(256)
void k_gemm_k(KJobs jobs)
{
  int bx = blockIdx.x;
  int z = 0;
  for (int q = 1; q < 17; q++) if (bx >= jobs.rb[q]) z = q;
  KJob jb = jobs.j[z];
  int row0 = (bx - jobs.rb[z]) * 64;
  __shared__ __align__(16) unsigned short Asm[64*LDG];
  __shared__ __align__(16) unsigned short Wsm[64*LDG];
  int t = threadIdx.x;
  int col0 = blockIdx.y * 64;
  int r = t >> 2, seg = t & 3;
  int w = t >> 6, lane = t & 63;
  int quad = lane >> 4, mr = lane & 15;
  float4v acc[4] = {};
  for (int k0 = jb.kbeg; k0 < jb.kend; k0 += BKG) {
    {
      int gr = row0 + r;
      unsigned short* ad = Asm + r*LDG + seg*32;
      if (gr < jb.n) {
        const unsigned short* Ar = jb.A + (size_t)gr*jb.lda + k0 + seg*32;
        #pragma unroll
        for (int i = 0; i < 4; i++) *(uint4*)(ad + i*8) = *(const uint4*)(Ar + i*8);
      } else {
        uint4 zz = make_uint4(0,0,0,0);
        #pragma unroll
        for (int i = 0; i < 4; i++) *(uint4*)(ad + i*8) = zz;
      }
      const unsigned short* Wr = jb.W + (size_t)(col0 + r)*jb.ldw + k0 + seg*32;
      unsigned short* wd = Wsm + r*LDG + seg*32;
      #pragma unroll
      for (int i = 0; i < 4; i++) *(uint4*)(wd + i*8) = *(const uint4*)(Wr + i*8);
    }
    __syncthreads();
    const unsigned short* Abase = Asm + (w*16 + mr)*LDG + quad*8;
    const unsigned short* Wbase = Wsm + mr*LDG + quad*8;
    #pragma unroll
    for (int kk = 0; kk < 4; kk++) {
      short8 a = *(const short8*)(Abase + kk*32);
      #pragma unroll
      for (int ct = 0; ct < 4; ct++) {
        short8 b = *(const short8*)(Wbase + ct*16*LDG + kk*32);
        acc[ct] = __builtin_amdgcn_mfma_f32_16x16x32_bf16(a, b, acc[ct], 0, 0, 0);
      }
    }
    __syncthreads();
  }
  #pragma unroll
  for (int ct = 0; ct < 4; ct++) {
    #pragma unroll
    for (int reg = 0; reg < 4; reg++) {
      int rr = row0 + w*16 + quad*4 + reg;
      if (rr < jb.n) jb.out[(size_t)rr*HID + col0 + ct*16 + mr] = acc[ct][reg];
    }
  }
}

__global__ __launch_bounds__(256)
void k_reduce_sk(const float* __restrict__ part, float* __restrict__ outp, int n){
  int i = blockIdx.x*256 + threadIdx.x;
  if (i >= n*HID) return;
  float s = 0.0f;
  #pragma unroll
  for (int z = 0; z < SPLITK; z++) s += part[(size_t)z*n*HID + i];
  outp[i] = s;
}

// ---------------- batched GATv2: wave-per-dst, LDS-staged gl rows ----------
struct GatJob { const unsigned short* gl; const unsigned short* gr;
                const int* rowptr; const int* col;
                const float* att; const float* bias; float* out; int ndst; int accum; };
struct GatJobs { GatJob j[3]; int bo[4]; };

#define GLS_LD 200   // padded LDS row (ushort) for staged gl
__global__ __launch_bounds__(256)
void k_gat_all(GatJobs jobs)
{
  int bx = blockIdx.x;
  int jz = 0;
  if (bx >= jobs.bo[1]) jz = 1;
  if (bx >= jobs.bo[2]) jz = 2;
  GatJob jb = jobs.j[jz];
  int tid = threadIdx.x;
  int w = tid >> 6, lane = tid & 63;
  int dst = (bx - jobs.bo[jz])*4 + w;
  bool active = dst < jb.ndst;
  __shared__ float attS[HID];
  __shared__ float grS[4][HID];
  __shared__ __align__(16) unsigned short glS[4][16][GLS_LD];
  __shared__ float swS[4][4][16];
  __shared__ float fS[4][4];
  __shared__ float lS[4][4];
  if (tid < HID) attS[tid] = jb.att[tid];
  if (active) {
    const unsigned short* grr = jb.gr + (size_t)dst*HID;
    grS[w][lane]     = bf2f(grr[lane]);
    grS[w][lane+64]  = bf2f(grr[lane+64]);
    grS[w][lane+128] = bf2f(grr[lane+128]);
  }
  __syncthreads();   // attS visibility (all 256 threads reach this)
  if (!active) return;

  int h16 = lane >> 4, j16 = lane & 15;
  int start = jb.rowptr[dst], end = jb.rowptr[dst+1];
  float m = -1e30f, l = 0.0f;
  float acc0 = 0.f, acc1 = 0.f, acc2 = 0.f;
  int hd0 = lane/48, hd1 = (lane+64)/48, hd2 = (lane+128)/48;
  const float* attH = attS + h16*CDIM;
  const float* grH  = grS[w] + h16*CDIM;

  for (int c0 = start; c0 < end; c0 += 16) {
    int nc = min(16, end - c0);
    float sc = -1e30f;
    if (j16 < nc) {
      int s = jb.col[c0 + j16];
      const short8* glv = (const short8*)(jb.gl + (size_t)s*HID + h16*CDIM);
      unsigned short* ls = &glS[w][j16][h16*CDIM];
      float a = 0.0f;
      #pragma unroll
      for (int v8 = 0; v8 < 6; v8++) {
        short8 g8 = glv[v8];
        *(short8*)(ls + v8*8) = g8;     // stage row slice to LDS (wave-local)
        #pragma unroll
        for (int jj = 0; jj < 8; jj++) {
          float v = bf2f((unsigned short)g8[jj]) + grH[v8*8+jj];
          v = v > 0.0f ? v : 0.2f*v;
          a += v * attH[v8*8+jj];
        }
      }
      sc = a;
    }
    float cm = sc;
    cm = fmaxf(cm, __shfl_xor(cm, 1));
    cm = fmaxf(cm, __shfl_xor(cm, 2));
    cm = fmaxf(cm, __shfl_xor(cm, 4));
    cm = fmaxf(cm, __shfl_xor(cm, 8));
    float nm = fmaxf(m, cm);
    float f = __expf(m - nm);          // m=-1e30 -> 0
    l *= f;
    float e = (j16 < nc) ? __expf(sc - nm) : 0.0f;
    swS[w][h16][j16] = e;
    float cl = e;
    cl += __shfl_xor(cl, 1);
    cl += __shfl_xor(cl, 2);
    cl += __shfl_xor(cl, 4);
    cl += __shfl_xor(cl, 8);
    l += cl;
    m = nm;
    if (j16 == 0) fS[w][h16] = f;
    acc0 *= fS[w][hd0]; acc1 *= fS[w][hd1]; acc2 *= fS[w][hd2];
    for (int j = 0; j < nc; j++) {
      acc0 += swS[w][hd0][j] * bf2f(glS[w][j][lane]);
      acc1 += swS[w][hd1][j] * bf2f(glS[w][j][lane+64]);
      acc2 += swS[w][hd2][j] * bf2f(glS[w][j][lane+128]);
    }
  }
  if (j16 == 0) lS[w][h16] = l;
  float* od = jb.out + (size_t)dst*HID;
  float v0 = acc0 / (lS[w][hd0] + 1e-16f) + jb.bias[lane];
  float v1 = acc1 / (lS[w][hd1] + 1e-16f) + jb.bias[lane+64];
  float v2 = acc2 / (lS[w][hd2] + 1e-16f) + jb.bias[lane+128];
  if (jb.accum) { v0 += od[lane]; v1 += od[lane+64]; v2 += od[lane+128]; }
  od[lane] = v0; od[lane+64] = v1; od[lane+128] = v2;
}

// ---------------- batched residual + LayerNorm (3 node types) -------------
__global__ __launch_bounds__(64)
void k_ln3(float* __restrict__ xs, const float* __restrict__ osb,
           float* __restrict__ xg, const float* __restrict__ og,
           float* __restrict__ xp, const float* __restrict__ opb,
           const float* __restrict__ op2,
           const float* __restrict__ LNg, const float* __restrict__ LNb, int l)
{
  int r = blockIdx.x;
  float* x; const float* d1; const float* d2 = nullptr; int typ;
  if (r < N_S)            { x = xs + (size_t)r*HID; d1 = osb + (size_t)r*HID; typ = 0; }
  else if (r < N_S + N_G) { int rr = r - N_S; x = xg + (size_t)rr*HID; d1 = og + (size_t)rr*HID; typ = 1; }
  else                    { int rr = r - N_S - N_G; x = xp + (size_t)rr*HID; d1 = opb + (size_t)rr*HID;
                            d2 = op2 + (size_t)rr*HID; typ = 2; }
  const float* g = LNg + (l*3 + typ)*HID;
  const float* b = LNb + (l*3 + typ)*HID;
  int lane = threadIdx.x;
  float v[3]; float sum = 0.0f;
  #pragma unroll
  for (int j=0;j<3;j++){
    int d = j*64 + lane;
    float t = x[d] + d1[d];
    if (d2) t += d2[d];
    v[j] = t; sum += t;
  }
  #pragma unroll
  for (int o=32;o;o>>=1) sum += __shfl_xor(sum, o);
  float mu = sum * (1.0f/HID);
  float var = 0.0f;
  #pragma unroll
  for (int j=0;j<3;j++){ float dd = v[j]-mu; var += dd*dd; }
  #pragma unroll
  for (int o=32;o;o>>=1) var += __shfl_xor(var, o);
  var *= (1.0f/HID);
  float inv = rsqrtf(var + 1e-5f);
  #pragma unroll
  for (int j=0;j<3;j++){
    int d = j*64 + lane;
    x[d] = (v[j]-mu)*inv*g[d] + b[d];
  }
}

// ---------------- pooling attention: one block per (q,h) ----------------
__global__ __launch_bounds__(256)
void k_pool_attn(const float* __restrict__ qb, const float* __restrict__ kb,
                 const float* __restrict__ vb, float* __restrict__ ob)
{
  int h = blockIdx.x & 3;
  int q = blockIdx.x >> 2;
  __shared__ float prob[N_S];
  __shared__ float red[256];
  int t = threadIdx.x;
  const float* qrow = qb + (size_t)q*HID + h*CDIM;
  const float scale = 0.14433756729740643f;
  for (int n = t; n < N_S; n += 256) {
    const float* krow = kb + (size_t)n*HID + h*CDIM;
    float s = 0.0f;
    #pragma unroll 8
    for (int c=0;c<CDIM;c++) s += qrow[c]*krow[c];
    prob[n] = s * scale;
  }
  __syncthreads();
  float m = -1e30f;
  for (int n=t;n<N_S;n+=256) m = fmaxf(m, prob[n]);
  red[t] = m; __syncthreads();
  for (int s2=128;s2;s2>>=1){ if (t<s2) red[t]=fmaxf(red[t],red[t+s2]); __syncthreads(); }
  m = red[0]; __syncthreads();
  float sum = 0.0f;
  for (int n=t;n<N_S;n+=256){ float e=__expf(prob[n]-m); prob[n]=e; sum+=e; }
  red[t] = sum; __syncthreads();
  for (int s2=128;s2;s2>>=1){ if (t<s2) red[t]+=red[t+s2]; __syncthreads(); }
  float inv = 1.0f/red[0];
  __syncthreads();
  if (t < CDIM) {
    float acc = 0.0f;
    for (int n=0;n<N_S;n++) acc += prob[n]*vb[(size_t)n*HID + h*CDIM + t];
    ob[(size_t)q*HID + h*CDIM + t] = acc * inv;
  }
}

// ---------------- tail ----------------
__global__ __launch_bounds__(192)
void k_tail(const float* __restrict__ ob2,
            const float* ffw1, const float* ffb1,
            const float* ffw2, const float* ffb2,
            const float* lng, const float* lnb,
            const float* pw, const float* pb,
            void* __restrict__ outp, const int* __restrict__ flag)
{
  __shared__ float pooled[HID];
  __shared__ float hh[HID];
  __shared__ float stats[2];
  int t = threadIdx.x;
  float a = 0.0f;
  for (int q=0;q<NQd;q++) a += ob2[q*HID + t];
  pooled[t] = a * (1.0f/NQd);
  __syncthreads();
  float s1 = ffb1[t];
  for (int k=0;k<HID;k++) s1 += pooled[k]*ffw1[t*HID+k];
  hh[t] = fmaxf(s1, 0.0f);
  __syncthreads();
  float s2 = ffb2[t];
  for (int k=0;k<HID;k++) s2 += hh[k]*ffw2[t*HID+k];
  __syncthreads();
  hh[t] = s2;
  __syncthreads();
  if (t == 0) {
    float mu=0.0f; for (int k=0;k<HID;k++) mu += hh[k];
    mu *= (1.0f/HID);
    float v=0.0f; for (int k=0;k<HID;k++){ float d=hh[k]-mu; v+=d*d; }
    v *= (1.0f/HID);
    stats[0]=mu; stats[1]=rsqrtf(v + 1e-5f);
  }
  __syncthreads();
  pooled[t] = (hh[t]-stats[0])*stats[1]*lng[t] + lnb[t];
  __syncthreads();
  if (t < OUTD) {
    float acc = pb[t];
    for (int k=0;k<HID;k++) acc += pooled[k]*pw[t*HID+k];
    if (flag[0]) ((float*)outp)[t] = acc;
    else         ((unsigned short*)outp)[t] = f2bf(acc);
  }
}

// =====================================================================
extern "C" void kernel_launch(void* const* d_in, const int* in_sizes, int n_in,
                              void* d_out, int out_size, void* d_ws, size_t ws_size,
                              hipStream_t stream)
{
  const int* sg_src = (const int*)d_in[3];
  const int* sg_dst = (const int*)d_in[4];
  const int* gp_src = (const int*)d_in[5];
  const int* gp_dst = (const int*)d_in[6];
  const int* pp_src = (const int*)d_in[7];
  const int* pp_dst = (const int*)d_in[8];

  float* base = (float*)d_ws;
  size_t off = 0;
  auto alloc = [&](size_t nf){ nf = (nf + 3) & ~(size_t)3; float* p = base + off; off += nf; return p; };
  int*   flag = (int*)alloc(4);
  float* xs   = alloc((size_t)N_S*HID);
  float* xg   = alloc((size_t)N_G*HID);
  float* xp   = alloc((size_t)N_P*HID);
  float* qin  = alloc((size_t)NQd*HID);
  float* Wsl  = alloc(2*2*HID*HID); float* bsl = alloc(2*2*HID); float* Wsr = alloc(2*2*HID*HID);
  float* Wgl  = alloc(2*3*HID*HID); float* bgl = alloc(2*3*HID);
  float* Wgr  = alloc(2*3*HID*HID); float* bgr = alloc(2*3*HID);
  float* Agat = alloc(2*3*HEADS*CDIM); float* Bgat = alloc(2*3*HID);
  float* LNg  = alloc(2*3*HID); float* LNb = alloc(2*3*HID);
  float* Pinw = alloc(3*HID*HID); float* Pinb = alloc(3*HID);
  float* Poutw= alloc(HID*HID);   float* Poutb= alloc(HID);
  float* Fw1  = alloc(HID*HID);   float* Fb1  = alloc(HID);
  float* Fw2  = alloc(HID*HID);   float* Fb2  = alloc(HID);
  float* PLg  = alloc(HID);       float* PLb  = alloc(HID);
  float* Pw   = alloc(OUTD*HID);  float* Pb   = alloc(OUTD);
  // runtime buffers
  float* agg  = alloc((size_t)N_G*HID);
  float* aggS = alloc((size_t)N_S*HID);
  float* og   = alloc((size_t)N_G*HID);
  float* osb  = alloc((size_t)N_S*HID);
  float* opb  = alloc((size_t)N_P*HID);
  float* op2  = alloc((size_t)N_P*HID);
  // bf16 GAT node transforms
  unsigned short* glGb  = (unsigned short*)alloc((size_t)N_G*HID/2);
  unsigned short* grGb  = (unsigned short*)alloc((size_t)N_G*HID/2);
  unsigned short* grP0b = (unsigned short*)alloc((size_t)N_P*HID/2);
  unsigned short* glP1b = (unsigned short*)alloc((size_t)N_P*HID/2);
  unsigned short* glP2b = (unsigned short*)alloc((size_t)N_P*HID/2);
  unsigned short* grP2b = (unsigned short*)alloc((size_t)N_P*HID/2);
  float* qbuf = alloc((size_t)NQd*HID);
  float* kbuf = alloc((size_t)N_S*HID);
  float* vbuf = alloc((size_t)N_S*HID);
  float* obuf = alloc((size_t)NQd*HID);
  float* ob2  = alloc((size_t)NQd*HID);
  // dense SAGE matrices
  int*            CntGi = (int*)alloc((size_t)N_G*N_S);
  unsigned short* CntGb = (unsigned short*)alloc((size_t)N_G*N_S/2);
  unsigned short* CntSb = (unsigned short*)alloc((size_t)N_S*LDK/2);
  unsigned short* xsTb  = (unsigned short*)alloc((size_t)HID*N_S/2);
  unsigned short* xgTb  = (unsigned short*)alloc((size_t)HID*LDK/2);
  float* part = alloc((size_t)SPLITK*N_S*HID);
  float* invdegG = alloc(N_G);
  float* invdegS = alloc(N_S);
  // CSR storage (GAT graphs)
  int* degAll = (int*)alloc(2*N_P + N_G + 4);
  int* curAll = (int*)alloc(2*N_P + N_G + 4);
  int* rp_gp_p = (int*)alloc(N_P+2);  int* col_gp_p = (int*)alloc(NE_GP);
  int* rp_gp_g = (int*)alloc(N_G+2);  int* col_gp_g = (int*)alloc(NE_GP);
  int* rp_pp_p = (int*)alloc(N_P+2);  int* col_pp_p = (int*)alloc(NE_PP);
  (void)ws_size; (void)in_sizes; (void)n_in; (void)out_size;

  k_detect<<<1,256,0,stream>>>((const unsigned int*)d_in[0], flag);

  // ---- batched input conversion ----
  {
    LoadTable tab;
    int k = 0;
    auto add = [&](int i, float* dst, int n){ tab.d[k].src = d_in[i]; tab.d[k].dst = dst; tab.d[k].n = n; k++; };
    add(0,  xs,  N_S*HID);  add(1,  xg,  N_G*HID);  add(2,  xp,  N_P*HID);
    add(9,  Wsl, 2*2*HID*HID); add(10, bsl, 2*2*HID); add(11, Wsr, 2*2*HID*HID);
    add(12, Wgl, 2*3*HID*HID); add(13, bgl, 2*3*HID);
    add(14, Wgr, 2*3*HID*HID); add(15, bgr, 2*3*HID);
    add(16, Agat, 2*3*HEADS*CDIM); add(17, Bgat, 2*3*HID);
    add(18, LNg, 2*3*HID); add(19, LNb, 2*3*HID);
    add(20, qin, NQd*HID);
    add(21, Pinw, 3*HID*HID); add(22, Pinb, 3*HID);
    add(23, Poutw, HID*HID);  add(24, Poutb, HID);
    add(25, Fw1, HID*HID); add(26, Fb1, HID);
    add(27, Fw2, HID*HID); add(28, Fb2, HID);
    add(29, PLg, HID); add(30, PLb, HID);
    add(31, Pw, OUTD*HID); add(32, Pb, OUTD);
    k_load_all<<<dim3(LOADBX, NLOAD),256,0,stream>>>(tab, flag);
  }

  // ---- dense SAGE counts ----
  hipMemsetAsync(CntGi, 0, (size_t)N_G*N_S*4, stream);
  hipMemsetAsync(degAll, 0, (size_t)(2*N_P + N_G)*4, stream);
  k_cntbuild<<<(NE_SG+255)/256,256,0,stream>>>(sg_src, sg_dst, CntGi, NE_SG);
  k_cvtT<<<dim3(LDK/64, N_S/64),256,0,stream>>>(CntGi, CntGb, CntSb);
  k_rowinv_i<<<(N_G+3)/4,256,0,stream>>>(CntGi, N_S, N_S, N_G, invdegG);
  k_rowinv_h<<<N_S,256,0,stream>>>(CntSb, LDK, LDK, N_S, invdegS);

  // ---- batched CSR build for the 3 GAT graphs ----
  {
    CsrJobs jobs;
    jobs.j[0] = { gp_src, gp_dst, NE_GP, N_P, degAll,           rp_gp_p, curAll,           col_gp_p };
    jobs.j[1] = { gp_dst, gp_src, NE_GP, N_G, degAll+N_P,       rp_gp_g, curAll+N_P,       col_gp_g };
    jobs.j[2] = { pp_src, pp_dst, NE_PP, N_P, degAll+N_P+N_G,   rp_pp_p, curAll+N_P+N_G,   col_pp_p };
    k_hist3<<<dim3((NE_GP+255)/256, 3),256,0,stream>>>(jobs);
    k_scan3<<<3,256,0,stream>>>(jobs);
    k_fill3<<<dim3((NE_GP+255)/256, 3),256,0,stream>>>(jobs);
  }

  const int RB_G = (N_G+63)/64, RB_P = (N_P+63)/64;       // 181, 32
  const int GB_P = (N_P+3)/4,  GB_G = (N_G+3)/4;          // 500, 2890

  for (int l=0; l<2; l++) {
    // both feature transposes in one dispatch
    {
      TransJobs tj;
      tj.inA = xs; tj.outA = xsTb; tj.nA = N_S; tj.ldoA = N_S; tj.rbA = 8;
      tj.inB = xg; tj.outB = xgTb; tj.nB = N_G; tj.ldoB = LDK;
      k_transpose2<<<dim3(8 + LDK/64, 3),256,0,stream>>>(tj);
    }
    // SAGE aggregations: s->g (K=512) + split-K g->s, one dispatch
    {
      KJobs kj;
      kj.j[0] = { CntGb, N_S, xsTb, N_S, agg, N_G, 0, N_S };
      kj.rb[0] = 0; kj.rb[1] = RB_G;
      for (int z = 0; z < SPLITK; z++) {
        kj.j[1+z] = { CntSb, LDK, xgTb, LDK, part + (size_t)z*N_S*HID, N_S,
                      z*CHUNKK, (z+1)*CHUNKK };
        kj.rb[2+z] = kj.rb[1+z] + 8;
      }
      k_gemm_k<<<dim3(kj.rb[17],3),256,0,stream>>>(kj);
    }
    k_reduce_sk<<<(N_S*HID+255)/256,256,0,stream>>>(part, aggS, N_S);
    // both SAGE weight GEMMs (og, osb) in one dispatch
    {
      G2Jobs g2;
      g2.j[0] = { agg,  invdegG, Wsl + (size_t)(l*2+0)*HID*HID,
                  xg, Wsr + (size_t)(l*2+0)*HID*HID, bsl + (l*2+0)*HID, og,  N_G };
      g2.j[1] = { aggS, invdegS, Wsl + (size_t)(l*2+1)*HID*HID,
                  xs, Wsr + (size_t)(l*2+1)*HID*HID, bsl + (l*2+1)*HID, osb, N_S };
      g2.rb[0] = 0; g2.rb[1] = RB_G; g2.rb[2] = RB_G + (N_S+63)/64;
      k_gemm2<<<dim3(g2.rb[2],3),256,0,stream>>>(g2);
    }
    // GAT: 6 node transforms in one flat dispatch (bf16 outputs)
    {
      GemmJobs gj;
      int w0 = l*3+0, w1 = l*3+1, w2 = l*3+2;
      gj.j[0] = { xg, Wgl + (size_t)w0*HID*HID, bgl + w0*HID, glGb,  N_G };
      gj.j[1] = { xp, Wgr + (size_t)w0*HID*HID, bgr + w0*HID, grP0b, N_P };
      gj.j[2] = { xp, Wgl + (size_t)w1*HID*HID, bgl + w1*HID, glP1b, N_P };
      gj.j[3] = { xg, Wgr + (size_t)w1*HID*HID, bgr + w1*HID, grGb,  N_G };
      gj.j[4] = { xp, Wgl + (size_t)w2*HID*HID, bgl + w2*HID, glP2b, N_P };
      gj.j[5] = { xp, Wgr + (size_t)w2*HID*HID, bgr + w2*HID, grP2b, N_P };
      int nrb[6] = { RB_G, RB_P, RB_P, RB_G, RB_P, RB_P };
      gj.rb[0] = 0;
      for (int q = 0; q < 6; q++) gj.rb[q+1] = gj.rb[q] + nrb[q];
      k_gemm6<<<dim3(gj.rb[6],3),256,0,stream>>>(gj);
    }
    // GAT: 3 edge passes in one flat dispatch (wave-per-destination)
    {
      GatJobs gt;
      int w0 = l*3+0, w1 = l*3+1, w2 = l*3+2;
      gt.j[0] = { glGb,  grP0b, rp_gp_p, col_gp_p, Agat + (size_t)w0*HID, Bgat + (size_t)w0*HID, opb, N_P, 0 };
      gt.j[1] = { glP1b, grGb,  rp_gp_g, col_gp_g, Agat + (size_t)w1*HID, Bgat + (size_t)w1*HID, og,  N_G, 1 };
      gt.j[2] = { glP2b, grP2b, rp_pp_p, col_pp_p, Agat + (size_t)w2*HID, Bgat + (size_t)w2*HID, op2, N_P, 0 };
      gt.bo[0] = 0; gt.bo[1] = GB_P; gt.bo[2] = GB_P + GB_G; gt.bo[3] = GB_P + GB_G + GB_P;
      k_gat_all<<<dim3(gt.bo[3]),256,0,stream>>>(gt);
    }
    // residual + LN, all node types in one dispatch
    k_ln3<<<N_S+N_G+N_P,64,0,stream>>>(xs, osb, xg, og, xp, opb, op2, LNg, LNb, l);
  }

  // ---- pooling: q/k/v in one dispatch ----
  {
    PoolJobs pj;
    pj.j[0] = { qin, Pinw,                     Pinb,         qbuf, NQd };
    pj.j[1] = { xs,  Pinw + (size_t)HID*HID,   Pinb + HID,   kbuf, N_S };
    pj.j[2] = { xs,  Pinw + (size_t)2*HID*HID, Pinb + 2*HID, vbuf, N_S };
    pj.rb[0] = 0; pj.rb[1] = 1; pj.rb[2] = 1 + (N_S+63)/64; pj.rb[3] = pj.rb[2] + (N_S+63)/64;
    k_gemm3<<<dim3(pj.rb[3],3),256,0,stream>>>(pj);
  }
  k_pool_attn<<<NQd*HEADS,256,0,stream>>>(qbuf, kbuf, vbuf, obuf);
  k_gemm<<<dim3(1,3),256,0,stream>>>(obuf, Poutw, Poutb, ob2, NQd);
  k_tail<<<1,HID,0,stream>>>(ob2, Fw1, Fb1, Fw2, Fb2, PLg, PLb, Pw, Pb, d_out, flag);
}

// Round 15
// 612.995 us; speedup vs baseline: 1.2656x; 1.0412x over previous
//
#include <hip/hip_runtime.h>

#define N_S 512
#define N_G 11560
#define N_P 2000
#define NE_SG 1000000
#define NE_GP 200000
#define NE_PP 50000
#define HID 192
#define HEADS 4
#define CDIM 48
#define NQd 20
#define OUTD 128
#define LDK 12288
#define SPLITK 16
#define CHUNKK 768

typedef __attribute__((ext_vector_type(8))) short short8;
typedef __attribute__((ext_vector_type(4))) float float4v;

__device__ __forceinline__ float bf2f(unsigned short u){
  union { unsigned int i; float f; } x; x.i = ((unsigned int)u) << 16; return x.f;
}
__device__ __forceinline__ unsigned short f2bf(float f){
  union { float f; unsigned int i; } u; u.f = f;
  unsigned int r = u.i + 0x7FFFu + ((u.i >> 16) & 1u);
  return (unsigned short)(r >> 16);
}
__device__ __forceinline__ ushort4 f4bf(float4 v){
  return make_ushort4(f2bf(v.x), f2bf(v.y), f2bf(v.z), f2bf(v.w));
}

// ---------------- dtype detection (flag=1 fp32, flag=0 bf16) ----------------
__global__ __launch_bounds__(256) void k_detect(const unsigned int* __restrict__ raw,
                                                int* __restrict__ flag){
  __shared__ int cnt;
  if (threadIdx.x == 0) cnt = 0;
  __syncthreads();
  int c = 0;
  for (int i = threadIdx.x; i < 2048; i += 256) {
    float f = __uint_as_float(raw[i]);
    float a = fabsf(f);
    if (f == f && a > 1e-4f && a < 1000.0f) c++;
  }
  atomicAdd(&cnt, c);
  __syncthreads();
  if (threadIdx.x == 0) flag[0] = (cnt >= 1024) ? 1 : 0;
}

// ---------------- batched input load (27 tensors, grid-stride) ----------
#define NLOAD 27
#define LOADBX 2048
struct LoadDesc { const void* src; float* dst; unsigned short* dst16; int n; };
struct LoadTable { LoadDesc d[NLOAD]; };
__global__ __launch_bounds__(256)
void k_load_all(LoadTable tab, const int* __restrict__ flag){
  LoadDesc de = tab.d[blockIdx.y];
  int fp32 = flag[0];
  unsigned short* m = de.dst16;
  for (int i = blockIdx.x*256 + threadIdx.x; i < de.n; i += LOADBX*256) {
    float v = fp32 ? ((const float*)de.src)[i] : bf2f(((const unsigned short*)de.src)[i]);
    de.dst[i] = v;
    if (m) m[i] = f2bf(v);
  }
}

// ---------------- dense count matrix (CntG only; CntS derived) -------------
__global__ __launch_bounds__(256)
void k_cntbuild(const int* __restrict__ src, const int* __restrict__ dst,
                int* __restrict__ cg, int E){
  int i = blockIdx.x*256 + threadIdx.x;
  if (i >= E) return;
  atomicAdd(&cg[(size_t)dst[i]*N_S + src[i]], 1);
}

// convert CntG(int)->bf16 and write transposed bf16 CntS [512 x LDK] (zero-pad)
__global__ __launch_bounds__(256)
void k_cvtT(const int* __restrict__ cg, unsigned short* __restrict__ bfA,
            unsigned short* __restrict__ bfB){
  __shared__ unsigned short tile[64][68];
  int g0 = blockIdx.x*64, s0 = blockIdx.y*64;
  int t = threadIdx.x; int r = t>>2, seg = t&3;
  int g = g0 + r;
  if (g < N_G) {
    const int* row = cg + (size_t)g*N_S + s0 + seg*16;
    unsigned short* arow = bfA + (size_t)g*N_S + s0 + seg*16;
    #pragma unroll
    for (int i=0;i<16;i++){
      unsigned short v = f2bf((float)row[i]);
      tile[r][seg*16+i] = v;
      arow[i] = v;
    }
  } else {
    #pragma unroll
    for (int i=0;i<16;i++) tile[r][seg*16+i] = 0;
  }
  __syncthreads();
  int s = s0 + r;
  unsigned short* brow = bfB + (size_t)s*LDK + g0 + seg*16;
  #pragma unroll
  for (int i=0;i<16;i++) brow[i] = tile[seg*16+i][r];
}

__global__ __launch_bounds__(256)
void k_rowinv_i(const int* __restrict__ A, int lda, int cols, int n,
                float* __restrict__ outp){
  int row = blockIdx.x*4 + (threadIdx.x >> 6);
  if (row >= n) return;
  int lane = threadIdx.x & 63;
  const int* Ar = A + (size_t)row*lda;
  float s = 0.0f;
  for (int c = lane; c < cols; c += 64) s += (float)Ar[c];
  #pragma unroll
  for (int o = 32; o; o >>= 1) s += __shfl_xor(s, o);
  if (lane == 0) outp[row] = 1.0f / fmaxf(s, 1.0f);
}
// block-per-row vectorized bf16 row-sum
__global__ __launch_bounds__(256)
void k_rowinv_h(const unsigned short* __restrict__ A, int lda, int cols, int n,
                float* __restrict__ outp){
  int row = blockIdx.x;
  if (row >= n) return;
  int t = threadIdx.x;
  const short8* Av = (const short8*)(A + (size_t)row*lda);
  float s = 0.0f;
  for (int i = t; i < cols/8; i += 256) {
    short8 v = Av[i];
    #pragma unroll
    for (int j = 0; j < 8; j++) s += bf2f((unsigned short)v[j]);
  }
  #pragma unroll
  for (int o = 32; o; o >>= 1) s += __shfl_xor(s, o);
  __shared__ float red[4];
  int w = t >> 6, lane = t & 63;
  if (lane == 0) red[w] = s;
  __syncthreads();
  if (t == 0) {
    float tot = red[0] + red[1] + red[2] + red[3];
    outp[row] = 1.0f / fmaxf(tot, 1.0f);
  }
}

// ---------------- dual transpose [n x 192] fp32 -> [192 x ldo] bf16 --------
struct TransJobs { const float* inA; unsigned short* outA; int nA; int ldoA; int rbA;
                   const float* inB; unsigned short* outB; int nB; int ldoB; };
__global__ __launch_bounds__(256)
void k_transpose2(TransJobs tj){
  const float* in; unsigned short* outp; int n, ldo, r0;
  int bx = blockIdx.x;
  if (bx < tj.rbA) { in = tj.inA; outp = tj.outA; n = tj.nA; ldo = tj.ldoA; r0 = bx*64; }
  else             { in = tj.inB; outp = tj.outB; n = tj.nB; ldo = tj.ldoB; r0 = (bx - tj.rbA)*64; }
  __shared__ float tile[64][65];
  int c0 = blockIdx.y*64;
  int t = threadIdx.x;
  int r = t >> 2, seg = t & 3;
  int grr = r0 + r;
  if (grr < n) {
    #pragma unroll
    for (int i = 0; i < 4; i++) {
      float4 v = *(const float4*)(in + (size_t)grr*HID + c0 + seg*16 + i*4);
      tile[r][seg*16+i*4+0] = v.x; tile[r][seg*16+i*4+1] = v.y;
      tile[r][seg*16+i*4+2] = v.z; tile[r][seg*16+i*4+3] = v.w;
    }
  } else {
    #pragma unroll
    for (int i = 0; i < 16; i++) tile[r][seg*16+i] = 0.0f;
  }
  __syncthreads();
  int w = t >> 6, lane = t & 63;
  if (r0 + lane < ldo) {
    #pragma unroll
    for (int j = 0; j < 16; j++) {
      int c = w*16 + j;
      outp[(size_t)(c0+c)*ldo + r0 + lane] = f2bf(tile[lane][c]);
    }
  }
}

// ---------------- batched CSR build (3 graphs) ----------------
struct CsrJob { const int* src; const int* dst; int E; int n;
                int* deg; int* rowptr; int* cursor; int* col; };
struct CsrJobs { CsrJob j[3]; };

__global__ __launch_bounds__(256) void k_hist3(CsrJobs jobs){
  CsrJob jb = jobs.j[blockIdx.y];
  int i = blockIdx.x*256 + threadIdx.x;
  if (i < jb.E) atomicAdd(&jb.deg[jb.dst[i]], 1);
}
__global__ __launch_bounds__(256) void k_scan3(CsrJobs jobs){
  CsrJob jb = jobs.j[blockIdx.x];
  __shared__ int part[256];
  __shared__ int pre[256];
  int t = threadIdx.x;
  int n = jb.n;
  int C = (n + 255) >> 8;
  int lo = t*C, hi = min(n, lo + C);
  int s = 0;
  for (int i = lo; i < hi; i++) s += jb.deg[i];
  part[t] = s;
  __syncthreads();
  if (t == 0) {
    int acc = 0;
    for (int i = 0; i < 256; i++) { pre[i] = acc; acc += part[i]; }
    jb.rowptr[n] = acc;
  }
  __syncthreads();
  int run = pre[t];
  for (int i = lo; i < hi; i++) {
    jb.rowptr[i] = run; jb.cursor[i] = run; run += jb.deg[i];
  }
}
__global__ __launch_bounds__(256) void k_fill3(CsrJobs jobs){
  CsrJob jb = jobs.j[blockIdx.y];
  int i = blockIdx.x*256 + threadIdx.x;
  if (i >= jb.E) return;
  int pos = atomicAdd(&jb.cursor[jb.dst[i]], 1);
  jb.col[pos] = jb.src[i];
}

// ---------------- MFMA bf16 GEMM (K=192, fp32 A/W): out = A·W^T + bias ----
#define LDA 200
__global__ __launch_bounds__(256)
void k_gemm(const float* __restrict__ A,
            const float* __restrict__ W, const float* __restrict__ bias,
            float* __restrict__ outp, int n)
{
  __shared__ __align__(16) unsigned short Asm[64*LDA];
  __shared__ __align__(16) unsigned short Wsm[64*LDA];
  int t = threadIdx.x;
  int row0 = blockIdx.x * 64;
  int col0 = blockIdx.y * 64;
  {
    int r = t >> 2, seg = t & 3;
    int gr = row0 + r;
    unsigned short* ad = Asm + r*LDA + seg*48;
    if (gr < n) {
      const float* Ar = A + (size_t)gr*HID + seg*48;
      #pragma unroll
      for (int i = 0; i < 12; i++) {
        float4 v = *reinterpret_cast<const float4*>(Ar + i*4);
        *reinterpret_cast<ushort4*>(ad + i*4) = f4bf(v);
      }
    } else {
      ushort4 z = make_ushort4(0,0,0,0);
      #pragma unroll
      for (int i = 0; i < 12; i++) *reinterpret_cast<ushort4*>(ad + i*4) = z;
    }
    const float* Wr = W + (size_t)(col0 + r)*HID + seg*48;
    unsigned short* wd = Wsm + r*LDA + seg*48;
    #pragma unroll
    for (int i = 0; i < 12; i++) {
      float4 v = *reinterpret_cast<const float4*>(Wr + i*4);
      *reinterpret_cast<ushort4*>(wd + i*4) = f4bf(v);
    }
  }
  __syncthreads();
  int w = t >> 6, lane = t & 63;
  int quad = lane >> 4, mr = lane & 15;
  float4v acc[4] = {};
  const unsigned short* Abase = Asm + (w*16 + mr)*LDA + quad*8;
  const unsigned short* Wbase = Wsm + mr*LDA + quad*8;
  #pragma unroll
  for (int k0 = 0; k0 < 6; k0++) {
    short8 a = *reinterpret_cast<const short8*>(Abase + k0*32);
    #pragma unroll
    for (int ct = 0; ct < 4; ct++) {
      short8 b = *reinterpret_cast<const short8*>(Wbase + ct*16*LDA + k0*32);
      acc[ct] = __builtin_amdgcn_mfma_f32_16x16x32_bf16(a, b, acc[ct], 0, 0, 0);
    }
  }
  #pragma unroll
  for (int ct = 0; ct < 4; ct++) {
    #pragma unroll
    for (int reg = 0; reg < 4; reg++) {
      int rr = row0 + w*16 + quad*4 + reg;
      if (rr < n) {
        int cc = col0 + ct*16 + mr;
        outp[(size_t)rr*HID + cc] = acc[ct][reg] + bias[cc];
      }
    }
  }
}

// ---------------- batched K=192 GEMM (6 jobs, bf16 A, bf16 out) ------------
struct GemmJob { const unsigned short* A; const float* W; const float* bias;
                 unsigned short* out; int n; };
struct GemmJobs { GemmJob j[6]; int rb[7]; };
__global__ __launch_bounds__(256)
void k_gemm6(GemmJobs jobs)
{
  int bx = blockIdx.x;
  int z = 0;
  #pragma unroll
  for (int q = 1; q < 6; q++) if (bx >= jobs.rb[q]) z = q;
  GemmJob jb = jobs.j[z];
  int row0 = (bx - jobs.rb[z]) * 64;
  __shared__ __align__(16) unsigned short Asm[64*LDA];
  __shared__ __align__(16) unsigned short Wsm[64*LDA];
  int t = threadIdx.x;
  int col0 = blockIdx.y * 64;
  {
    int r = t >> 2, seg = t & 3;
    int gr = row0 + r;
    unsigned short* ad = Asm + r*LDA + seg*48;
    if (gr < jb.n) {
      const unsigned short* Ar = jb.A + (size_t)gr*HID + seg*48;
      #pragma unroll
      for (int i = 0; i < 6; i++) *(uint4*)(ad + i*8) = *(const uint4*)(Ar + i*8);
    } else {
      uint4 zz = make_uint4(0,0,0,0);
      #pragma unroll
      for (int i = 0; i < 6; i++) *(uint4*)(ad + i*8) = zz;
    }
    const float* Wr = jb.W + (size_t)(col0 + r)*HID + seg*48;
    unsigned short* wd = Wsm + r*LDA + seg*48;
    #pragma unroll
    for (int i = 0; i < 12; i++) {
      float4 v = *reinterpret_cast<const float4*>(Wr + i*4);
      *reinterpret_cast<ushort4*>(wd + i*4) = f4bf(v);
    }
  }
  __syncthreads();
  int w = t >> 6, lane = t & 63;
  int quad = lane >> 4, mr = lane & 15;
  float4v acc[4] = {};
  const unsigned short* Abase = Asm + (w*16 + mr)*LDA + quad*8;
  const unsigned short* Wbase = Wsm + mr*LDA + quad*8;
  #pragma unroll
  for (int k0 = 0; k0 < 6; k0++) {
    short8 a = *reinterpret_cast<const short8*>(Abase + k0*32);
    #pragma unroll
    for (int ct = 0; ct < 4; ct++) {
      short8 b = *reinterpret_cast<const short8*>(Wbase + ct*16*LDA + k0*32);
      acc[ct] = __builtin_amdgcn_mfma_f32_16x16x32_bf16(a, b, acc[ct], 0, 0, 0);
    }
  }
  #pragma unroll
  for (int ct = 0; ct < 4; ct++) {
    #pragma unroll
    for (int reg = 0; reg < 4; reg++) {
      int rr = row0 + w*16 + quad*4 + reg;
      if (rr < jb.n) {
        int cc = col0 + ct*16 + mr;
        jb.out[(size_t)rr*HID + cc] = f2bf(acc[ct][reg] + jb.bias[cc]);
      }
    }
  }
}

// ---------------- batched K=192 GEMM (3 jobs, bf16 A, fp32 out) — pooling --
struct PoolJob { const unsigned short* A; const float* W; const float* bias;
                 float* out; int n; };
struct PoolJobs { PoolJob j[3]; int rb[4]; };
__global__ __launch_bounds__(256)
void k_gemm3(PoolJobs jobs)
{
  int bx = blockIdx.x;
  int z = 0;
  if (bx >= jobs.rb[1]) z = 1;
  if (bx >= jobs.rb[2]) z = 2;
  PoolJob jb = jobs.j[z];
  int row0 = (bx - jobs.rb[z]) * 64;
  __shared__ __align__(16) unsigned short Asm[64*LDA];
  __shared__ __align__(16) unsigned short Wsm[64*LDA];
  int t = threadIdx.x;
  int col0 = blockIdx.y * 64;
  {
    int r = t >> 2, seg = t & 3;
    int gr = row0 + r;
    unsigned short* ad = Asm + r*LDA + seg*48;
    if (gr < jb.n) {
      const unsigned short* Ar = jb.A + (size_t)gr*HID + seg*48;
      #pragma unroll
      for (int i = 0; i < 6; i++) *(uint4*)(ad + i*8) = *(const uint4*)(Ar + i*8);
    } else {
      uint4 zz = make_uint4(0,0,0,0);
      #pragma unroll
      for (int i = 0; i < 6; i++) *(uint4*)(ad + i*8) = zz;
    }
    const float* Wr = jb.W + (size_t)(col0 + r)*HID + seg*48;
    unsigned short* wd = Wsm + r*LDA + seg*48;
    #pragma unroll
    for (int i = 0; i < 12; i++) {
      float4 v = *reinterpret_cast<const float4*>(Wr + i*4);
      *reinterpret_cast<ushort4*>(wd + i*4) = f4bf(v);
    }
  }
  __syncthreads();
  int w = t >> 6, lane = t & 63;
  int quad = lane >> 4, mr = lane & 15;
  float4v acc[4] = {};
  const unsigned short* Abase = Asm + (w*16 + mr)*LDA + quad*8;
  const unsigned short* Wbase = Wsm + mr*LDA + quad*8;
  #pragma unroll
  for (int k0 = 0; k0 < 6; k0++) {
    short8 a = *reinterpret_cast<const short8*>(Abase + k0*32);
    #pragma unroll
    for (int ct = 0; ct < 4; ct++) {
      short8 b = *reinterpret_cast<const short8*>(Wbase + ct*16*LDA + k0*32);
      acc[ct] = __builtin_amdgcn_mfma_f32_16x16x32_bf16(a, b, acc[ct], 0, 0, 0);
    }
  }
  #pragma unroll
  for (int ct = 0; ct < 4; ct++) {
    #pragma unroll
    for (int reg = 0; reg < 4; reg++) {
      int rr = row0 + w*16 + quad*4 + reg;
      if (rr < jb.n) {
        int cc = col0 + ct*16 + mr;
        jb.out[(size_t)rr*HID + cc] = acc[ct][reg] + jb.bias[cc];
      }
    }
  }
}

// -------- batched dual GEMM (2 jobs): out = A1(fp32,rs)·W1^T + A2(bf16)·W2^T + b
struct G2Job { const float* A1; const float* rs1; const float* W1;
               const unsigned short* A2; const float* W2; const float* bias;
               float* out; int n; };
struct G2Jobs { G2Job j[2]; int rb[3]; };
__global__ __launch_bounds__(256)
void k_gemm2(G2Jobs jobs)
{
  int bx = blockIdx.x;
  int z = (bx >= jobs.rb[1]) ? 1 : 0;
  G2Job jb = jobs.j[z];
  int row0 = (bx - jobs.rb[z]) * 64;
  __shared__ __align__(16) unsigned short Asm[64*LDA];
  __shared__ __align__(16) unsigned short Wsm[64*LDA];
  int t = threadIdx.x;
  int col0 = blockIdx.y * 64;
  int r = t >> 2, seg = t & 3;
  int w = t >> 6, lane = t & 63;
  int quad = lane >> 4, mr = lane & 15;
  float4v acc[4] = {};
  for (int p = 0; p < 2; p++) {
    if (p) __syncthreads();
    const float* W = p ? jb.W2 : jb.W1;
    {
      int gr = row0 + r;
      unsigned short* ad = Asm + r*LDA + seg*48;
      if (gr < jb.n) {
        if (p == 0) {
          float sc = jb.rs1 ? jb.rs1[gr] : 1.0f;
          const float* Ar = jb.A1 + (size_t)gr*HID + seg*48;
          #pragma unroll
          for (int i = 0; i < 12; i++) {
            float4 v = *reinterpret_cast<const float4*>(Ar + i*4);
            v.x *= sc; v.y *= sc; v.z *= sc; v.w *= sc;
            *reinterpret_cast<ushort4*>(ad + i*4) = f4bf(v);
          }
        } else {
          const unsigned short* Ar = jb.A2 + (size_t)gr*HID + seg*48;
          #pragma unroll
          for (int i = 0; i < 6; i++) *(uint4*)(ad + i*8) = *(const uint4*)(Ar + i*8);
        }
      } else {
        uint4 zz = make_uint4(0,0,0,0);
        #pragma unroll
        for (int i = 0; i < 6; i++) *(uint4*)(ad + i*8) = zz;
      }
      const float* Wr = W + (size_t)(col0 + r)*HID + seg*48;
      unsigned short* wd = Wsm + r*LDA + seg*48;
      #pragma unroll
      for (int i = 0; i < 12; i++) {
        float4 v = *reinterpret_cast<const float4*>(Wr + i*4);
        *reinterpret_cast<ushort4*>(wd + i*4) = f4bf(v);
      }
    }
    __syncthreads();
    const unsigned short* Abase = Asm + (w*16 + mr)*LDA + quad*8;
    const unsigned short* Wbase = Wsm + mr*LDA + quad*8;
    #pragma unroll
    for (int k0 = 0; k0 < 6; k0++) {
      short8 a = *reinterpret_cast<const short8*>(Abase + k0*32);
      #pragma unroll
      for (int ct = 0; ct < 4; ct++) {
        short8 b = *reinterpret_cast<const short8*>(Wbase + ct*16*LDA + k0*32);
        acc[ct] = __builtin_amdgcn_mfma_f32_16x16x32_bf16(a, b, acc[ct], 0, 0, 0);
      }
    }
  }
  #pragma unroll
  for (int ct = 0; ct < 4; ct++) {
    #pragma unroll
    for (int reg = 0; reg < 4; reg++) {
      int rr = row0 + w*16 + quad*4 + reg;
      if (rr < jb.n) {
        int cc = col0 + ct*16 + mr;
        jb.out[(size_t)rr*HID + cc] = acc[ct][reg] + jb.bias[cc];
      }
    }
  }
}

// ---------------- unified K-loop MFMA GEMM (17 jobs: s->g + split-K g->s) --
#define BKG 128
#define LDG 136
struct KJob { const unsigned short* A; int lda;
              const unsigned short* W; int ldw;
              float* out; int n; int kbeg; int kend; };
struct KJobs { KJob j[17]; int rb[18]; };
__global__ __launch_bounds__(256)
void k_gemm_k(KJobs jobs)
{
  int bx = blockIdx.x;
  int z = 0;
  for (int q = 1; q < 17; q++) if (bx >= jobs.rb[q]) z = q;
  KJob jb = jobs.j[z];
  int row0 = (bx - jobs.rb[z]) * 64;
  __shared__ __align__(16) unsigned short Asm[64*LDG];
  __shared__ __align__(16) unsigned short Wsm[64*LDG];
  int t = threadIdx.x;
  int col0 = blockIdx.y * 64;
  int r = t >> 2, seg = t & 3;
  int w = t >> 6, lane = t & 63;
  int quad = lane >> 4, mr = lane & 15;
  float4v acc[4] = {};
  for (int k0 = jb.kbeg; k0 < jb.kend; k0 += BKG) {
    {
      int gr = row0 + r;
      unsigned short* ad = Asm + r*LDG + seg*32;
      if (gr < jb.n) {
        const unsigned short* Ar = jb.A + (size_t)gr*jb.lda + k0 + seg*32;
        #pragma unroll
        for (int i = 0; i < 4; i++) *(uint4*)(ad + i*8) = *(const uint4*)(Ar + i*8);
      } else {
        uint4 zz = make_uint4(0,0,0,0);
        #pragma unroll
        for (int i = 0; i < 4; i++) *(uint4*)(ad + i*8) = zz;
      }
      const unsigned short* Wr = jb.W + (size_t)(col0 + r)*jb.ldw + k0 + seg*32;
      unsigned short* wd = Wsm + r*LDG + seg*32;
      #pragma unroll
      for (int i = 0; i < 4; i++) *(uint4*)(wd + i*8) = *(const uint4*)(Wr + i*8);
    }
    __syncthreads();
    const unsigned short* Abase = Asm + (w*16 + mr)*LDG + quad*8;
    const unsigned short* Wbase = Wsm + mr*LDG + quad*8;
    #pragma unroll
    for (int kk = 0; kk < 4; kk++) {
      short8 a = *(const short8*)(Abase + kk*32);
      #pragma unroll
      for (int ct = 0; ct < 4; ct++) {
        short8 b = *(const short8*)(Wbase + ct*16*LDG + kk*32);
        acc[ct] = __builtin_amdgcn_mfma_f32_16x16x32_bf16(a, b, acc[ct], 0, 0, 0);
      }
    }
    __syncthreads();
  }
  #pragma unroll
  for (int ct = 0; ct < 4; ct++) {
    #pragma unroll
    for (int reg = 0; reg < 4; reg++) {
      int rr = row0 + w*16 + quad*4 + reg;
      if (rr < jb.n) jb.out[(size_t)rr*HID + col0 + ct*16 + mr] = acc[ct][reg];
    }
  }
}

__global__ __launch_bounds__(256)
void k_reduce_sk(const float* __restrict__ part, float* __restrict__ outp, int n){
  int i = blockIdx.x*256 + threadIdx.x;
  if (i >= n*HID) return;
  float s = 0.0f;
  #pragma unroll
  for (int z = 0; z < SPLITK; z++) s += part[(size_t)z*n*HID + i];
  outp[i] = s;
}

// ---------------- batched GATv2: wave-per-dst, LDS-staged gl, b64 agg ------
struct GatJob { const unsigned short* gl; const unsigned short* gr;
                const int* rowptr; const int* col;
                const float* att; const float* bias; float* out; int ndst; int accum; };
struct GatJobs { GatJob j[3]; int bo[4]; };

#define GLS_LD 200   // padded LDS row (ushort) for staged gl
__global__ __launch_bounds__(256)
void k_gat_all(GatJobs jobs)
{
  int bx = blockIdx.x;
  int jz = 0;
  if (bx >= jobs.bo[1]) jz = 1;
  if (bx >= jobs.bo[2]) jz = 2;
  GatJob jb = jobs.j[jz];
  int tid = threadIdx.x;
  int w = tid >> 6, lane = tid & 63;
  int dst = (bx - jobs.bo[jz])*4 + w;
  bool active = dst < jb.ndst;
  __shared__ float attS[HID];
  __shared__ float grS[4][HID];
  __shared__ __align__(16) unsigned short glS[4][16][GLS_LD];
  __shared__ float swS[4][4][16];
  __shared__ float fS[4][4];
  __shared__ float lS[4][4];
  if (tid < HID) attS[tid] = jb.att[tid];
  if (active) {
    const unsigned short* grr = jb.gr + (size_t)dst*HID;
    grS[w][lane]     = bf2f(grr[lane]);
    grS[w][lane+64]  = bf2f(grr[lane+64]);
    grS[w][lane+128] = bf2f(grr[lane+128]);
  }
  __syncthreads();   // attS visibility (all 256 threads reach this)
  if (!active) return;

  int h16 = lane >> 4, j16 = lane & 15;
  bool aggL = lane < 48;           // lane owns dims 4*lane .. 4*lane+3
  int hAgg = lane / 12;            // head of those dims (only valid if aggL)
  if (hAgg > 3) hAgg = 3;
  int start = jb.rowptr[dst], end = jb.rowptr[dst+1];
  float m = -1e30f, l = 0.0f;
  float4 facc = make_float4(0.f, 0.f, 0.f, 0.f);
  const float* attH = attS + h16*CDIM;
  const float* grH  = grS[w] + h16*CDIM;

  for (int c0 = start; c0 < end; c0 += 16) {
    int nc = min(16, end - c0);
    float sc = -1e30f;
    if (j16 < nc) {
      int s = jb.col[c0 + j16];
      const short8* glv = (const short8*)(jb.gl + (size_t)s*HID + h16*CDIM);
      unsigned short* ls = &glS[w][j16][h16*CDIM];
      float a = 0.0f;
      #pragma unroll
      for (int v8 = 0; v8 < 6; v8++) {
        short8 g8 = glv[v8];
        *(short8*)(ls + v8*8) = g8;     // stage row slice to LDS (wave-local)
        #pragma unroll
        for (int jj = 0; jj < 8; jj++) {
          float v = bf2f((unsigned short)g8[jj]) + grH[v8*8+jj];
          v = v > 0.0f ? v : 0.2f*v;
          a += v * attH[v8*8+jj];
        }
      }
      sc = a;
    }
    float cm = sc;
    cm = fmaxf(cm, __shfl_xor(cm, 1));
    cm = fmaxf(cm, __shfl_xor(cm, 2));
    cm = fmaxf(cm, __shfl_xor(cm, 4));
    cm = fmaxf(cm, __shfl_xor(cm, 8));
    float nm = fmaxf(m, cm);
    float f = __expf(m - nm);          // m=-1e30 -> 0
    l *= f;
    float e = (j16 < nc) ? __expf(sc - nm) : 0.0f;
    swS[w][h16][j16] = e;
    float cl = e;
    cl += __shfl_xor(cl, 1);
    cl += __shfl_xor(cl, 2);
    cl += __shfl_xor(cl, 4);
    cl += __shfl_xor(cl, 8);
    l += cl;
    m = nm;
    if (j16 == 0) fS[w][h16] = f;
    if (aggL) {
      float fr = fS[w][hAgg];
      facc.x *= fr; facc.y *= fr; facc.z *= fr; facc.w *= fr;
      for (int j = 0; j < nc; j++) {
        float wgt = swS[w][hAgg][j];
        uint2 u = *(const uint2*)&glS[w][j][lane*4];
        facc.x += wgt * __uint_as_float(u.x << 16);
        facc.y += wgt * __uint_as_float(u.x & 0xffff0000u);
        facc.z += wgt * __uint_as_float(u.y << 16);
        facc.w += wgt * __uint_as_float(u.y & 0xffff0000u);
      }
    }
  }
  if (j16 == 0) lS[w][h16] = l;
  if (aggL) {
    float invl = 1.0f / (lS[w][hAgg] + 1e-16f);
    float4 bi = *(const float4*)(jb.bias + lane*4);
    float4 o;
    o.x = facc.x*invl + bi.x;
    o.y = facc.y*invl + bi.y;
    o.z = facc.z*invl + bi.z;
    o.w = facc.w*invl + bi.w;
    float* od = jb.out + (size_t)dst*HID;
    if (jb.accum) {
      float4 pv = *(const float4*)(od + lane*4);
      o.x += pv.x; o.y += pv.y; o.z += pv.z; o.w += pv.w;
    }
    *(float4*)(od + lane*4) = o;
  }
}

// ---------------- batched residual + LayerNorm (3 node types, bf16 mirror) --
__global__ __launch_bounds__(64)
void k_ln3(float* __restrict__ xs, const float* __restrict__ osb,
           float* __restrict__ xg, const float* __restrict__ og,
           float* __restrict__ xp, const float* __restrict__ opb,
           const float* __restrict__ op2,
           unsigned short* __restrict__ xsb, unsigned short* __restrict__ xgb,
           unsigned short* __restrict__ xpb,
           const float* __restrict__ LNg, const float* __restrict__ LNb, int l)
{
  int r = blockIdx.x;
  float* x; const float* d1; const float* d2 = nullptr; unsigned short* xb; int typ;
  if (r < N_S)            { x = xs + (size_t)r*HID; d1 = osb + (size_t)r*HID;
                            xb = xsb + (size_t)r*HID; typ = 0; }
  else if (r < N_S + N_G) { int rr = r - N_S; x = xg + (size_t)rr*HID; d1 = og + (size_t)rr*HID;
                            xb = xgb + (size_t)rr*HID; typ = 1; }
  else                    { int rr = r - N_S - N_G; x = xp + (size_t)rr*HID; d1 = opb + (size_t)rr*HID;
                            d2 = op2 + (size_t)rr*HID; xb = xpb + (size_t)rr*HID; typ = 2; }
  const float* g = LNg + (l*3 + typ)*HID;
  const float* b = LNb + (l*3 + typ)*HID;
  int lane = threadIdx.x;
  float v[3]; float sum = 0.0f;
  #pragma unroll
  for (int j=0;j<3;j++){
    int d = j*64 + lane;
    float t = x[d] + d1[d];
    if (d2) t += d2[d];
    v[j] = t; sum += t;
  }
  #pragma unroll
  for (int o=32;o;o>>=1) sum += __shfl_xor(sum, o);
  float mu = sum * (1.0f/HID);
  float var = 0.0f;
  #pragma unroll
  for (int j=0;j<3;j++){ float dd = v[j]-mu; var += dd*dd; }
  #pragma unroll
  for (int o=32;o;o>>=1) var += __shfl_xor(var, o);
  var *= (1.0f/HID);
  float inv = rsqrtf(var + 1e-5f);
  #pragma unroll
  for (int j=0;j<3;j++){
    int d = j*64 + lane;
    float val = (v[j]-mu)*inv*g[d] + b[d];
    x[d] = val;
    xb[d] = f2bf(val);
  }
}

// ---------------- pooling attention: one block per (q,h) ----------------
__global__ __launch_bounds__(256)
void k_pool_attn(const float* __restrict__ qb, const float* __restrict__ kb,
                 const float* __restrict__ vb, float* __restrict__ ob)
{
  int h = blockIdx.x & 3;
  int q = blockIdx.x >> 2;
  __shared__ float prob[N_S];
  __shared__ float red[256];
  int t = threadIdx.x;
  const float* qrow = qb + (size_t)q*HID + h*CDIM;
  const float scale = 0.14433756729740643f;
  for (int n = t; n < N_S; n += 256) {
    const float* krow = kb + (size_t)n*HID + h*CDIM;
    float s = 0.0f;
    #pragma unroll 8
    for (int c=0;c<CDIM;c++) s += qrow[c]*krow[c];
    prob[n] = s * scale;
  }
  __syncthreads();
  float m = -1e30f;
  for (int n=t;n<N_S;n+=256) m = fmaxf(m, prob[n]);
  red[t] = m; __syncthreads();
  for (int s2=128;s2;s2>>=1){ if (t<s2) red[t]=fmaxf(red[t],red[t+s2]); __syncthreads(); }
  m = red[0]; __syncthreads();
  float sum = 0.0f;
  for (int n=t;n<N_S;n+=256){ float e=__expf(prob[n]-m); prob[n]=e; sum+=e; }
  red[t] = sum; __syncthreads();
  for (int s2=128;s2;s2>>=1){ if (t<s2) red[t]+=red[t+s2]; __syncthreads(); }
  float inv = 1.0f/red[0];
  __syncthreads();
  if (t < CDIM) {
    float acc = 0.0f;
    for (int n=0;n<N_S;n++) acc += prob[n]*vb[(size_t)n*HID + h*CDIM + t];
    ob[(size_t)q*HID + h*CDIM + t] = acc * inv;
  }
}

// ---------------- tail ----------------
__global__ __launch_bounds__(192)
void k_tail(const float* __restrict__ ob2,
            const float* ffw1, const float* ffb1,
            const float* ffw2, const float* ffb2,
            const float* lng, const float* lnb,
            const float* pw, const float* pb,
            void* __restrict__ outp, const int* __restrict__ flag)
{
  __shared__ float pooled[HID];
  __shared__ float hh[HID];
  __shared__ float stats[2];
  int t = threadIdx.x;
  float a = 0.0f;
  for (int q=0;q<NQd;q++) a += ob2[q*HID + t];
  pooled[t] = a * (1.0f/NQd);
  __syncthreads();
  float s1 = ffb1[t];
  for (int k=0;k<HID;k++) s1 += pooled[k]*ffw1[t*HID+k];
  hh[t] = fmaxf(s1, 0.0f);
  __syncthreads();
  float s2 = ffb2[t];
  for (int k=0;k<HID;k++) s2 += hh[k]*ffw2[t*HID+k];
  __syncthreads();
  hh[t] = s2;
  __syncthreads();
  if (t == 0) {
    float mu=0.0f; for (int k=0;k<HID;k++) mu += hh[k];
    mu *= (1.0f/HID);
    float v=0.0f; for (int k=0;k<HID;k++){ float d=hh[k]-mu; v+=d*d; }
    v *= (1.0f/HID);
    stats[0]=mu; stats[1]=rsqrtf(v + 1e-5f);
  }
  __syncthreads();
  pooled[t] = (hh[t]-stats[0])*stats[1]*lng[t] + lnb[t];
  __syncthreads();
  if (t < OUTD) {
    float acc = pb[t];
    for (int k=0;k<HID;k++) acc += pooled[k]*pw[t*HID+k];
    if (flag[0]) ((float*)outp)[t] = acc;
    else         ((unsigned short*)outp)[t] = f2bf(acc);
  }
}

// =====================================================================
extern "C" void kernel_launch(void* const* d_in, const int* in_sizes, int n_in,
                              void* d_out, int out_size, void* d_ws, size_t ws_size,
                              hipStream_t stream)
{
  const int* sg_src = (const int*)d_in[3];
  const int* sg_dst = (const int*)d_in[4];
  const int* gp_src = (const int*)d_in[5];
  const int* gp_dst = (const int*)d_in[6];
  const int* pp_src = (const int*)d_in[7];
  const int* pp_dst = (const int*)d_in[8];

  float* base = (float*)d_ws;
  size_t off = 0;
  auto alloc = [&](size_t nf){ nf = (nf + 3) & ~(size_t)3; float* p = base + off; off += nf; return p; };
  int*   flag = (int*)alloc(4);
  float* xs   = alloc((size_t)N_S*HID);
  float* xg   = alloc((size_t)N_G*HID);
  float* xp   = alloc((size_t)N_P*HID);
  float* qin  = alloc((size_t)NQd*HID);
  float* Wsl  = alloc(2*2*HID*HID); float* bsl = alloc(2*2*HID); float* Wsr = alloc(2*2*HID*HID);
  float* Wgl  = alloc(2*3*HID*HID); float* bgl = alloc(2*3*HID);
  float* Wgr  = alloc(2*3*HID*HID); float* bgr = alloc(2*3*HID);
  float* Agat = alloc(2*3*HEADS*CDIM); float* Bgat = alloc(2*3*HID);
  float* LNg  = alloc(2*3*HID); float* LNb = alloc(2*3*HID);
  float* Pinw = alloc(3*HID*HID); float* Pinb = alloc(3*HID);
  float* Poutw= alloc(HID*HID);   float* Poutb= alloc(HID);
  float* Fw1  = alloc(HID*HID);   float* Fb1  = alloc(HID);
  float* Fw2  = alloc(HID*HID);   float* Fb2  = alloc(HID);
  float* PLg  = alloc(HID);       float* PLb  = alloc(HID);
  float* Pw   = alloc(OUTD*HID);  float* Pb   = alloc(OUTD);
  // runtime buffers
  float* agg  = alloc((size_t)N_G*HID);
  float* aggS = alloc((size_t)N_S*HID);
  float* og   = alloc((size_t)N_G*HID);
  float* osb  = alloc((size_t)N_S*HID);
  float* opb  = alloc((size_t)N_P*HID);
  float* op2  = alloc((size_t)N_P*HID);
  // bf16 mirrors of node features (+ pool query)
  unsigned short* xsb  = (unsigned short*)alloc((size_t)N_S*HID/2);
  unsigned short* xgb  = (unsigned short*)alloc((size_t)N_G*HID/2);
  unsigned short* xpb  = (unsigned short*)alloc((size_t)N_P*HID/2);
  unsigned short* qinb = (unsigned short*)alloc((size_t)NQd*HID/2 + 4);
  // bf16 GAT node transforms
  unsigned short* glGb  = (unsigned short*)alloc((size_t)N_G*HID/2);
  unsigned short* grGb  = (unsigned short*)alloc((size_t)N_G*HID/2);
  unsigned short* grP0b = (unsigned short*)alloc((size_t)N_P*HID/2);
  unsigned short* glP1b = (unsigned short*)alloc((size_t)N_P*HID/2);
  unsigned short* glP2b = (unsigned short*)alloc((size_t)N_P*HID/2);
  unsigned short* grP2b = (unsigned short*)alloc((size_t)N_P*HID/2);
  float* qbuf = alloc((size_t)NQd*HID);
  float* kbuf = alloc((size_t)N_S*HID);
  float* vbuf = alloc((size_t)N_S*HID);
  float* obuf = alloc((size_t)NQd*HID);
  float* ob2  = alloc((size_t)NQd*HID);
  // dense SAGE matrices
  int*            CntGi = (int*)alloc((size_t)N_G*N_S);
  unsigned short* CntGb = (unsigned short*)alloc((size_t)N_G*N_S/2);
  unsigned short* CntSb = (unsigned short*)alloc((size_t)N_S*LDK/2);
  unsigned short* xsTb  = (unsigned short*)alloc((size_t)HID*N_S/2);
  unsigned short* xgTb  = (unsigned short*)alloc((size_t)HID*LDK/2);
  float* part = alloc((size_t)SPLITK*N_S*HID);
  float* invdegG = alloc(N_G);
  float* invdegS = alloc(N_S);
  // CSR storage (GAT graphs)
  int* degAll = (int*)alloc(2*N_P + N_G + 4);
  int* curAll = (int*)alloc(2*N_P + N_G + 4);
  int* rp_gp_p = (int*)alloc(N_P+2);  int* col_gp_p = (int*)alloc(NE_GP);
  int* rp_gp_g = (int*)alloc(N_G+2);  int* col_gp_g = (int*)alloc(NE_GP);
  int* rp_pp_p = (int*)alloc(N_P+2);  int* col_pp_p = (int*)alloc(NE_PP);
  (void)ws_size; (void)in_sizes; (void)n_in; (void)out_size;

  k_detect<<<1,256,0,stream>>>((const unsigned int*)d_in[0], flag);

  // ---- batched input conversion (bf16 mirrors for feature tensors) ----
  {
    LoadTable tab;
    int k = 0;
    auto add = [&](int i, float* dst, unsigned short* m, int n){
      tab.d[k].src = d_in[i]; tab.d[k].dst = dst; tab.d[k].dst16 = m; tab.d[k].n = n; k++; };
    add(0,  xs, xsb, N_S*HID);  add(1,  xg, xgb, N_G*HID);  add(2,  xp, xpb, N_P*HID);
    add(9,  Wsl, nullptr, 2*2*HID*HID); add(10, bsl, nullptr, 2*2*HID); add(11, Wsr, nullptr, 2*2*HID*HID);
    add(12, Wgl, nullptr, 2*3*HID*HID); add(13, bgl, nullptr, 2*3*HID);
    add(14, Wgr, nullptr, 2*3*HID*HID); add(15, bgr, nullptr, 2*3*HID);
    add(16, Agat, nullptr, 2*3*HEADS*CDIM); add(17, Bgat, nullptr, 2*3*HID);
    add(18, LNg, nullptr, 2*3*HID); add(19, LNb, nullptr, 2*3*HID);
    add(20, qin, qinb, NQd*HID);
    add(21, Pinw, nullptr, 3*HID*HID); add(22, Pinb, nullptr, 3*HID);
    add(23, Poutw, nullptr, HID*HID);  add(24, Poutb, nullptr, HID);
    add(25, Fw1, nullptr, HID*HID); add(26, Fb1, nullptr, HID);
    add(27, Fw2, nullptr, HID*HID); add(28, Fb2, nullptr, HID);
    add(29, PLg, nullptr, HID); add(30, PLb, nullptr, HID);
    add(31, Pw, nullptr, OUTD*HID); add(32, Pb, nullptr, OUTD);
    k_load_all<<<dim3(LOADBX, NLOAD),256,0,stream>>>(tab, flag);
  }

  // ---- dense SAGE counts ----
  hipMemsetAsync(CntGi, 0, (size_t)N_G*N_S*4, stream);
  hipMemsetAsync(degAll, 0, (size_t)(2*N_P + N_G)*4, stream);
  k_cntbuild<<<(NE_SG+255)/256,256,0,stream>>>(sg_src, sg_dst, CntGi, NE_SG);
  k_cvtT<<<dim3(LDK/64, N_S/64),256,0,stream>>>(CntGi, CntGb, CntSb);
  k_rowinv_i<<<(N_G+3)/4,256,0,stream>>>(CntGi, N_S, N_S, N_G, invdegG);
  k_rowinv_h<<<N_S,256,0,stream>>>(CntSb, LDK, LDK, N_S, invdegS);

  // ---- batched CSR build for the 3 GAT graphs ----
  {
    CsrJobs jobs;
    jobs.j[0] = { gp_src, gp_dst, NE_GP, N_P, degAll,           rp_gp_p, curAll,           col_gp_p };
    jobs.j[1] = { gp_dst, gp_src, NE_GP, N_G, degAll+N_P,       rp_gp_g, curAll+N_P,       col_gp_g };
    jobs.j[2] = { pp_src, pp_dst, NE_PP, N_P, degAll+N_P+N_G,   rp_pp_p, curAll+N_P+N_G,   col_pp_p };
    k_hist3<<<dim3((NE_GP+255)/256, 3),256,0,stream>>>(jobs);
    k_scan3<<<3,256,0,stream>>>(jobs);
    k_fill3<<<dim3((NE_GP+255)/256, 3),256,0,stream>>>(jobs);
  }

  const int RB_G = (N_G+63)/64, RB_P = (N_P+63)/64;       // 181, 32
  const int GB_P = (N_P+3)/4,  GB_G = (N_G+3)/4;          // 500, 2890

  for (int l=0; l<2; l++) {
    // both feature transposes in one dispatch
    {
      TransJobs tj;
      tj.inA = xs; tj.outA = xsTb; tj.nA = N_S; tj.ldoA = N_S; tj.rbA = 8;
      tj.inB = xg; tj.outB = xgTb; tj.nB = N_G; tj.ldoB = LDK;
      k_transpose2<<<dim3(8 + LDK/64, 3),256,0,stream>>>(tj);
    }
    // SAGE aggregations: s->g (K=512) + split-K g->s, one dispatch
    {
      KJobs kj;
      kj.j[0] = { CntGb, N_S, xsTb, N_S, agg, N_G, 0, N_S };
      kj.rb[0] = 0; kj.rb[1] = RB_G;
      for (int z = 0; z < SPLITK; z++) {
        kj.j[1+z] = { CntSb, LDK, xgTb, LDK, part + (size_t)z*N_S*HID, N_S,
                      z*CHUNKK, (z+1)*CHUNKK };
        kj.rb[2+z] = kj.rb[1+z] + 8;
      }
      k_gemm_k<<<dim3(kj.rb[17],3),256,0,stream>>>(kj);
    }
    k_reduce_sk<<<(N_S*HID+255)/256,256,0,stream>>>(part, aggS, N_S);
    // both SAGE weight GEMMs (og, osb) in one dispatch
    {
      G2Jobs g2;
      g2.j[0] = { agg,  invdegG, Wsl + (size_t)(l*2+0)*HID*HID,
                  xgb, Wsr + (size_t)(l*2+0)*HID*HID, bsl + (l*2+0)*HID, og,  N_G };
      g2.j[1] = { aggS, invdegS, Wsl + (size_t)(l*2+1)*HID*HID,
                  xsb, Wsr + (size_t)(l*2+1)*HID*HID, bsl + (l*2+1)*HID, osb, N_S };
      g2.rb[0] = 0; g2.rb[1] = RB_G; g2.rb[2] = RB_G + (N_S+63)/64;
      k_gemm2<<<dim3(g2.rb[2],3),256,0,stream>>>(g2);
    }
    // GAT: 6 node transforms in one flat dispatch (bf16 A and outputs)
    {
      GemmJobs gj;
      int w0 = l*3+0, w1 = l*3+1, w2 = l*3+2;
      gj.j[0] = { xgb, Wgl + (size_t)w0*HID*HID, bgl + w0*HID, glGb,  N_G };
      gj.j[1] = { xpb, Wgr + (size_t)w0*HID*HID, bgr + w0*HID, grP0b, N_P };
      gj.j[2] = { xpb, Wgl + (size_t)w1*HID*HID, bgl + w1*HID, glP1b, N_P };
      gj.j[3] = { xgb, Wgr + (size_t)w1*HID*HID, bgr + w1*HID, grGb,  N_G };
      gj.j[4] = { xpb, Wgl + (size_t)w2*HID*HID, bgl + w2*HID, glP2b, N_P };
      gj.j[5] = { xpb, Wgr + (size_t)w2*HID*HID, bgr + w2*HID, grP2b, N_P };
      int nrb[6] = { RB_G, RB_P, RB_P, RB_G, RB_P, RB_P };
      gj.rb[0] = 0;
      for (int q = 0; q < 6; q++) gj.rb[q+1] = gj.rb[q] + nrb[q];
      k_gemm6<<<dim3(gj.rb[6],3),256,0,stream>>>(gj);
    }
    // GAT: 3 edge passes in one flat dispatch (wave-per-destination)
    {
      GatJobs gt;
      int w0 = l*3+0, w1 = l*3+1, w2 = l*3+2;
      gt.j[0] = { glGb,  grP0b, rp_gp_p, col_gp_p, Agat + (size_t)w0*HID, Bgat + (size_t)w0*HID, opb, N_P, 0 };
      gt.j[1] = { glP1b, grGb,  rp_gp_g, col_gp_g, Agat + (size_t)w1*HID, Bgat + (size_t)w1*HID, og,  N_G, 1 };
      gt.j[2] = { glP2b, grP2b, rp_pp_p, col_pp_p, Agat + (size_t)w2*HID, Bgat + (size_t)w2*HID, op2, N_P, 0 };
      gt.bo[0] = 0; gt.bo[1] = GB_P; gt.bo[2] = GB_P + GB_G; gt.bo[3] = GB_P + GB_G + GB_P;
      k_gat_all<<<dim3(gt.bo[3]),256,0,stream>>>(gt);
    }
    // residual + LN (fp32 + bf16 mirror), all node types in one dispatch
    k_ln3<<<N_S+N_G+N_P,64,0,stream>>>(xs, osb, xg, og, xp, opb, op2,
                                       xsb, xgb, xpb, LNg, LNb, l);
  }

  // ---- pooling: q/k/v in one dispatch (bf16 A) ----
  {
    PoolJobs pj;
    pj.j[0] = { qinb, Pinw,                     Pinb,         qbuf, NQd };
    pj.j[1] = { xsb,  Pinw + (size_t)HID*HID,   Pinb + HID,   kbuf, N_S };
    pj.j[2] = { xsb,  Pinw + (size_t)2*HID*HID, Pinb + 2*HID, vbuf, N_S };
    pj.rb[0] = 0; pj.rb[1] = 1; pj.rb[2] = 1 + (N_S+63)/64; pj.rb[3] = pj.rb[2] + (N_S+63)/64;
    k_gemm3<<<dim3(pj.rb[3],3),256,0,stream>>>(pj);
  }
  k_pool_attn<<<NQd*HEADS,256,0,stream>>>(qbuf, kbuf, vbuf, obuf);
  k_gemm<<<dim3(1,3),256,0,stream>>>(obuf, Poutw, Poutb, ob2, NQd);
  k_tail<<<1,HID,0,stream>>>(ob2, Fw1, Fb1, Fw2, Fb2, PLg, PLb, Pw, Pb, d_out, flag);
}